// Round 1
// baseline (2689.490 us; speedup 1.0000x reference)
//
#include <hip/hip_runtime.h>
#include <math.h>

// Problem constants (fixed by setup_inputs)
#define NB 2
#define NL 2048
#define NH 16
#define ND 64
#define NDM 1024
#define NU 409                  // max(1, 2048 // 5)
#define NBH (NB*NH)             // 32
#define NROWS (NB*NL)           // 4096
#define NRTOT (NB*NH*NL)        // 65536

// ---------------------------------------------------------------- zero fill
__global__ __launch_bounds__(256) void zero_f4(float4* __restrict__ p) {
  const size_t i = (size_t)blockIdx.x * 256 + threadIdx.x;
  p[i] = make_float4(0.f, 0.f, 0.f, 0.f);
}

// ---------------------------------------------------------------- f32 GEMM
// C = A(MxK) * W(NxK)^T + bias.  GA: gather A from (B,H,L,D) ctx layout.
// SC: scatter C into (B,H,L,D) layout (col n -> h=n/64, d=n%64).
template<bool GA, bool SC>
__global__ __launch_bounds__(256) void gemm_f32_k(
    const float* __restrict__ A, const float* __restrict__ W,
    const float* __restrict__ bias, float* __restrict__ C,
    int M, int N, int K)
{
  __shared__ float As[64][16];   // [m][k]
  __shared__ float Ws[16][64];   // [k][n]
  const int tid = threadIdx.x;
  const int n0 = blockIdx.x << 6, m0 = blockIdx.y << 6;
  const int tx = tid & 15, ty = tid >> 4;
  const int lm = tid >> 2;            // 0..63 (row of tile)
  const int lk = (tid & 3) << 2;      // 0,4,8,12

  float4 a0 = {0,0,0,0}, a1 = {0,0,0,0}, a2 = {0,0,0,0}, a3 = {0,0,0,0};

  for (int k0 = 0; k0 < K; k0 += 16) {
    float4 av;
    if (GA) {
      const int gm = m0 + lm, gk = k0 + lk;
      const int bb = gm >> 11, ll = gm & (NL - 1);
      const int hh = gk >> 6,  dd = gk & 63;
      av = *(const float4*)(A + (((size_t)(bb*NH + hh)*NL + ll) << 6) + dd);
    } else {
      av = *(const float4*)(A + (size_t)(m0 + lm)*K + (k0 + lk));
    }
    *(float4*)&As[lm][lk] = av;
    const float4 wv = *(const float4*)(W + (size_t)(n0 + lm)*K + (k0 + lk));
    Ws[lk+0][lm] = wv.x; Ws[lk+1][lm] = wv.y;
    Ws[lk+2][lm] = wv.z; Ws[lk+3][lm] = wv.w;
    __syncthreads();
    #pragma unroll
    for (int k = 0; k < 16; ++k) {
      const float4 w4 = *(const float4*)&Ws[k][tx << 2];
      const float x0 = As[(ty<<2)+0][k];
      const float x1 = As[(ty<<2)+1][k];
      const float x2 = As[(ty<<2)+2][k];
      const float x3 = As[(ty<<2)+3][k];
      a0.x = fmaf(x0,w4.x,a0.x); a0.y = fmaf(x0,w4.y,a0.y);
      a0.z = fmaf(x0,w4.z,a0.z); a0.w = fmaf(x0,w4.w,a0.w);
      a1.x = fmaf(x1,w4.x,a1.x); a1.y = fmaf(x1,w4.y,a1.y);
      a1.z = fmaf(x1,w4.z,a1.z); a1.w = fmaf(x1,w4.w,a1.w);
      a2.x = fmaf(x2,w4.x,a2.x); a2.y = fmaf(x2,w4.y,a2.y);
      a2.z = fmaf(x2,w4.z,a2.z); a2.w = fmaf(x2,w4.w,a2.w);
      a3.x = fmaf(x3,w4.x,a3.x); a3.y = fmaf(x3,w4.y,a3.y);
      a3.z = fmaf(x3,w4.z,a3.z); a3.w = fmaf(x3,w4.w,a3.w);
    }
    __syncthreads();
  }

  const int col = n0 + (tx << 2);
  const float4 b4 = *(const float4*)(bias + col);
  float4 r[4] = {a0, a1, a2, a3};
  #pragma unroll
  for (int i = 0; i < 4; ++i) {
    r[i].x += b4.x; r[i].y += b4.y; r[i].z += b4.z; r[i].w += b4.w;
  }
  const int gm0 = m0 + (ty << 2);
  if (SC) {
    const int hh = col >> 6, dd = col & 63;
    #pragma unroll
    for (int i = 0; i < 4; ++i) {
      const int gm = gm0 + i, bb = gm >> 11, ll = gm & (NL - 1);
      *(float4*)(C + (((size_t)(bb*NH + hh)*NL + ll) << 6) + dd) = r[i];
    }
  } else {
    #pragma unroll
    for (int i = 0; i < 4; ++i)
      *(float4*)(C + (size_t)(gm0 + i)*N + col) = r[i];
  }
}

// ---------------------------------------------------------------- K row inv-norms
__global__ __launch_bounds__(256) void invnorm_k(const float* __restrict__ Kb,
                                                 float* __restrict__ invn) {
  const int r = blockIdx.x * 256 + threadIdx.x;
  const float4* p = (const float4*)(Kb + ((size_t)r << 6));
  double s = 0.0;
  #pragma unroll
  for (int i = 0; i < 16; ++i) {
    const float4 v = p[i];
    s += (double)v.x*v.x + (double)v.y*v.y + (double)v.z*v.z + (double)v.w*v.w;
  }
  invn[r] = (float)(1.0 / sqrt(s));
}

// ---------------------------------------------------------------- kbar = mean_l k_norm  (f64)
__global__ __launch_bounds__(64) void kbar_k(const float* __restrict__ Kb,
                                             const float* __restrict__ invn,
                                             double* __restrict__ kbar) {
  const int bh = blockIdx.x, d = threadIdx.x;
  const float* base = Kb + ((size_t)bh * NL << 6);
  const float* ib = invn + (size_t)bh * NL;
  double s = 0.0;
  for (int l = 0; l < NL; ++l)
    s += (double)base[(l << 6) + d] * (double)ib[l];
  kbar[(bh << 6) + d] = s * (1.0 / NL);
}

// ---------------------------------------------------------------- mean_scores = (q . kbar)/|q|  (f64)
__global__ __launch_bounds__(256) void ms_k(const float* __restrict__ Q,
                                            const double* __restrict__ kbar,
                                            float* __restrict__ ms) {
  __shared__ double kb[64];
  const int bh = blockIdx.x >> 3;              // 8 blocks of 256 rows per (b,h)
  if (threadIdx.x < 64) kb[threadIdx.x] = kbar[(bh << 6) + threadIdx.x];
  __syncthreads();
  const int r = blockIdx.x * 256 + threadIdx.x;
  const float* q = Q + ((size_t)r << 6);
  double dot = 0.0, ss = 0.0;
  #pragma unroll 16
  for (int i = 0; i < 64; ++i) {
    const double x = q[i];
    dot += x * kb[i];
    ss += x * x;
  }
  ms[r] = (float)(dot / sqrt(ss));
}

// ---------------------------------------------------------------- top-NU selection per (b,h)
__global__ __launch_bounds__(256) void select_k(const float* __restrict__ ms,
                                                int* __restrict__ sel) {
  __shared__ unsigned keys[NL];
  __shared__ int red[256];
  const int bh = blockIdx.x, tid = threadIdx.x;
  for (int l = tid; l < NL; l += 256) {
    const unsigned b = __float_as_uint(ms[(size_t)bh * NL + l]);
    keys[l] = (b & 0x80000000u) ? ~b : (b | 0x80000000u);   // order-preserving map
  }
  __syncthreads();
  unsigned lo = 0u, hi = 0xFFFFFFFFu;
  while (hi - lo > 1u) {           // invariant: count(>=lo) >= NU > count(>=hi)
    const unsigned mid = lo + ((hi - lo) >> 1);
    int c = 0;
    for (int l = tid; l < NL; l += 256) c += (keys[l] >= mid) ? 1 : 0;
    red[tid] = c; __syncthreads();
    for (int s = 128; s > 0; s >>= 1) {
      if (tid < s) red[tid] += red[tid + s];
      __syncthreads();
    }
    const int tot = red[0]; __syncthreads();
    if (tot >= NU) lo = mid; else hi = mid;
  }
  const unsigned V = lo;           // NU-th largest key
  int c = 0;
  for (int l = tid; l < NL; l += 256) c += (keys[l] > V) ? 1 : 0;
  red[tid] = c; __syncthreads();
  for (int s = 128; s > 0; s >>= 1) {
    if (tid < s) red[tid] += red[tid + s];
    __syncthreads();
  }
  const int g = red[0];
  if (tid == 0) {                  // ties broken by lowest index (matches lax.top_k)
    const int need = NU - g;
    int cnt = 0, t = 0;
    for (int l = 0; l < NL && cnt < NU; ++l) {
      const unsigned kk = keys[l];
      if (kk > V) sel[bh*NU + (cnt++)] = l;
      else if (kk == V && t < need) { sel[bh*NU + (cnt++)] = l; ++t; }
    }
  }
}

// ---------------------------------------------------------------- dense attention on selected queries
__global__ __launch_bounds__(256) void attn_k(
    const float* __restrict__ Q, const float* __restrict__ Kb,
    const float* __restrict__ Vb, const int* __restrict__ sel,
    float* __restrict__ ctx)
{
  __shared__ float sc[NL];
  __shared__ float qs[64];
  __shared__ float pr[4][64];
  __shared__ float red[256];
  const int bh = blockIdx.x / NU, ui = blockIdx.x % NU;
  const int tid = threadIdx.x;
  const int lq = sel[bh*NU + ui];

  if (tid < 16)
    ((float4*)qs)[tid] = ((const float4*)(Q + (((size_t)bh*NL + lq) << 6)))[tid];
  __syncthreads();

  float lmax = -1e30f;
  for (int l = tid; l < NL; l += 256) {
    const float4* kr = (const float4*)(Kb + (((size_t)bh*NL + l) << 6));
    float s = 0.f;
    #pragma unroll
    for (int i = 0; i < 16; ++i) {
      const float4 kv = kr[i]; const float4 qv = ((float4*)qs)[i];
      s = fmaf(kv.x,qv.x, fmaf(kv.y,qv.y, fmaf(kv.z,qv.z, fmaf(kv.w,qv.w, s))));
    }
    s *= 0.125f;                       // 1/sqrt(64)
    sc[l] = s; lmax = fmaxf(lmax, s);
  }
  red[tid] = lmax; __syncthreads();
  for (int s = 128; s > 0; s >>= 1) {
    if (tid < s) red[tid] = fmaxf(red[tid], red[tid + s]);
    __syncthreads();
  }
  const float gmax = red[0]; __syncthreads();

  float lsum = 0.f;
  for (int l = tid; l < NL; l += 256) {
    const float p = __expf(sc[l] - gmax);
    sc[l] = p; lsum += p;
  }
  red[tid] = lsum; __syncthreads();
  for (int s = 128; s > 0; s >>= 1) {
    if (tid < s) red[tid] += red[tid + s];
    __syncthreads();
  }
  const float inv = 1.f / red[0];

  const int d = tid & 63, g = tid >> 6;
  float a = 0.f;
  for (int l = g; l < NL; l += 4)
    a = fmaf(sc[l], Vb[(((size_t)bh*NL + l) << 6) + d], a);
  pr[g][d] = a; __syncthreads();
  if (tid < 64) {
    ctx[(((size_t)bh*NL + lq) << 6) + tid] =
        (pr[0][tid] + pr[1][tid] + pr[2][tid] + pr[3][tid]) * inv;
  }
}

// ---------------------------------------------------------------- launch
extern "C" void kernel_launch(void* const* d_in, const int* in_sizes, int n_in,
                              void* d_out, int out_size, void* d_ws, size_t ws_size,
                              hipStream_t stream)
{
  (void)in_sizes; (void)n_in; (void)out_size; (void)ws_size;
  const float* queries = (const float*)d_in[0];
  const float* keys    = (const float*)d_in[1];
  const float* values  = (const float*)d_in[2];
  const float* Wq = (const float*)d_in[3];  const float* bq = (const float*)d_in[4];
  const float* Wk = (const float*)d_in[5];  const float* bk = (const float*)d_in[6];
  const float* Wv = (const float*)d_in[7];  const float* bv = (const float*)d_in[8];
  const float* Wo = (const float*)d_in[9];  const float* bo = (const float*)d_in[10];
  float* out = (float*)d_out;

  char* w = (char*)d_ws;
  const size_t fsz = (size_t)NRTOT * ND * sizeof(float);       // 16.78 MB
  float*  Qb   = (float*)w;  w += fsz;
  float*  Kbuf = (float*)w;  w += fsz;
  float*  Vbuf = (float*)w;  w += fsz;
  float*  CTX  = (float*)w;  w += fsz;
  float*  invn = (float*)w;  w += (size_t)NRTOT * sizeof(float);
  double* kbar = (double*)w; w += (size_t)NBH * ND * sizeof(double);
  float*  msb  = (float*)w;  w += (size_t)NRTOT * sizeof(float);
  int*    sel  = (int*)w;    w += (size_t)NBH * NU * sizeof(int);

  const dim3 gg(NDM / 64, NROWS / 64);

  gemm_f32_k<false, true><<<gg, 256, 0, stream>>>(queries, Wq, bq, Qb,   NROWS, NDM, NDM);
  gemm_f32_k<false, true><<<gg, 256, 0, stream>>>(keys,    Wk, bk, Kbuf, NROWS, NDM, NDM);
  gemm_f32_k<false, true><<<gg, 256, 0, stream>>>(values,  Wv, bv, Vbuf, NROWS, NDM, NDM);

  invnorm_k<<<NRTOT / 256, 256, 0, stream>>>(Kbuf, invn);
  kbar_k<<<NBH, 64, 0, stream>>>(Kbuf, invn, kbar);
  ms_k<<<NRTOT / 256, 256, 0, stream>>>(Qb, kbar, msb);
  select_k<<<NBH, 256, 0, stream>>>(msb, sel);

  zero_f4<<<(NRTOT * ND / 4) / 256, 256, 0, stream>>>((float4*)CTX);
  attn_k<<<NBH * NU, 256, 0, stream>>>(Qb, Kbuf, Vbuf, sel, CTX);

  gemm_f32_k<true, false><<<gg, 256, 0, stream>>>(CTX, Wo, bo, out, NROWS, NDM, NDM);
}

// Round 2
// 960.029 us; speedup vs baseline: 2.8015x; 2.8015x over previous
//
#include <hip/hip_runtime.h>
#include <math.h>

// Problem constants (fixed by setup_inputs)
#define NB 2
#define NL 2048
#define NH 16
#define ND 64
#define NDM 1024
#define NU 409                  // max(1, 2048 // 5)
#define NUP 416                 // NU padded to multiple of 32 (and 16); 416 = 26*16 = 13*32
#define NBH (NB*NH)             // 32
#define NROWS (NB*NL)           // 4096
#define NRTOT (NB*NH*NL)        // 65536
#define MTOT (NBH*NUP)          // 13312

typedef short bf16x8 __attribute__((ext_vector_type(8)));
typedef short bf16x4 __attribute__((ext_vector_type(4)));
typedef float f32x4  __attribute__((ext_vector_type(4)));

__device__ __forceinline__ short f2bf(float x) {   // RNE f32 -> bf16
  unsigned u = __float_as_uint(x);
  return (short)((u + 0x7FFFu + ((u >> 16) & 1u)) >> 16);
}
__device__ __forceinline__ float bf2f(short s) {
  return __uint_as_float(((unsigned)(unsigned short)s) << 16);
}

// ---------------------------------------------------------------- zero fill
__global__ __launch_bounds__(256) void zero_f4(float4* __restrict__ p) {
  const size_t i = (size_t)blockIdx.x * 256 + threadIdx.x;
  p[i] = make_float4(0.f, 0.f, 0.f, 0.f);
}

// ---------------------------------------------------------------- f32 GEMM
// C = A(MxK) * W(NxK)^T + bias.  GA: gather A from (B,H,L,D) ctx layout.
// SC: scatter C into (B,H,L,D) layout (col n -> h=n/64, d=n%64).
template<bool GA, bool SC>
__global__ __launch_bounds__(256) void gemm_f32_k(
    const float* __restrict__ A, const float* __restrict__ W,
    const float* __restrict__ bias, float* __restrict__ C,
    int M, int N, int K)
{
  __shared__ float As[64][16];   // [m][k]
  __shared__ float Ws[16][64];   // [k][n]
  const int tid = threadIdx.x;
  const int n0 = blockIdx.x << 6, m0 = blockIdx.y << 6;
  const int tx = tid & 15, ty = tid >> 4;
  const int lm = tid >> 2;            // 0..63 (row of tile)
  const int lk = (tid & 3) << 2;      // 0,4,8,12

  float4 a0 = {0,0,0,0}, a1 = {0,0,0,0}, a2 = {0,0,0,0}, a3 = {0,0,0,0};

  for (int k0 = 0; k0 < K; k0 += 16) {
    float4 av;
    if (GA) {
      const int gm = m0 + lm, gk = k0 + lk;
      const int bb = gm >> 11, ll = gm & (NL - 1);
      const int hh = gk >> 6,  dd = gk & 63;
      av = *(const float4*)(A + (((size_t)(bb*NH + hh)*NL + ll) << 6) + dd);
    } else {
      av = *(const float4*)(A + (size_t)(m0 + lm)*K + (k0 + lk));
    }
    *(float4*)&As[lm][lk] = av;
    const float4 wv = *(const float4*)(W + (size_t)(n0 + lm)*K + (k0 + lk));
    Ws[lk+0][lm] = wv.x; Ws[lk+1][lm] = wv.y;
    Ws[lk+2][lm] = wv.z; Ws[lk+3][lm] = wv.w;
    __syncthreads();
    #pragma unroll
    for (int k = 0; k < 16; ++k) {
      const float4 w4 = *(const float4*)&Ws[k][tx << 2];
      const float x0 = As[(ty<<2)+0][k];
      const float x1 = As[(ty<<2)+1][k];
      const float x2 = As[(ty<<2)+2][k];
      const float x3 = As[(ty<<2)+3][k];
      a0.x = fmaf(x0,w4.x,a0.x); a0.y = fmaf(x0,w4.y,a0.y);
      a0.z = fmaf(x0,w4.z,a0.z); a0.w = fmaf(x0,w4.w,a0.w);
      a1.x = fmaf(x1,w4.x,a1.x); a1.y = fmaf(x1,w4.y,a1.y);
      a1.z = fmaf(x1,w4.z,a1.z); a1.w = fmaf(x1,w4.w,a1.w);
      a2.x = fmaf(x2,w4.x,a2.x); a2.y = fmaf(x2,w4.y,a2.y);
      a2.z = fmaf(x2,w4.z,a2.z); a2.w = fmaf(x2,w4.w,a2.w);
      a3.x = fmaf(x3,w4.x,a3.x); a3.y = fmaf(x3,w4.y,a3.y);
      a3.z = fmaf(x3,w4.z,a3.z); a3.w = fmaf(x3,w4.w,a3.w);
    }
    __syncthreads();
  }

  const int col = n0 + (tx << 2);
  const float4 b4 = *(const float4*)(bias + col);
  float4 r[4] = {a0, a1, a2, a3};
  #pragma unroll
  for (int i = 0; i < 4; ++i) {
    r[i].x += b4.x; r[i].y += b4.y; r[i].z += b4.z; r[i].w += b4.w;
  }
  const int gm0 = m0 + (ty << 2);
  if (SC) {
    const int hh = col >> 6, dd = col & 63;
    #pragma unroll
    for (int i = 0; i < 4; ++i) {
      const int gm = gm0 + i, bb = gm >> 11, ll = gm & (NL - 1);
      *(float4*)(C + (((size_t)(bb*NH + hh)*NL + ll) << 6) + dd) = r[i];
    }
  } else {
    #pragma unroll
    for (int i = 0; i < 4; ++i)
      *(float4*)(C + (size_t)(gm0 + i)*N + col) = r[i];
  }
}

// ---------------------------------------------------------------- K row inv-norms
__global__ __launch_bounds__(256) void invnorm_k(const float* __restrict__ Kb,
                                                 float* __restrict__ invn) {
  const int r = blockIdx.x * 256 + threadIdx.x;
  const float4* p = (const float4*)(Kb + ((size_t)r << 6));
  double s = 0.0;
  #pragma unroll
  for (int i = 0; i < 16; ++i) {
    const float4 v = p[i];
    s += (double)v.x*v.x + (double)v.y*v.y + (double)v.z*v.z + (double)v.w*v.w;
  }
  invn[r] = (float)(1.0 / sqrt(s));
}

// ---------------------------------------------------------------- kbar = mean_l k_norm  (f64)
__global__ __launch_bounds__(64) void kbar_k(const float* __restrict__ Kb,
                                             const float* __restrict__ invn,
                                             double* __restrict__ kbar) {
  const int bh = blockIdx.x, d = threadIdx.x;
  const float* base = Kb + ((size_t)bh * NL << 6);
  const float* ib = invn + (size_t)bh * NL;
  double s = 0.0;
  for (int l = 0; l < NL; ++l)
    s += (double)base[(l << 6) + d] * (double)ib[l];
  kbar[(bh << 6) + d] = s * (1.0 / NL);
}

// ---------------------------------------------------------------- mean_scores = (q . kbar)/|q|  (f64)
__global__ __launch_bounds__(256) void ms_k(const float* __restrict__ Q,
                                            const double* __restrict__ kbar,
                                            float* __restrict__ ms) {
  __shared__ double kb[64];
  const int bh = blockIdx.x >> 3;              // 8 blocks of 256 rows per (b,h)
  if (threadIdx.x < 64) kb[threadIdx.x] = kbar[(bh << 6) + threadIdx.x];
  __syncthreads();
  const int r = blockIdx.x * 256 + threadIdx.x;
  const float* q = Q + ((size_t)r << 6);
  double dot = 0.0, ss = 0.0;
  #pragma unroll 16
  for (int i = 0; i < 64; ++i) {
    const double x = q[i];
    dot += x * kb[i];
    ss += x * x;
  }
  ms[r] = (float)(dot / sqrt(ss));
}

// ---------------------------------------------------------------- top-NU selection per (b,h)
__global__ __launch_bounds__(256) void select_k(const float* __restrict__ ms,
                                                int* __restrict__ sel) {
  __shared__ unsigned keys[NL];
  __shared__ int red[256];
  const int bh = blockIdx.x, tid = threadIdx.x;
  for (int l = tid; l < NL; l += 256) {
    const unsigned b = __float_as_uint(ms[(size_t)bh * NL + l]);
    keys[l] = (b & 0x80000000u) ? ~b : (b | 0x80000000u);   // order-preserving map
  }
  __syncthreads();
  unsigned lo = 0u, hi = 0xFFFFFFFFu;
  while (hi - lo > 1u) {           // invariant: count(>=lo) >= NU > count(>=hi)
    const unsigned mid = lo + ((hi - lo) >> 1);
    int c = 0;
    for (int l = tid; l < NL; l += 256) c += (keys[l] >= mid) ? 1 : 0;
    red[tid] = c; __syncthreads();
    for (int s = 128; s > 0; s >>= 1) {
      if (tid < s) red[tid] += red[tid + s];
      __syncthreads();
    }
    const int tot = red[0]; __syncthreads();
    if (tot >= NU) lo = mid; else hi = mid;
  }
  const unsigned V = lo;           // NU-th largest key
  int c = 0;
  for (int l = tid; l < NL; l += 256) c += (keys[l] > V) ? 1 : 0;
  red[tid] = c; __syncthreads();
  for (int s = 128; s > 0; s >>= 1) {
    if (tid < s) red[tid] += red[tid + s];
    __syncthreads();
  }
  const int g = red[0];
  if (tid == 0) {                  // ties broken by lowest index (matches lax.top_k)
    const int need = NU - g;
    int cnt = 0, t = 0;
    for (int l = 0; l < NL && cnt < NU; ++l) {
      const unsigned kk = keys[l];
      if (kk > V) sel[bh*NU + (cnt++)] = l;
      else if (kk == V && t < need) { sel[bh*NU + (cnt++)] = l; ++t; }
    }
  }
}

// ---------------------------------------------------------------- f32 -> bf16 elementwise (8/thread)
__global__ __launch_bounds__(256) void cvt_bf16_k(const float* __restrict__ in,
                                                  short* __restrict__ out, int n8) {
  const int i = blockIdx.x * 256 + threadIdx.x;
  if (i >= n8) return;
  const float4 a = ((const float4*)in)[2*i];
  const float4 b = ((const float4*)in)[2*i + 1];
  bf16x8 v;
  v[0]=f2bf(a.x); v[1]=f2bf(a.y); v[2]=f2bf(a.z); v[3]=f2bf(a.w);
  v[4]=f2bf(b.x); v[5]=f2bf(b.y); v[6]=f2bf(b.z); v[7]=f2bf(b.w);
  *(bf16x8*)(out + 8*(size_t)i) = v;
}

// ---------------------------------------------------------------- V (bh,l,d) f32 -> Vt (bh,d,l) bf16
__global__ __launch_bounds__(256) void transpose_v_k(const float* __restrict__ Vb,
                                                     short* __restrict__ Vt) {
  __shared__ float Ts[64][65];
  const int bh = blockIdx.x >> 5, lt = blockIdx.x & 31;   // 32 l-tiles of 64
  const int l0 = lt << 6, tid = threadIdx.x;
  const int lr = tid >> 2, j = tid & 3;
  const float* src = Vb + (((size_t)bh*NL + l0 + lr) << 6);
  #pragma unroll
  for (int s = 0; s < 4; ++s) {
    const float4 v = *(const float4*)(src + ((j + 4*s) << 2));
    Ts[lr][(j+4*s)*4+0] = v.x; Ts[lr][(j+4*s)*4+1] = v.y;
    Ts[lr][(j+4*s)*4+2] = v.z; Ts[lr][(j+4*s)*4+3] = v.w;
  }
  __syncthreads();
  const int d = tid >> 2, lc = (tid & 3) << 4;
  short* dst = Vt + ((size_t)bh*ND + d) * NL + l0 + lc;
  bf16x8 o0, o1;
  #pragma unroll
  for (int i = 0; i < 8; ++i) {
    o0[i] = f2bf(Ts[lc + i][d]);
    o1[i] = f2bf(Ts[lc + 8 + i][d]);
  }
  *(bf16x8*)dst = o0;
  *(bf16x8*)(dst + 8) = o1;
}

// ---------------------------------------------------------------- gather selected Q rows -> bf16 [MTOT][64]
__global__ __launch_bounds__(256) void gather_q_k(const float* __restrict__ Qb,
                                                  const int* __restrict__ sel,
                                                  short* __restrict__ Qg) {
  const int row = blockIdx.x * 4 + (threadIdx.x >> 6);    // grid = MTOT/4
  const int d = threadIdx.x & 63;
  const int bh = row / NUP, u = row - bh * NUP;
  float v = 0.f;
  if (u < NU) {
    const int lq = sel[bh*NU + u];
    v = Qb[(((size_t)bh*NL + lq) << 6) + d];
  }
  Qg[((size_t)row << 6) + d] = f2bf(v);
}

// ---------------------------------------------------------------- S = Qg * K^T  (bf16 MFMA, direct-global frags)
// grid (MTOT/64, NL/64); wave w handles 16 m-rows x 64 n-cols.
// mfma(A=K rows->n, B=Q rows->m): D col = m (lane&15), D rows = n (lane>>4)*4+reg.
__global__ __launch_bounds__(256) void sgemm_qk_k(const short* __restrict__ Qg,
                                                  const short* __restrict__ Kb,
                                                  short* __restrict__ S) {
  const int w = threadIdx.x >> 6, L = threadIdx.x & 63;
  const int m0 = (blockIdx.x << 6) + (w << 4);
  const int n0 = blockIdx.y << 6;
  const int bh = m0 / NUP;                     // 416 % 16 == 0: uniform per 16-row subtile
  const int lr = L & 15, lg = L >> 4;

  const short* qp = Qg + (((size_t)m0 + lr) << 6) + lg*8;
  const bf16x8 qf0 = *(const bf16x8*)qp;
  const bf16x8 qf1 = *(const bf16x8*)(qp + 32);

  const short* kbase = Kb + (((size_t)bh*NL + n0 + lr) << 6) + lg*8;
  f32x4 acc[4];
  #pragma unroll
  for (int nt = 0; nt < 4; ++nt) {
    const short* kp = kbase + ((size_t)nt << 10);   // 16 rows * 64
    const bf16x8 kf0 = *(const bf16x8*)kp;
    const bf16x8 kf1 = *(const bf16x8*)(kp + 32);
    f32x4 a = {0.f,0.f,0.f,0.f};
    a = __builtin_amdgcn_mfma_f32_16x16x32_bf16(kf0, qf0, a, 0, 0, 0);
    a = __builtin_amdgcn_mfma_f32_16x16x32_bf16(kf1, qf1, a, 0, 0, 0);
    acc[nt] = a;
  }
  short* sp = S + ((size_t)m0 + lr) * NL + n0 + lg*4;
  #pragma unroll
  for (int nt = 0; nt < 4; ++nt) {
    bf16x4 o;
    o[0]=f2bf(acc[nt][0]); o[1]=f2bf(acc[nt][1]);
    o[2]=f2bf(acc[nt][2]); o[3]=f2bf(acc[nt][3]);
    *(bf16x4*)(sp + nt*16) = o;
  }
}

// ---------------------------------------------------------------- row softmax, in place, scale 1/8
__global__ __launch_bounds__(256) void softmax_k(short* __restrict__ S) {
  __shared__ float red[4];
  const int tid = threadIdx.x;
  short* sp = S + (size_t)blockIdx.x * NL + tid*8;
  const bf16x8 v = *(const bf16x8*)sp;
  float f[8];
  #pragma unroll
  for (int i = 0; i < 8; ++i) f[i] = bf2f(v[i]) * 0.125f;
  float m = f[0];
  #pragma unroll
  for (int i = 1; i < 8; ++i) m = fmaxf(m, f[i]);
  #pragma unroll
  for (int off = 32; off > 0; off >>= 1) m = fmaxf(m, __shfl_xor(m, off));
  if ((tid & 63) == 0) red[tid >> 6] = m;
  __syncthreads();
  const float gm = fmaxf(fmaxf(red[0], red[1]), fmaxf(red[2], red[3]));
  __syncthreads();
  float s = 0.f;
  #pragma unroll
  for (int i = 0; i < 8; ++i) { f[i] = __expf(f[i] - gm); s += f[i]; }
  #pragma unroll
  for (int off = 32; off > 0; off >>= 1) s += __shfl_xor(s, off);
  if ((tid & 63) == 0) red[tid >> 6] = s;
  __syncthreads();
  const float inv = 1.f / (red[0] + red[1] + red[2] + red[3]);
  bf16x8 o;
  #pragma unroll
  for (int i = 0; i < 8; ++i) o[i] = f2bf(f[i] * inv);
  *(bf16x8*)sp = o;
}

// ---------------------------------------------------------------- Csel = P * V  (bf16 MFMA)
// grid MTOT/32; wave w: m-sub (w&1), d0 = (w>>1)*32 (two 16-d tiles), full K=2048.
// mfma(A=P rows->m, B=Vt rows->d): D col = d, rows = m.
__global__ __launch_bounds__(256) void pgemm_pv_k(const short* __restrict__ P,
                                                  const short* __restrict__ Vt,
                                                  float* __restrict__ Csel) {
  const int w = threadIdx.x >> 6, L = threadIdx.x & 63;
  const int m0 = blockIdx.x << 5;
  const int bh = m0 / NUP;                     // 416 % 32 == 0: uniform per block
  const int mt = w & 1, d0 = (w >> 1) << 5;
  const int lr = L & 15, lg = L >> 4;

  const short* prow = P + ((size_t)m0 + mt*16 + lr) * NL + lg*8;
  const short* v0 = Vt + ((size_t)bh*ND + d0 + lr) * NL + lg*8;
  const short* v1 = v0 + (size_t)16 * NL;

  f32x4 acc0 = {0.f,0.f,0.f,0.f}, acc1 = {0.f,0.f,0.f,0.f};
  for (int k = 0; k < NL; k += 32) {
    const bf16x8 pf  = *(const bf16x8*)(prow + k);
    const bf16x8 vf0 = *(const bf16x8*)(v0 + k);
    const bf16x8 vf1 = *(const bf16x8*)(v1 + k);
    acc0 = __builtin_amdgcn_mfma_f32_16x16x32_bf16(pf, vf0, acc0, 0, 0, 0);
    acc1 = __builtin_amdgcn_mfma_f32_16x16x32_bf16(pf, vf1, acc1, 0, 0, 0);
  }
  float* c = Csel + (((size_t)m0 + mt*16 + lg*4) << 6);
  #pragma unroll
  for (int r = 0; r < 4; ++r) {
    c[(size_t)(r << 6) + d0 + lr]      = acc0[r];
    c[(size_t)(r << 6) + d0 + 16 + lr] = acc1[r];
  }
}

// ---------------------------------------------------------------- scatter Csel -> CTX at sel rows
__global__ __launch_bounds__(256) void scatter_ctx_k(const float* __restrict__ Csel,
                                                     const int* __restrict__ sel,
                                                     float* __restrict__ CTX) {
  const int r = blockIdx.x * 4 + (threadIdx.x >> 6);   // over NBH*NU = 13088 rows
  const int d = threadIdx.x & 63;
  if (r >= NBH * NU) return;
  const int bh = r / NU, u = r - bh * NU;
  const int lq = sel[bh*NU + u];
  CTX[(((size_t)bh*NL + lq) << 6) + d] = Csel[(((size_t)bh*NUP + u) << 6) + d];
}

// ---------------------------------------------------------------- launch
extern "C" void kernel_launch(void* const* d_in, const int* in_sizes, int n_in,
                              void* d_out, int out_size, void* d_ws, size_t ws_size,
                              hipStream_t stream)
{
  (void)in_sizes; (void)n_in; (void)out_size; (void)ws_size;
  const float* queries = (const float*)d_in[0];
  const float* keys    = (const float*)d_in[1];
  const float* values  = (const float*)d_in[2];
  const float* Wq = (const float*)d_in[3];  const float* bq = (const float*)d_in[4];
  const float* Wk = (const float*)d_in[5];  const float* bk = (const float*)d_in[6];
  const float* Wv = (const float*)d_in[7];  const float* bv = (const float*)d_in[8];
  const float* Wo = (const float*)d_in[9];  const float* bo = (const float*)d_in[10];
  float* out = (float*)d_out;

  char* w = (char*)d_ws;
  const size_t fsz = (size_t)NRTOT * ND * sizeof(float);       // 16.78 MB
  // Sbf (54.5 MB) aliases [Qb | Kbuf | Vbuf | head of CTX]; all four dead (or
  // not-yet-live, for CTX) during the S/softmax/P phase. CTX is zeroed AFTER
  // pgemm_pv_k has consumed Sbf.
  float*  Qb   = (float*)w;               // w + 0
  float*  Kbuf = (float*)(w + fsz);
  float*  Vbuf = (float*)(w + 2*fsz);
  float*  CTX  = (float*)(w + 3*fsz);
  short*  Sbf  = (short*)w;               // MTOT*NL bf16 = 54.5 MB (< 4*fsz)
  char* p = w + 4*fsz;
  float*  invn = (float*)p;  p += (size_t)NRTOT * sizeof(float);
  double* kbar = (double*)p; p += (size_t)NBH * ND * sizeof(double);
  float*  msb  = (float*)p;  p += (size_t)NRTOT * sizeof(float);
  int*    sel  = (int*)p;    p += (size_t)NBH * NU * sizeof(int);
  p = (char*)(((size_t)p + 255) & ~(size_t)255);
  short*  Kbf  = (short*)p;  p += (size_t)NRTOT * ND * sizeof(short);   // 8.4 MB
  short*  Vt   = (short*)p;  p += (size_t)NRTOT * ND * sizeof(short);   // 8.4 MB
  short*  Qg   = (short*)p;  p += (size_t)MTOT * ND * sizeof(short);    // 1.7 MB
  float*  Csel = (float*)p;  p += (size_t)MTOT * ND * sizeof(float);    // 3.4 MB

  const dim3 gg(NDM / 64, NROWS / 64);

  // ---- projections (f32, exact path for ranking)
  gemm_f32_k<false, true><<<gg, 256, 0, stream>>>(queries, Wq, bq, Qb,   NROWS, NDM, NDM);
  gemm_f32_k<false, true><<<gg, 256, 0, stream>>>(keys,    Wk, bk, Kbuf, NROWS, NDM, NDM);
  gemm_f32_k<false, true><<<gg, 256, 0, stream>>>(values,  Wv, bv, Vbuf, NROWS, NDM, NDM);

  // ---- ranking + selection (f64 accumulation, unchanged)
  invnorm_k<<<NRTOT / 256, 256, 0, stream>>>(Kbuf, invn);
  kbar_k<<<NBH, 64, 0, stream>>>(Kbuf, invn, kbar);
  ms_k<<<NRTOT / 256, 256, 0, stream>>>(Qb, kbar, msb);
  select_k<<<NBH, 256, 0, stream>>>(msb, sel);

  // ---- bf16 operand prep (Kbuf/Vbuf/Qb die here; Sbf may then alias them)
  cvt_bf16_k<<<(NRTOT*ND/8 + 255)/256, 256, 0, stream>>>(Kbuf, Kbf, NRTOT*ND/8);
  transpose_v_k<<<NBH * 32, 256, 0, stream>>>(Vbuf, Vt);
  gather_q_k<<<MTOT / 4, 256, 0, stream>>>(Qb, sel, Qg);

  // ---- attention as three GEMM-shaped passes (bf16 MFMA)
  sgemm_qk_k<<<dim3(MTOT/64, NL/64), 256, 0, stream>>>(Qg, Kbf, Sbf);
  softmax_k<<<MTOT, 256, 0, stream>>>(Sbf);
  pgemm_pv_k<<<MTOT / 32, 256, 0, stream>>>(Sbf, Vt, Csel);

  // ---- scatter into zeroed CTX (after Sbf is dead), then output projection
  zero_f4<<<(NRTOT * ND / 4) / 256, 256, 0, stream>>>((float4*)CTX);
  scatter_ctx_k<<<(NBH*NU + 3) / 4, 256, 0, stream>>>(Csel, sel, CTX);
  gemm_f32_k<true, false><<<gg, 256, 0, stream>>>(CTX, Wo, bo, out, NROWS, NDM, NDM);
}

// Round 3
// 776.600 us; speedup vs baseline: 3.4632x; 1.2362x over previous
//
#include <hip/hip_runtime.h>
#include <math.h>

// Problem constants (fixed by setup_inputs)
#define NB 2
#define NL 2048
#define NH 16
#define ND 64
#define NDM 1024
#define NU 409                  // max(1, 2048 // 5)
#define NUP 416                 // NU padded to multiple of 32; 416 = 26*16 = 13*32
#define NBH (NB*NH)             // 32
#define NROWS (NB*NL)           // 4096
#define NRTOT (NB*NH*NL)        // 65536
#define MTOT (NBH*NUP)          // 13312

typedef short bf16x8 __attribute__((ext_vector_type(8)));
typedef short bf16x4 __attribute__((ext_vector_type(4)));
typedef float f32x4  __attribute__((ext_vector_type(4)));

__device__ __forceinline__ short f2bf(float x) {   // RNE f32 -> bf16
  unsigned u = __float_as_uint(x);
  return (short)((u + 0x7FFFu + ((u >> 16) & 1u)) >> 16);
}
__device__ __forceinline__ float bf2f(short s) {
  return __uint_as_float(((unsigned)(unsigned short)s) << 16);
}

// ---------------------------------------------------------------- zero fill
__global__ __launch_bounds__(256) void zero_f4(float4* __restrict__ p) {
  const size_t i = (size_t)blockIdx.x * 256 + threadIdx.x;
  p[i] = make_float4(0.f, 0.f, 0.f, 0.f);
}

// ---------------------------------------------------------------- f32 -> NC bf16 split components
// a = hi, b = bf16(x - hi), c = bf16(x - hi - mid). Residual ~2^-27*|x| for NC=3.
template<int NC>
__global__ __launch_bounds__(256) void split_k(const float* __restrict__ in,
                                               short* __restrict__ a,
                                               short* __restrict__ b,
                                               short* __restrict__ c) {
  const size_t i = (size_t)blockIdx.x * 256 + threadIdx.x;
  const float4 x0 = ((const float4*)in)[2*i];
  const float4 x1 = ((const float4*)in)[2*i + 1];
  float x[8] = {x0.x,x0.y,x0.z,x0.w, x1.x,x1.y,x1.z,x1.w};
  bf16x8 va, vb, vc;
  #pragma unroll
  for (int j = 0; j < 8; ++j) {
    const short A = f2bf(x[j]);
    const float r1 = x[j] - bf2f(A);
    const short B = f2bf(r1);
    va[j] = A; vb[j] = B;
    if (NC == 3) vc[j] = f2bf(r1 - bf2f(B));
  }
  *(bf16x8*)(a + 8*i) = va;
  *(bf16x8*)(b + 8*i) = vb;
  if (NC == 3) *(bf16x8*)(c + 8*i) = vc;
}

// ---------------------------------------------------------------- split-bf16 MFMA GEMM
// C[m,n] = bias[n] + sum_k X[m,k]*W[n,k], X ~ Xa+Xb(+Xc), W ~ Wa+Wb(+Wc).
// NPROD=6: AA'+AB'+BA'+AC'+CA'+BB' (~f32 precision). NPROD=3: AA'+AB'+BA'.
// M=4096, N=K=1024. Block 128m x 64n (4 waves on m), wave 32m x 64n.
// MFMA 16x16x32: A-op = W rows (n -> D-row), B-op = X rows (m -> D-col).
template<int NPROD, bool SC>
__global__ __launch_bounds__(256) void gemm_split_k(
    const short* __restrict__ Xa, const short* __restrict__ Xb, const short* __restrict__ Xc,
    const short* __restrict__ Wa, const short* __restrict__ Wb, const short* __restrict__ Wc,
    const float* __restrict__ bias, float* __restrict__ C)
{
  const int wv = threadIdx.x >> 6, L = threadIdx.x & 63;
  const int lr = L & 15, lg = L >> 4;
  const int m0 = (blockIdx.x << 7) + (wv << 5);
  const int n0 = blockIdx.y << 6;

  const size_t xo0 = ((size_t)(m0 + lr) << 10) + (lg << 3);
  const size_t xo1 = xo0 + (16 << 10);
  const size_t wob = ((size_t)(n0 + lr) << 10) + (lg << 3);

  f32x4 acc[2][4];
  #pragma unroll
  for (int i = 0; i < 2; ++i)
    #pragma unroll
    for (int j = 0; j < 4; ++j) acc[i][j] = (f32x4){0.f,0.f,0.f,0.f};

  for (int k0 = 0; k0 < NDM; k0 += 32) {
    const bf16x8 xa0 = *(const bf16x8*)(Xa + xo0 + k0);
    const bf16x8 xa1 = *(const bf16x8*)(Xa + xo1 + k0);
    const bf16x8 xb0 = *(const bf16x8*)(Xb + xo0 + k0);
    const bf16x8 xb1 = *(const bf16x8*)(Xb + xo1 + k0);
    bf16x8 xc0, xc1;
    if constexpr (NPROD == 6) {
      xc0 = *(const bf16x8*)(Xc + xo0 + k0);
      xc1 = *(const bf16x8*)(Xc + xo1 + k0);
    }
    #pragma unroll
    for (int nt = 0; nt < 4; ++nt) {
      const size_t wo = wob + ((size_t)nt << 14) + k0;
      const bf16x8 wa = *(const bf16x8*)(Wa + wo);
      const bf16x8 wb = *(const bf16x8*)(Wb + wo);
      acc[0][nt] = __builtin_amdgcn_mfma_f32_16x16x32_bf16(wa, xa0, acc[0][nt], 0, 0, 0);
      acc[1][nt] = __builtin_amdgcn_mfma_f32_16x16x32_bf16(wa, xa1, acc[1][nt], 0, 0, 0);
      acc[0][nt] = __builtin_amdgcn_mfma_f32_16x16x32_bf16(wa, xb0, acc[0][nt], 0, 0, 0);
      acc[1][nt] = __builtin_amdgcn_mfma_f32_16x16x32_bf16(wa, xb1, acc[1][nt], 0, 0, 0);
      acc[0][nt] = __builtin_amdgcn_mfma_f32_16x16x32_bf16(wb, xa0, acc[0][nt], 0, 0, 0);
      acc[1][nt] = __builtin_amdgcn_mfma_f32_16x16x32_bf16(wb, xa1, acc[1][nt], 0, 0, 0);
      if constexpr (NPROD == 6) {
        const bf16x8 wc = *(const bf16x8*)(Wc + wo);
        acc[0][nt] = __builtin_amdgcn_mfma_f32_16x16x32_bf16(wa, xc0, acc[0][nt], 0, 0, 0);
        acc[1][nt] = __builtin_amdgcn_mfma_f32_16x16x32_bf16(wa, xc1, acc[1][nt], 0, 0, 0);
        acc[0][nt] = __builtin_amdgcn_mfma_f32_16x16x32_bf16(wc, xa0, acc[0][nt], 0, 0, 0);
        acc[1][nt] = __builtin_amdgcn_mfma_f32_16x16x32_bf16(wc, xa1, acc[1][nt], 0, 0, 0);
        acc[0][nt] = __builtin_amdgcn_mfma_f32_16x16x32_bf16(wb, xb0, acc[0][nt], 0, 0, 0);
        acc[1][nt] = __builtin_amdgcn_mfma_f32_16x16x32_bf16(wb, xb1, acc[1][nt], 0, 0, 0);
      }
    }
  }

  #pragma unroll
  for (int nt = 0; nt < 4; ++nt) {
    const int nb = n0 + (nt << 4) + (lg << 2);
    const float4 b4 = *(const float4*)(bias + nb);
    #pragma unroll
    for (int mt = 0; mt < 2; ++mt) {
      f32x4 a = acc[mt][nt];
      a[0] += b4.x; a[1] += b4.y; a[2] += b4.z; a[3] += b4.w;
      const int m = m0 + (mt << 4) + lr;
      if (SC) {   // scatter into (B,H,L,D)
        const int bb = m >> 11, ll = m & (NL - 1);
        const int hh = nb >> 6, dd = nb & 63;
        *(f32x4*)(C + (((size_t)(bb*NH + hh)*NL + ll) << 6) + dd) = a;
      } else {
        *(f32x4*)(C + ((size_t)m << 10) + nb) = a;
      }
    }
  }
}

// ---------------------------------------------------------------- K row inv-norms
__global__ __launch_bounds__(256) void invnorm_k(const float* __restrict__ Kb,
                                                 float* __restrict__ invn) {
  const int r = blockIdx.x * 256 + threadIdx.x;
  const float4* p = (const float4*)(Kb + ((size_t)r << 6));
  double s = 0.0;
  #pragma unroll
  for (int i = 0; i < 16; ++i) {
    const float4 v = p[i];
    s += (double)v.x*v.x + (double)v.y*v.y + (double)v.z*v.z + (double)v.w*v.w;
  }
  invn[r] = (float)(1.0 / sqrt(s));
}

// ---------------------------------------------------------------- kbar = mean_l k_norm  (f64)
__global__ __launch_bounds__(256) void kbar_k(const float* __restrict__ Kb,
                                              const float* __restrict__ invn,
                                              double* __restrict__ kbar) {
  __shared__ double part[4][64];
  const int bh = blockIdx.x, tid = threadIdx.x;
  const int d = tid & 63, g = tid >> 6;
  const float* base = Kb + ((size_t)bh * NL << 6);
  const float* ib = invn + (size_t)bh * NL;
  double s = 0.0;
  for (int l = g; l < NL; l += 4)
    s += (double)base[((size_t)l << 6) + d] * (double)ib[l];
  part[g][d] = s;
  __syncthreads();
  if (tid < 64)
    kbar[(bh << 6) + tid] =
        (part[0][tid] + part[1][tid] + part[2][tid] + part[3][tid]) * (1.0 / NL);
}

// ---------------------------------------------------------------- mean_scores = (q . kbar)/|q|  (f64)
__global__ __launch_bounds__(256) void ms_k(const float* __restrict__ Q,
                                            const double* __restrict__ kbar,
                                            float* __restrict__ ms) {
  __shared__ double kb[64];
  const int bh = blockIdx.x >> 3;
  if (threadIdx.x < 64) kb[threadIdx.x] = kbar[(bh << 6) + threadIdx.x];
  __syncthreads();
  const int r = blockIdx.x * 256 + threadIdx.x;
  const float* q = Q + ((size_t)r << 6);
  double dot = 0.0, ss = 0.0;
  #pragma unroll 16
  for (int i = 0; i < 64; ++i) {
    const double x = q[i];
    dot += x * kb[i];
    ss += x * x;
  }
  ms[r] = (float)(dot / sqrt(ss));
}

// ---------------------------------------------------------------- rank-based top-NU selection
// Strict total order (value desc, index asc) via 64-bit composite key; exact
// rank by counting; identical set to lax.top_k. 8 blocks per (b,h).
__global__ __launch_bounds__(256) void select_rank_k(const float* __restrict__ ms,
                                                     int* __restrict__ sel) {
  __shared__ unsigned long long keys[NL];
  const int bh = blockIdx.x >> 3, seg = blockIdx.x & 7;
  const int tid = threadIdx.x;
  for (int l = tid; l < NL; l += 256) {
    unsigned u = __float_as_uint(ms[(size_t)bh * NL + l]);
    u = (u & 0x80000000u) ? ~u : (u | 0x80000000u);   // order-preserving map
    keys[l] = ((unsigned long long)u << 32) | (unsigned)(NL - 1 - l);
  }
  __syncthreads();
  const int r = (seg << 8) + tid;
  const unsigned long long mine = keys[r];
  int cnt = 0;
  #pragma unroll 8
  for (int l = 0; l < NL; ++l) cnt += (keys[l] > mine) ? 1 : 0;
  if (cnt < NU) sel[bh*NU + cnt] = r;
}

// ---------------------------------------------------------------- f32 -> bf16 elementwise (8/thread)
__global__ __launch_bounds__(256) void cvt_bf16_k(const float* __restrict__ in,
                                                  short* __restrict__ out, int n8) {
  const int i = blockIdx.x * 256 + threadIdx.x;
  if (i >= n8) return;
  const float4 a = ((const float4*)in)[2*i];
  const float4 b = ((const float4*)in)[2*i + 1];
  bf16x8 v;
  v[0]=f2bf(a.x); v[1]=f2bf(a.y); v[2]=f2bf(a.z); v[3]=f2bf(a.w);
  v[4]=f2bf(b.x); v[5]=f2bf(b.y); v[6]=f2bf(b.z); v[7]=f2bf(b.w);
  *(bf16x8*)(out + 8*(size_t)i) = v;
}

// ---------------------------------------------------------------- V (bh,l,d) f32 -> Vt (bh,d,l) bf16
__global__ __launch_bounds__(256) void transpose_v_k(const float* __restrict__ Vb,
                                                     short* __restrict__ Vt) {
  __shared__ float Ts[64][65];
  const int bh = blockIdx.x >> 5, lt = blockIdx.x & 31;
  const int l0 = lt << 6, tid = threadIdx.x;
  const int lr = tid >> 2, j = tid & 3;
  const float* src = Vb + (((size_t)bh*NL + l0 + lr) << 6);
  #pragma unroll
  for (int s = 0; s < 4; ++s) {
    const float4 v = *(const float4*)(src + ((j + 4*s) << 2));
    Ts[lr][(j+4*s)*4+0] = v.x; Ts[lr][(j+4*s)*4+1] = v.y;
    Ts[lr][(j+4*s)*4+2] = v.z; Ts[lr][(j+4*s)*4+3] = v.w;
  }
  __syncthreads();
  const int d = tid >> 2, lc = (tid & 3) << 4;
  short* dst = Vt + ((size_t)bh*ND + d) * NL + l0 + lc;
  bf16x8 o0, o1;
  #pragma unroll
  for (int i = 0; i < 8; ++i) {
    o0[i] = f2bf(Ts[lc + i][d]);
    o1[i] = f2bf(Ts[lc + 8 + i][d]);
  }
  *(bf16x8*)dst = o0;
  *(bf16x8*)(dst + 8) = o1;
}

// ---------------------------------------------------------------- gather selected Q rows -> bf16 [MTOT][64]
__global__ __launch_bounds__(256) void gather_q_k(const float* __restrict__ Qb,
                                                  const int* __restrict__ sel,
                                                  short* __restrict__ Qg) {
  const int row = blockIdx.x * 4 + (threadIdx.x >> 6);
  const int d = threadIdx.x & 63;
  const int bh = row / NUP, u = row - bh * NUP;
  float v = 0.f;
  if (u < NU) {
    const int lq = sel[bh*NU + u];
    v = Qb[(((size_t)bh*NL + lq) << 6) + d];
  }
  Qg[((size_t)row << 6) + d] = f2bf(v);
}

// ---------------------------------------------------------------- S = Qg * K^T  (bf16 MFMA)
__global__ __launch_bounds__(256) void sgemm_qk_k(const short* __restrict__ Qg,
                                                  const short* __restrict__ Kb,
                                                  short* __restrict__ S) {
  const int w = threadIdx.x >> 6, L = threadIdx.x & 63;
  const int m0 = (blockIdx.x << 6) + (w << 4);
  const int n0 = blockIdx.y << 6;
  const int bh = m0 / NUP;
  const int lr = L & 15, lg = L >> 4;

  const short* qp = Qg + (((size_t)m0 + lr) << 6) + lg*8;
  const bf16x8 qf0 = *(const bf16x8*)qp;
  const bf16x8 qf1 = *(const bf16x8*)(qp + 32);

  const short* kbase = Kb + (((size_t)bh*NL + n0 + lr) << 6) + lg*8;
  f32x4 acc[4];
  #pragma unroll
  for (int nt = 0; nt < 4; ++nt) {
    const short* kp = kbase + ((size_t)nt << 10);
    const bf16x8 kf0 = *(const bf16x8*)kp;
    const bf16x8 kf1 = *(const bf16x8*)(kp + 32);
    f32x4 a = {0.f,0.f,0.f,0.f};
    a = __builtin_amdgcn_mfma_f32_16x16x32_bf16(kf0, qf0, a, 0, 0, 0);
    a = __builtin_amdgcn_mfma_f32_16x16x32_bf16(kf1, qf1, a, 0, 0, 0);
    acc[nt] = a;
  }
  short* sp = S + ((size_t)m0 + lr) * NL + n0 + lg*4;
  #pragma unroll
  for (int nt = 0; nt < 4; ++nt) {
    bf16x4 o;
    o[0]=f2bf(acc[nt][0]); o[1]=f2bf(acc[nt][1]);
    o[2]=f2bf(acc[nt][2]); o[3]=f2bf(acc[nt][3]);
    *(bf16x4*)(sp + nt*16) = o;
  }
}

// ---------------------------------------------------------------- row softmax, in place, scale 1/8
__global__ __launch_bounds__(256) void softmax_k(short* __restrict__ S) {
  __shared__ float red[4];
  const int tid = threadIdx.x;
  short* sp = S + (size_t)blockIdx.x * NL + tid*8;
  const bf16x8 v = *(const bf16x8*)sp;
  float f[8];
  #pragma unroll
  for (int i = 0; i < 8; ++i) f[i] = bf2f(v[i]) * 0.125f;
  float m = f[0];
  #pragma unroll
  for (int i = 1; i < 8; ++i) m = fmaxf(m, f[i]);
  #pragma unroll
  for (int off = 32; off > 0; off >>= 1) m = fmaxf(m, __shfl_xor(m, off));
  if ((tid & 63) == 0) red[tid >> 6] = m;
  __syncthreads();
  const float gm = fmaxf(fmaxf(red[0], red[1]), fmaxf(red[2], red[3]));
  __syncthreads();
  float s = 0.f;
  #pragma unroll
  for (int i = 0; i < 8; ++i) { f[i] = __expf(f[i] - gm); s += f[i]; }
  #pragma unroll
  for (int off = 32; off > 0; off >>= 1) s += __shfl_xor(s, off);
  if ((tid & 63) == 0) red[tid >> 6] = s;
  __syncthreads();
  const float inv = 1.f / (red[0] + red[1] + red[2] + red[3]);
  bf16x8 o;
  #pragma unroll
  for (int i = 0; i < 8; ++i) o[i] = f2bf(f[i] * inv);
  *(bf16x8*)sp = o;
}

// ---------------------------------------------------------------- Csel = P * V  (bf16 MFMA)
__global__ __launch_bounds__(256) void pgemm_pv_k(const short* __restrict__ P,
                                                  const short* __restrict__ Vt,
                                                  float* __restrict__ Csel) {
  const int w = threadIdx.x >> 6, L = threadIdx.x & 63;
  const int m0 = blockIdx.x << 5;
  const int bh = m0 / NUP;
  const int mt = w & 1, d0 = (w >> 1) << 5;
  const int lr = L & 15, lg = L >> 4;

  const short* prow = P + ((size_t)m0 + mt*16 + lr) * NL + lg*8;
  const short* v0 = Vt + ((size_t)bh*ND + d0 + lr) * NL + lg*8;
  const short* v1 = v0 + (size_t)16 * NL;

  f32x4 acc0 = {0.f,0.f,0.f,0.f}, acc1 = {0.f,0.f,0.f,0.f};
  for (int k = 0; k < NL; k += 32) {
    const bf16x8 pf  = *(const bf16x8*)(prow + k);
    const bf16x8 vf0 = *(const bf16x8*)(v0 + k);
    const bf16x8 vf1 = *(const bf16x8*)(v1 + k);
    acc0 = __builtin_amdgcn_mfma_f32_16x16x32_bf16(pf, vf0, acc0, 0, 0, 0);
    acc1 = __builtin_amdgcn_mfma_f32_16x16x32_bf16(pf, vf1, acc1, 0, 0, 0);
  }
  float* c = Csel + (((size_t)m0 + mt*16 + lg*4) << 6);
  #pragma unroll
  for (int r = 0; r < 4; ++r) {
    c[(size_t)(r << 6) + d0 + lr]      = acc0[r];
    c[(size_t)(r << 6) + d0 + 16 + lr] = acc1[r];
  }
}

// ---------------------------------------------------------------- scatter+split Csel rows into zeroed Cta/Ctb
__global__ __launch_bounds__(256) void scatter_split2_k(const float* __restrict__ Csel,
                                                        const int* __restrict__ sel,
                                                        short* __restrict__ Ca,
                                                        short* __restrict__ Cb) {
  const int r = blockIdx.x * 4 + (threadIdx.x >> 6);
  const int d = threadIdx.x & 63;
  if (r >= NBH * NU) return;
  const int bh = r / NU, u = r - bh * NU;
  const int b = bh >> 4, h = bh & 15;
  const int lq = sel[bh*NU + u];
  const float x = Csel[(((size_t)bh*NUP + u) << 6) + d];
  const short A = f2bf(x);
  const size_t o = ((((size_t)b << 11) + lq) << 10) + (h << 6) + d;
  Ca[o] = A;
  Cb[o] = f2bf(x - bf2f(A));
}

// ---------------------------------------------------------------- launch
extern "C" void kernel_launch(void* const* d_in, const int* in_sizes, int n_in,
                              void* d_out, int out_size, void* d_ws, size_t ws_size,
                              hipStream_t stream)
{
  (void)in_sizes; (void)n_in; (void)out_size; (void)ws_size;
  const float* queries = (const float*)d_in[0];
  const float* keys    = (const float*)d_in[1];
  const float* values  = (const float*)d_in[2];
  const float* Wq = (const float*)d_in[3];  const float* bq = (const float*)d_in[4];
  const float* Wk = (const float*)d_in[5];  const float* bk = (const float*)d_in[6];
  const float* Wv = (const float*)d_in[7];  const float* bv = (const float*)d_in[8];
  const float* Wo = (const float*)d_in[9];  const float* bo = (const float*)d_in[10];
  float* out = (float*)d_out;

  const size_t fsz  = (size_t)NRTOT * ND * sizeof(float);     // 16.78 MB
  const size_t hsz  = (size_t)NRTOT * ND * sizeof(short);     // 8.39 MB
  const size_t wsz  = (size_t)NDM * NDM * sizeof(short);      // 2.10 MB

  // Region A (55 MB): Qb|Kbuf|Vbuf -> then Sbf -> then Cta|Ctb
  char* A = (char*)d_ws;
  float* Qb   = (float*)A;
  float* Kbuf = (float*)(A + fsz);
  float* Vbuf = (float*)(A + 2*fsz);
  short* Sbf  = (short*)A;                       // MTOT*NL bf16 = 54.5 MB
  short* Cta  = (short*)A;                       // after Sbf dead
  short* Ctb  = (short*)(A + hsz);
  // Region B (26 MB): X split scratch -> then Kbf/Vt/Qg/Csel
  char* Br = A + ((size_t)55 << 20);
  short* Xa = (short*)Br;
  short* Xb = (short*)(Br + hsz);
  short* Xc = (short*)(Br + 2*hsz);
  short* Kbf  = (short*)Br;
  short* Vt   = (short*)(Br + hsz);
  short* Qg   = (short*)(Br + 2*hsz);                          // 1.70 MB
  float* Csel = (float*)(Br + 2*hsz + (size_t)MTOT*ND*sizeof(short));
  // Region C: W splits + smalls
  char* Cr = Br + ((size_t)26 << 20);
  short* Wsa = (short*)Cr;
  short* Wsb = (short*)(Cr + wsz);
  short* Wsc = (short*)(Cr + 2*wsz);
  short* Woa = (short*)(Cr + 3*wsz);
  short* Wob = (short*)(Cr + 4*wsz);
  char* Sm = Cr + 5*wsz;
  float*  invn = (float*)Sm;   Sm += (size_t)NRTOT * sizeof(float);
  double* kbar = (double*)Sm;  Sm += (size_t)NBH * ND * sizeof(double);
  float*  msb  = (float*)Sm;   Sm += (size_t)NRTOT * sizeof(float);
  int*    sel  = (int*)Sm;

  const dim3 gsp(NROWS/128, NDM/64);   // (32,16)
  const int NX8 = NROWS*NDM/8/256;     // 2048 blocks for 4M-elem split
  const int NW8 = NDM*NDM/8/256;       // 512 blocks for 1M-elem split

  // persistent Wo split (2-way)
  split_k<2><<<NW8, 256, 0, stream>>>(Wo, Woa, Wob, nullptr);

  // ---- Q projection (6-product split, ~f32 precision)
  split_k<3><<<NX8, 256, 0, stream>>>(queries, Xa, Xb, Xc);
  split_k<3><<<NW8, 256, 0, stream>>>(Wq, Wsa, Wsb, Wsc);
  gemm_split_k<6, true><<<gsp, 256, 0, stream>>>(Xa,Xb,Xc, Wsa,Wsb,Wsc, bq, Qb);
  // ---- K projection
  split_k<3><<<NX8, 256, 0, stream>>>(keys, Xa, Xb, Xc);
  split_k<3><<<NW8, 256, 0, stream>>>(Wk, Wsa, Wsb, Wsc);
  gemm_split_k<6, true><<<gsp, 256, 0, stream>>>(Xa,Xb,Xc, Wsa,Wsb,Wsc, bk, Kbuf);
  // ---- V projection (3-product split)
  split_k<2><<<NX8, 256, 0, stream>>>(values, Xa, Xb, nullptr);
  split_k<2><<<NW8, 256, 0, stream>>>(Wv, Wsa, Wsb, nullptr);
  gemm_split_k<3, true><<<gsp, 256, 0, stream>>>(Xa,Xb,nullptr, Wsa,Wsb,nullptr, bv, Vbuf);

  // ---- ranking + selection
  invnorm_k<<<NRTOT/256, 256, 0, stream>>>(Kbuf, invn);
  kbar_k<<<NBH, 256, 0, stream>>>(Kbuf, invn, kbar);
  ms_k<<<NRTOT/256, 256, 0, stream>>>(Qb, kbar, msb);
  select_rank_k<<<NBH*8, 256, 0, stream>>>(msb, sel);

  // ---- bf16 operand prep
  cvt_bf16_k<<<NX8, 256, 0, stream>>>(Kbuf, Kbf, NRTOT*ND/8);
  transpose_v_k<<<NBH*32, 256, 0, stream>>>(Vbuf, Vt);
  gather_q_k<<<MTOT/4, 256, 0, stream>>>(Qb, sel, Qg);

  // ---- attention as three GEMM-shaped passes (Sbf overlays dead Qb/Kbuf/Vbuf)
  sgemm_qk_k<<<dim3(MTOT/64, NL/64), 256, 0, stream>>>(Qg, Kbf, Sbf);
  softmax_k<<<MTOT, 256, 0, stream>>>(Sbf);
  pgemm_pv_k<<<MTOT/32, 256, 0, stream>>>(Sbf, Vt, Csel);

  // ---- output projection: zero split-CTX, scatter selected rows, 3-product GEMM
  zero_f4<<<(int)((2*hsz/16)/256), 256, 0, stream>>>((float4*)Cta);   // zeroes Cta+Ctb
  scatter_split2_k<<<(NBH*NU + 3)/4, 256, 0, stream>>>(Csel, sel, Cta, Ctb);
  gemm_split_k<3, false><<<gsp, 256, 0, stream>>>(Cta,Ctb,nullptr, Woa,Wob,nullptr, bo, out);
}

// Round 4
// 473.659 us; speedup vs baseline: 5.6781x; 1.6396x over previous
//
#include <hip/hip_runtime.h>
#include <math.h>

// Problem constants (fixed by setup_inputs)
#define NB 2
#define NL 2048
#define NH 16
#define ND 64
#define NDM 1024
#define NU 409                  // max(1, 2048 // 5)
#define NUP 416                 // NU padded to multiple of 32; 416 = 26*16 = 13*32
#define NBH (NB*NH)             // 32
#define NROWS (NB*NL)           // 4096
#define NRTOT (NB*NH*NL)        // 65536
#define MTOT (NBH*NUP)          // 13312
#define MHALF (MTOT/2)          // 6656 = 16 bh

typedef short bf16x8 __attribute__((ext_vector_type(8)));
typedef short bf16x4 __attribute__((ext_vector_type(4)));
typedef float f32x4  __attribute__((ext_vector_type(4)));

__device__ __forceinline__ short f2bf(float x) {   // RNE f32 -> bf16
  unsigned u = __float_as_uint(x);
  return (short)((u + 0x7FFFu + ((u >> 16) & 1u)) >> 16);
}
__device__ __forceinline__ float bf2f(short s) {
  return __uint_as_float(((unsigned)(unsigned short)s) << 16);
}

__device__ __forceinline__ void gload16(const short* g, short* l) {
  __builtin_amdgcn_global_load_lds(
      (const __attribute__((address_space(1))) void*)g,
      (__attribute__((address_space(3))) void*)l, 16, 0, 0);
}

// ---------------------------------------------------------------- zero fill
__global__ __launch_bounds__(256) void zero_f4(float4* __restrict__ p) {
  const size_t i = (size_t)blockIdx.x * 256 + threadIdx.x;
  p[i] = make_float4(0.f, 0.f, 0.f, 0.f);
}

// ---------------------------------------------------------------- multi-tensor f32 -> bf16 splits
struct SplitDesc { const float* in; short* a; short* b; short* c; int nc; };
struct SplitArgs { SplitDesc d[2]; };

__global__ __launch_bounds__(256) void msplit_k(SplitArgs args) {
  const SplitDesc d = args.d[blockIdx.z];
  const size_t i = (size_t)blockIdx.x * 256 + threadIdx.x;
  const float4 x0 = ((const float4*)d.in)[2*i];
  const float4 x1 = ((const float4*)d.in)[2*i + 1];
  float x[8] = {x0.x,x0.y,x0.z,x0.w, x1.x,x1.y,x1.z,x1.w};
  bf16x8 va, vb, vc;
  #pragma unroll
  for (int j = 0; j < 8; ++j) {
    const short A = f2bf(x[j]);
    const float r1 = x[j] - bf2f(A);
    const short B = f2bf(r1);
    va[j] = A; vb[j] = B;
    vc[j] = f2bf(r1 - bf2f(B));
  }
  *(bf16x8*)(d.a + 8*i) = va;
  *(bf16x8*)(d.b + 8*i) = vb;
  if (d.nc == 3) *(bf16x8*)(d.c + 8*i) = vc;
}

// ---------------------------------------------------------------- tiled split-bf16 MFMA GEMM (m97 structure)
// C[m,n] = bias[n] + sum over product-chunks c of X[px(c)][m,:] . W[pw(c)][n,:]
// pairs: c0 (a,a), c1 (a,b), c2 (b,a), c3 (a,c), c4 (c,a), c5 (b,b)
// 128x128 tile, BK=32, 4 waves (2x2), each wave 64x64 = 4x4 16x16 frags.
struct GemmDesc {
  const short* X[3];
  const short* W[3];
  const float* bias;    // may be null
  float* C;
  int sbeg, send;       // step range; one step = 32 k-elems; chunk = step>>5
};
struct GemmArgs { GemmDesc d[3]; };

template<bool SC>
__global__ __launch_bounds__(256) void gemm_tile_k(GemmArgs args) {
  __shared__ short As[128*32];   // 8 KB, row-major [m][k]
  __shared__ short Bs[128*32];   // 8 KB, row-major [n][k]
  const GemmDesc d = args.d[blockIdx.z];
  const int tid = threadIdx.x;
  const int wv = tid >> 6, L = tid & 63;
  const int lr = L & 15, lg = L >> 4;
  const int n0 = blockIdx.x << 7, m0 = blockIdx.y << 7;
  const int wm = (wv >> 1) << 6, wn = (wv & 1) << 6;

  // staging map: lane covers LDS shorts [tid*8 + j*2048, +8) == tile row j*64+srow, col scol..+8
  const int srow = (wv << 4) + (L >> 2);
  const int scol = (L & 3) << 3;
  short* const asd = As + (tid << 3);
  short* const bsd = Bs + (tid << 3);

  f32x4 acc[4][4];
  #pragma unroll
  for (int i = 0; i < 4; ++i)
    #pragma unroll
    for (int j = 0; j < 4; ++j) acc[i][j] = (f32x4){0.f,0.f,0.f,0.f};

  for (int step = d.sbeg; step < d.send; ++step) {
    const int c = step >> 5, kk = (step & 31) << 5;
    const short *Xg, *Wg;
    switch (c) {
      case 0:  Xg = d.X[0]; Wg = d.W[0]; break;
      case 1:  Xg = d.X[0]; Wg = d.W[1]; break;
      case 2:  Xg = d.X[1]; Wg = d.W[0]; break;
      case 3:  Xg = d.X[0]; Wg = d.W[2]; break;
      case 4:  Xg = d.X[2]; Wg = d.W[0]; break;
      default: Xg = d.X[1]; Wg = d.W[1]; break;
    }
    const short* xg = Xg + (size_t)(m0 + srow) * NDM + kk + scol;
    const short* wg = Wg + (size_t)(n0 + srow) * NDM + kk + scol;
    gload16(xg,              asd);
    gload16(xg + (NDM << 6), asd + 2048);   // +64 rows
    gload16(wg,              bsd);
    gload16(wg + (NDM << 6), bsd + 2048);
    __syncthreads();
    bf16x8 af[4], bf[4];
    #pragma unroll
    for (int t = 0; t < 4; ++t) {
      af[t] = *(const bf16x8*)(As + ((wm + (t << 4) + lr) << 5) + (lg << 3));
      bf[t] = *(const bf16x8*)(Bs + ((wn + (t << 4) + lr) << 5) + (lg << 3));
    }
    #pragma unroll
    for (int mt = 0; mt < 4; ++mt)
      #pragma unroll
      for (int nt = 0; nt < 4; ++nt)
        acc[mt][nt] = __builtin_amdgcn_mfma_f32_16x16x32_bf16(bf[nt], af[mt], acc[mt][nt], 0, 0, 0);
    __syncthreads();
  }

  #pragma unroll
  for (int nt = 0; nt < 4; ++nt) {
    const int n = n0 + wn + (nt << 4) + (lg << 2);
    float4 b4 = make_float4(0.f, 0.f, 0.f, 0.f);
    if (d.bias) b4 = *(const float4*)(d.bias + n);
    #pragma unroll
    for (int mt = 0; mt < 4; ++mt) {
      f32x4 a = acc[mt][nt];
      a[0] += b4.x; a[1] += b4.y; a[2] += b4.z; a[3] += b4.w;
      const int m = m0 + wm + (mt << 4) + lr;
      if (SC) {   // scatter into (B,H,L,D)
        const int bb = m >> 11, ll = m & (NL - 1);
        const int hh = n >> 6, dd = n & 63;
        *(f32x4*)(d.C + (((size_t)(bb*NH + hh)*NL + ll) << 6) + dd) = a;
      } else {
        *(f32x4*)(d.C + ((size_t)m << 10) + n) = a;
      }
    }
  }
}

// ---------------------------------------------------------------- K row inv-norms
__global__ __launch_bounds__(256) void invnorm_k(const float* __restrict__ Kb,
                                                 float* __restrict__ invn) {
  const int r = blockIdx.x * 256 + threadIdx.x;
  const float4* p = (const float4*)(Kb + ((size_t)r << 6));
  double s = 0.0;
  #pragma unroll
  for (int i = 0; i < 16; ++i) {
    const float4 v = p[i];
    s += (double)v.x*v.x + (double)v.y*v.y + (double)v.z*v.z + (double)v.w*v.w;
  }
  invn[r] = (float)(1.0 / sqrt(s));
}

// ---------------------------------------------------------------- kbar stage 1: per-(bh,seg) partials (f64)
__global__ __launch_bounds__(256) void kbar1_k(const float* __restrict__ Kb,
                                               const float* __restrict__ invn,
                                               double* __restrict__ part) {
  __shared__ double sm[4][64];
  const int bh = blockIdx.x >> 4, seg = blockIdx.x & 15;
  const int d = threadIdx.x & 63, g = threadIdx.x >> 6;
  const float* base = Kb + (((size_t)bh * NL) << 6);
  const float* ib = invn + (size_t)bh * NL;
  double s = 0.0;
  const int l0 = seg << 7;
  for (int l = l0 + g; l < l0 + 128; l += 4)
    s += (double)base[((size_t)l << 6) + d] * (double)ib[l];
  sm[g][d] = s;
  __syncthreads();
  if (threadIdx.x < 64)
    part[(((size_t)(bh << 4) + seg) << 6) + threadIdx.x] =
        sm[0][threadIdx.x] + sm[1][threadIdx.x] + sm[2][threadIdx.x] + sm[3][threadIdx.x];
}

// ---------------------------------------------------------------- kbar stage 2: combine 16 segs
__global__ __launch_bounds__(64) void kbar2_k(const double* __restrict__ part,
                                              double* __restrict__ kbar) {
  const int bh = blockIdx.x, d = threadIdx.x;
  double s = 0.0;
  #pragma unroll
  for (int seg = 0; seg < 16; ++seg)
    s += part[(((size_t)(bh << 4) + seg) << 6) + d];
  kbar[(bh << 6) + d] = s * (1.0 / NL);
}

// ---------------------------------------------------------------- mean_scores = (q . kbar)/|q|  (f64)
__global__ __launch_bounds__(256) void ms_k(const float* __restrict__ Q,
                                            const double* __restrict__ kbar,
                                            float* __restrict__ ms) {
  __shared__ double kb[64];
  const int bh = blockIdx.x >> 3;
  if (threadIdx.x < 64) kb[threadIdx.x] = kbar[(bh << 6) + threadIdx.x];
  __syncthreads();
  const int r = blockIdx.x * 256 + threadIdx.x;
  const float* q = Q + ((size_t)r << 6);
  double dot = 0.0, ss = 0.0;
  #pragma unroll 16
  for (int i = 0; i < 64; ++i) {
    const double x = q[i];
    dot += x * kb[i];
    ss += x * x;
  }
  ms[r] = (float)(dot / sqrt(ss));
}

// ---------------------------------------------------------------- rank-based top-NU selection
__global__ __launch_bounds__(256) void select_rank_k(const float* __restrict__ ms,
                                                     int* __restrict__ sel) {
  __shared__ unsigned long long keys[NL];
  const int bh = blockIdx.x >> 3, seg = blockIdx.x & 7;
  const int tid = threadIdx.x;
  for (int l = tid; l < NL; l += 256) {
    unsigned u = __float_as_uint(ms[(size_t)bh * NL + l]);
    u = (u & 0x80000000u) ? ~u : (u | 0x80000000u);   // order-preserving map
    keys[l] = ((unsigned long long)u << 32) | (unsigned)(NL - 1 - l);
  }
  __syncthreads();
  const int r = (seg << 8) + tid;
  const unsigned long long mine = keys[r];
  int cnt = 0;
  #pragma unroll 8
  for (int l = 0; l < NL; ++l) cnt += (keys[l] > mine) ? 1 : 0;
  if (cnt < NU) sel[bh*NU + cnt] = r;
}

// ---------------------------------------------------------------- f32 -> bf16 elementwise
__global__ __launch_bounds__(256) void cvt_bf16_k(const float* __restrict__ in,
                                                  short* __restrict__ out) {
  const size_t i = (size_t)blockIdx.x * 256 + threadIdx.x;
  const float4 a = ((const float4*)in)[2*i];
  const float4 b = ((const float4*)in)[2*i + 1];
  bf16x8 v;
  v[0]=f2bf(a.x); v[1]=f2bf(a.y); v[2]=f2bf(a.z); v[3]=f2bf(a.w);
  v[4]=f2bf(b.x); v[5]=f2bf(b.y); v[6]=f2bf(b.z); v[7]=f2bf(b.w);
  *(bf16x8*)(out + 8*i) = v;
}

// ---------------------------------------------------------------- V = Vp0+Vp1+bv, transpose -> Vt (bh,d,l) bf16
__global__ __launch_bounds__(256) void transpose_v_k(const float* __restrict__ V0,
                                                     const float* __restrict__ V1,
                                                     const float* __restrict__ bv,
                                                     short* __restrict__ Vt) {
  __shared__ float Ts[64][65];
  const int bh = blockIdx.x >> 5, lt = blockIdx.x & 31;
  const int l0 = lt << 6, tid = threadIdx.x;
  const int lr = tid >> 2, j = tid & 3;
  const int h = bh & 15;
  const size_t rowo = ((size_t)bh*NL + l0 + lr) << 6;
  #pragma unroll
  for (int s = 0; s < 4; ++s) {
    const int dd = (j + 4*s) << 2;
    float4 v = *(const float4*)(V0 + rowo + dd);
    const float4 q = *(const float4*)(V1 + rowo + dd);
    const float4 b4 = *(const float4*)(bv + (h << 6) + dd);
    v.x += q.x + b4.x; v.y += q.y + b4.y; v.z += q.z + b4.z; v.w += q.w + b4.w;
    Ts[lr][dd+0] = v.x; Ts[lr][dd+1] = v.y; Ts[lr][dd+2] = v.z; Ts[lr][dd+3] = v.w;
  }
  __syncthreads();
  const int d = tid >> 2, lc = (tid & 3) << 4;
  short* dst = Vt + ((size_t)bh*ND + d) * NL + l0 + lc;
  bf16x8 o0, o1;
  #pragma unroll
  for (int i = 0; i < 8; ++i) {
    o0[i] = f2bf(Ts[lc + i][d]);
    o1[i] = f2bf(Ts[lc + 8 + i][d]);
  }
  *(bf16x8*)dst = o0;
  *(bf16x8*)(dst + 8) = o1;
}

// ---------------------------------------------------------------- gather selected Q rows -> bf16 [MTOT][64]
__global__ __launch_bounds__(256) void gather_q_k(const float* __restrict__ Qb,
                                                  const int* __restrict__ sel,
                                                  short* __restrict__ Qg) {
  const int row = blockIdx.x * 4 + (threadIdx.x >> 6);
  const int d = threadIdx.x & 63;
  const int bh = row / NUP, u = row - bh * NUP;
  float v = 0.f;
  if (u < NU) {
    const int lq = sel[bh*NU + u];
    v = Qb[(((size_t)bh*NL + lq) << 6) + d];
  }
  Qg[((size_t)row << 6) + d] = f2bf(v);
}

// ---------------------------------------------------------------- S = Qg * K^T  (bf16 MFMA), half-band
__global__ __launch_bounds__(256) void sgemm_qk_k(const short* __restrict__ Qg,
                                                  const short* __restrict__ Kb,
                                                  short* __restrict__ S, int mbase) {
  const int w = threadIdx.x >> 6, L = threadIdx.x & 63;
  const int mloc = (blockIdx.x << 6) + (w << 4);
  const int mg = mbase + mloc;
  const int n0 = blockIdx.y << 6;
  const int bh = mg / NUP;
  const int lr = L & 15, lg = L >> 4;

  const short* qp = Qg + (((size_t)mg + lr) << 6) + lg*8;
  const bf16x8 qf0 = *(const bf16x8*)qp;
  const bf16x8 qf1 = *(const bf16x8*)(qp + 32);

  const short* kbase = Kb + (((size_t)bh*NL + n0 + lr) << 6) + lg*8;
  f32x4 acc[4];
  #pragma unroll
  for (int nt = 0; nt < 4; ++nt) {
    const short* kp = kbase + ((size_t)nt << 10);
    const bf16x8 kf0 = *(const bf16x8*)kp;
    const bf16x8 kf1 = *(const bf16x8*)(kp + 32);
    f32x4 a = {0.f,0.f,0.f,0.f};
    a = __builtin_amdgcn_mfma_f32_16x16x32_bf16(kf0, qf0, a, 0, 0, 0);
    a = __builtin_amdgcn_mfma_f32_16x16x32_bf16(kf1, qf1, a, 0, 0, 0);
    acc[nt] = a;
  }
  short* sp = S + ((size_t)mloc + lr) * NL + n0 + lg*4;
  #pragma unroll
  for (int nt = 0; nt < 4; ++nt) {
    bf16x4 o;
    o[0]=f2bf(acc[nt][0]); o[1]=f2bf(acc[nt][1]);
    o[2]=f2bf(acc[nt][2]); o[3]=f2bf(acc[nt][3]);
    *(bf16x4*)(sp + nt*16) = o;
  }
}

// ---------------------------------------------------------------- row softmax, in place, scale 1/8
__global__ __launch_bounds__(256) void softmax_k(short* __restrict__ S) {
  __shared__ float red[4];
  const int tid = threadIdx.x;
  short* sp = S + (size_t)blockIdx.x * NL + tid*8;
  const bf16x8 v = *(const bf16x8*)sp;
  float f[8];
  #pragma unroll
  for (int i = 0; i < 8; ++i) f[i] = bf2f(v[i]) * 0.125f;
  float m = f[0];
  #pragma unroll
  for (int i = 1; i < 8; ++i) m = fmaxf(m, f[i]);
  #pragma unroll
  for (int off = 32; off > 0; off >>= 1) m = fmaxf(m, __shfl_xor(m, off));
  if ((tid & 63) == 0) red[tid >> 6] = m;
  __syncthreads();
  const float gm = fmaxf(fmaxf(red[0], red[1]), fmaxf(red[2], red[3]));
  __syncthreads();
  float s = 0.f;
  #pragma unroll
  for (int i = 0; i < 8; ++i) { f[i] = __expf(f[i] - gm); s += f[i]; }
  #pragma unroll
  for (int off = 32; off > 0; off >>= 1) s += __shfl_xor(s, off);
  if ((tid & 63) == 0) red[tid >> 6] = s;
  __syncthreads();
  const float inv = 1.f / (red[0] + red[1] + red[2] + red[3]);
  bf16x8 o;
  #pragma unroll
  for (int i = 0; i < 8; ++i) o[i] = f2bf(f[i] * inv);
  *(bf16x8*)sp = o;
}

// ---------------------------------------------------------------- Csel = P * V  (bf16 MFMA), half-band
__global__ __launch_bounds__(256) void pgemm_pv_k(const short* __restrict__ P,
                                                  const short* __restrict__ Vt,
                                                  float* __restrict__ Csel, int mbase) {
  const int w = threadIdx.x >> 6, L = threadIdx.x & 63;
  const int mloc = blockIdx.x << 5;
  const int mg = mbase + mloc;
  const int bh = mg / NUP;
  const int mt = w & 1, d0 = (w >> 1) << 5;
  const int lr = L & 15, lg = L >> 4;

  const short* prow = P + ((size_t)mloc + mt*16 + lr) * NL + lg*8;
  const short* v0 = Vt + ((size_t)bh*ND + d0 + lr) * NL + lg*8;
  const short* v1 = v0 + (size_t)16 * NL;

  f32x4 acc0 = {0.f,0.f,0.f,0.f}, acc1 = {0.f,0.f,0.f,0.f};
  for (int k = 0; k < NL; k += 32) {
    const bf16x8 pf  = *(const bf16x8*)(prow + k);
    const bf16x8 vf0 = *(const bf16x8*)(v0 + k);
    const bf16x8 vf1 = *(const bf16x8*)(v1 + k);
    acc0 = __builtin_amdgcn_mfma_f32_16x16x32_bf16(pf, vf0, acc0, 0, 0, 0);
    acc1 = __builtin_amdgcn_mfma_f32_16x16x32_bf16(pf, vf1, acc1, 0, 0, 0);
  }
  float* c = Csel + (((size_t)mg + mt*16 + lg*4) << 6);
  #pragma unroll
  for (int r = 0; r < 4; ++r) {
    c[(size_t)(r << 6) + d0 + lr]      = acc0[r];
    c[(size_t)(r << 6) + d0 + 16 + lr] = acc1[r];
  }
}

// ---------------------------------------------------------------- scatter+split Csel rows into zeroed Cta/Ctb
__global__ __launch_bounds__(256) void scatter_split2_k(const float* __restrict__ Csel,
                                                        const int* __restrict__ sel,
                                                        short* __restrict__ Ca,
                                                        short* __restrict__ Cb) {
  const int r = blockIdx.x * 4 + (threadIdx.x >> 6);
  const int d = threadIdx.x & 63;
  if (r >= NBH * NU) return;
  const int bh = r / NU, u = r - bh * NU;
  const int b = bh >> 4, h = bh & 15;
  const int lq = sel[bh*NU + u];
  const float x = Csel[(((size_t)bh*NUP + u) << 6) + d];
  const short A = f2bf(x);
  const size_t o = ((((size_t)b << 11) + lq) << 10) + (h << 6) + d;
  Ca[o] = A;
  Cb[o] = f2bf(x - bf2f(A));
}

// ---------------------------------------------------------------- out += P1 + bias
__global__ __launch_bounds__(256) void oadd_k(float* __restrict__ out,
                                              const float* __restrict__ P1,
                                              const float* __restrict__ bo) {
  const size_t i4 = (size_t)blockIdx.x * 256 + threadIdx.x;
  const size_t i = i4 << 2;
  float4 a = *(float4*)(out + i);
  const float4 b = *(const float4*)(P1 + i);
  const float4 c = *(const float4*)(bo + ((i4 & 255) << 2));
  a.x += b.x + c.x; a.y += b.y + c.y; a.z += b.z + c.z; a.w += b.w + c.w;
  *(float4*)(out + i) = a;
}

// ---------------------------------------------------------------- launch
extern "C" void kernel_launch(void* const* d_in, const int* in_sizes, int n_in,
                              void* d_out, int out_size, void* d_ws, size_t ws_size,
                              hipStream_t stream)
{
  (void)in_sizes; (void)n_in; (void)out_size; (void)ws_size;
  const float* queries = (const float*)d_in[0];
  const float* keys    = (const float*)d_in[1];
  const float* values  = (const float*)d_in[2];
  const float* Wq = (const float*)d_in[3];  const float* bq = (const float*)d_in[4];
  const float* Wk = (const float*)d_in[5];  const float* bk = (const float*)d_in[6];
  const float* Wv = (const float*)d_in[7];  const float* bv = (const float*)d_in[8];
  const float* Wo = (const float*)d_in[9];  const float* bo = (const float*)d_in[10];
  float* out = (float*)d_out;

  const size_t HSZ = (size_t)NRTOT * ND * sizeof(short);   // 8,388,608
  const size_t WSZ = (size_t)NDM * NDM * sizeof(short);    // 2,097,152
  const size_t FSZ = (size_t)NROWS * NDM * sizeof(float);  // 16,777,216

  char* base = (char*)d_ws;
  short* x[6];
  for (int i = 0; i < 6; ++i) x[i] = (short*)(base + i*HSZ);
  short* Qg = (short*)(base + 6*HSZ);                      // 1.70 MB
  char* wreg = base + ((size_t)55 << 20);
  short* wsp[6];
  for (int i = 0; i < 6; ++i) wsp[i] = (short*)(wreg + i*WSZ);
  float* Csel = (float*)(wreg + 4*WSZ);                    // 3.41 MB over w4,w5 (after QK GEMM)
  float* Qb   = (float*)(wreg + 6*WSZ);
  float* Kbuf = (float*)((char*)Qb + FSZ);
  char* sm = (char*)Kbuf + FSZ;
  float*  invn  = (float*)sm;   sm += 262144;
  double* kpart = (double*)sm;  sm += 262144;
  double* kbar  = (double*)sm;  sm += 16384;
  float*  msb   = (float*)sm;   sm += 262144;
  int*    sel   = (int*)sm;

  // time-multiplexed aliases
  float* Vbuf = (float*)base;              // x0,x1  (after QK GEMM)
  float* P1v  = (float*)(base + 2*HSZ);    // x2,x3
  short* Kbf  = x[4];                      // after V GEMM
  short* Vt   = x[5];
  short* Sh   = (short*)base;              // [MHALF][NL] bf16 = 27.3 MB over x0..x3
  short* Cta  = x[0];                      // after attention
  short* Ctb  = x[1];
  float* P1o  = (float*)(base + 2*HSZ);

  // ---- splits for Q/K inputs + weights (3-way)
  {
    SplitArgs a; 
    a.d[0] = {queries, x[0], x[1], x[2], 3};
    a.d[1] = {keys,    x[3], x[4], x[5], 3};
    msplit_k<<<dim3(2048,1,2), 256, 0, stream>>>(a);
  }
  {
    SplitArgs a;
    a.d[0] = {Wq, wsp[0], wsp[1], wsp[2], 3};
    a.d[1] = {Wk, wsp[3], wsp[4], wsp[5], 3};
    msplit_k<<<dim3(512,1,2), 256, 0, stream>>>(a);
  }
  // ---- Q,K projections fused (6 products = 192 steps)
  {
    GemmArgs g;
    g.d[0] = {{x[0],x[1],x[2]}, {wsp[0],wsp[1],wsp[2]}, bq, Qb,   0, 192};
    g.d[1] = {{x[3],x[4],x[5]}, {wsp[3],wsp[4],wsp[5]}, bk, Kbuf, 0, 192};
    g.d[2] = g.d[0];
    gemm_tile_k<true><<<dim3(8,32,2), 256, 0, stream>>>(g);
  }
  // ---- V splits (2-way) into dead Xk slots; Wv/Wo into dead Wq slots
  {
    SplitArgs a;
    a.d[0] = {values, x[4], x[5], x[3], 2};
    a.d[1] = a.d[0];
    msplit_k<<<dim3(2048,1,1), 256, 0, stream>>>(a);
  }
  {
    SplitArgs a;
    a.d[0] = {Wv, wsp[0], wsp[1], wsp[2], 2};
    a.d[1] = {Wo, wsp[2], wsp[3], wsp[4], 2};
    msplit_k<<<dim3(512,1,2), 256, 0, stream>>>(a);
  }
  // ---- V projection, split-K over 3 products (96 steps); bias deferred
  {
    GemmArgs g;
    g.d[0] = {{x[4],x[5],nullptr}, {wsp[0],wsp[1],nullptr}, nullptr, Vbuf, 0, 48};
    g.d[1] = {{x[4],x[5],nullptr}, {wsp[0],wsp[1],nullptr}, nullptr, P1v, 48, 96};
    g.d[2] = g.d[0];
    gemm_tile_k<true><<<dim3(8,32,2), 256, 0, stream>>>(g);
  }

  // ---- ranking + selection
  invnorm_k<<<NRTOT/256, 256, 0, stream>>>(Kbuf, invn);
  kbar1_k<<<NBH*16, 256, 0, stream>>>(Kbuf, invn, kpart);
  kbar2_k<<<NBH, 64, 0, stream>>>(kpart, kbar);
  ms_k<<<NRTOT/256, 256, 0, stream>>>(Qb, kbar, msb);
  select_rank_k<<<NBH*8, 256, 0, stream>>>(msb, sel);

  // ---- bf16 operand prep
  transpose_v_k<<<NBH*32, 256, 0, stream>>>(Vbuf, P1v, bv, Vt);
  cvt_bf16_k<<<2048, 256, 0, stream>>>(Kbuf, Kbf);
  gather_q_k<<<MTOT/4, 256, 0, stream>>>(Qb, sel, Qg);

  // ---- attention (two m-halves share the 27 MB S buffer)
  for (int half = 0; half < 2; ++half) {
    const int mbase = half * MHALF;
    sgemm_qk_k<<<dim3(MHALF/64, NL/64), 256, 0, stream>>>(Qg, Kbf, Sh, mbase);
    softmax_k<<<MHALF, 256, 0, stream>>>(Sh);
    pgemm_pv_k<<<MHALF/32, 256, 0, stream>>>(Sh, Vt, Csel, mbase);
  }

  // ---- output projection: zero split-CTX, scatter, split-K GEMM, combine
  zero_f4<<<4096, 256, 0, stream>>>((float4*)Cta);           // Cta+Ctb (2*HSZ)
  scatter_split2_k<<<(NBH*NU + 3)/4, 256, 0, stream>>>(Csel, sel, Cta, Ctb);
  {
    GemmArgs g;
    g.d[0] = {{Cta,Ctb,nullptr}, {wsp[2],wsp[3],nullptr}, nullptr, out, 0, 48};
    g.d[1] = {{Cta,Ctb,nullptr}, {wsp[2],wsp[3],nullptr}, nullptr, P1o, 48, 96};
    g.d[2] = g.d[0];
    gemm_tile_k<false><<<dim3(8,32,2), 256, 0, stream>>>(g);
  }
  oadd_k<<<4096, 256, 0, stream>>>(out, P1o, bo);
}

// Round 5
// 444.665 us; speedup vs baseline: 6.0484x; 1.0652x over previous
//
#include <hip/hip_runtime.h>
#include <math.h>

// Problem constants (fixed by setup_inputs)
#define NB 2
#define NL 2048
#define NH 16
#define ND 64
#define NDM 1024
#define NU 409                  // max(1, 2048 // 5)
#define NUP 416                 // NU padded to multiple of 32; 416 = 26*16 = 13*32
#define NBH (NB*NH)             // 32
#define NROWS (NB*NL)           // 4096
#define NRTOT (NB*NH*NL)        // 65536
#define MTOT (NBH*NUP)          // 13312
#define MHALF (MTOT/2)          // 6656 = 16 bh

typedef short bf16x8 __attribute__((ext_vector_type(8)));
typedef short bf16x4 __attribute__((ext_vector_type(4)));
typedef float f32x4  __attribute__((ext_vector_type(4)));

__device__ __forceinline__ short f2bf(float x) {   // RNE f32 -> bf16
  unsigned u = __float_as_uint(x);
  return (short)((u + 0x7FFFu + ((u >> 16) & 1u)) >> 16);
}
__device__ __forceinline__ float bf2f(short s) {
  return __uint_as_float(((unsigned)(unsigned short)s) << 16);
}

__device__ __forceinline__ void gload16(const short* g, short* l) {
  __builtin_amdgcn_global_load_lds(
      (const __attribute__((address_space(1))) void*)g,
      (__attribute__((address_space(3))) void*)l, 16, 0, 0);
}

// ---------------------------------------------------------------- zero fill
__global__ __launch_bounds__(256) void zero_f4(float4* __restrict__ p) {
  const size_t i = (size_t)blockIdx.x * 256 + threadIdx.x;
  p[i] = make_float4(0.f, 0.f, 0.f, 0.f);
}

// ---------------------------------------------------------------- multi-tensor f32 -> bf16 splits
struct SplitDesc { const float* in; short* a; short* b; short* c; int nc; };
struct SplitArgs { SplitDesc d[2]; };

__global__ __launch_bounds__(256) void msplit_k(SplitArgs args) {
  const SplitDesc d = args.d[blockIdx.z];
  const size_t i = (size_t)blockIdx.x * 256 + threadIdx.x;
  const float4 x0 = ((const float4*)d.in)[2*i];
  const float4 x1 = ((const float4*)d.in)[2*i + 1];
  float x[8] = {x0.x,x0.y,x0.z,x0.w, x1.x,x1.y,x1.z,x1.w};
  bf16x8 va, vb, vc;
  #pragma unroll
  for (int j = 0; j < 8; ++j) {
    const short A = f2bf(x[j]);
    const float r1 = x[j] - bf2f(A);
    const short B = f2bf(r1);
    va[j] = A; vb[j] = B;
    vc[j] = f2bf(r1 - bf2f(B));
  }
  *(bf16x8*)(d.a + 8*i) = va;
  *(bf16x8*)(d.b + 8*i) = vb;
  if (d.nc == 3) *(bf16x8*)(d.c + 8*i) = vc;
}

// ---------------------------------------------------------------- tiled split-bf16 MFMA GEMM (m97 structure)
// chunk pairs: c0 (a,a), c1 (a,b), c2 (b,a), c3 (a,c), c4 (c,a), c5 (b,b)
// 128x128 tile, BK=32, 4 waves (2x2), each wave 64x64 = 4x4 16x16 frags.
struct GemmDesc {
  const short* X[3];
  const short* W[3];
  const float* bias;    // may be null
  float* C;
  int sbeg, send;       // step range; one step = 32 k-elems; chunk = step>>5
};
struct GemmArgs { GemmDesc d[3]; };

template<bool SC>
__global__ __launch_bounds__(256) void gemm_tile_k(GemmArgs args) {
  __shared__ short As[128*32];   // 8 KB, row-major [m][k]
  __shared__ short Bs[128*32];   // 8 KB, row-major [n][k]
  const GemmDesc d = args.d[blockIdx.z];
  const int tid = threadIdx.x;
  const int wv = tid >> 6, L = tid & 63;
  const int lr = L & 15, lg = L >> 4;
  const int n0 = blockIdx.x << 7, m0 = blockIdx.y << 7;
  const int wm = (wv >> 1) << 6, wn = (wv & 1) << 6;

  const int srow = (wv << 4) + (L >> 2);
  const int scol = (L & 3) << 3;
  short* const asd = As + (tid << 3);
  short* const bsd = Bs + (tid << 3);

  f32x4 acc[4][4];
  #pragma unroll
  for (int i = 0; i < 4; ++i)
    #pragma unroll
    for (int j = 0; j < 4; ++j) acc[i][j] = (f32x4){0.f,0.f,0.f,0.f};

  for (int step = d.sbeg; step < d.send; ++step) {
    const int c = step >> 5, kk = (step & 31) << 5;
    const short *Xg, *Wg;
    switch (c) {
      case 0:  Xg = d.X[0]; Wg = d.W[0]; break;
      case 1:  Xg = d.X[0]; Wg = d.W[1]; break;
      case 2:  Xg = d.X[1]; Wg = d.W[0]; break;
      case 3:  Xg = d.X[0]; Wg = d.W[2]; break;
      case 4:  Xg = d.X[2]; Wg = d.W[0]; break;
      default: Xg = d.X[1]; Wg = d.W[1]; break;
    }
    const short* xg = Xg + (size_t)(m0 + srow) * NDM + kk + scol;
    const short* wg = Wg + (size_t)(n0 + srow) * NDM + kk + scol;
    gload16(xg,              asd);
    gload16(xg + (NDM << 6), asd + 2048);   // +64 rows
    gload16(wg,              bsd);
    gload16(wg + (NDM << 6), bsd + 2048);
    __syncthreads();
    bf16x8 af[4], bf[4];
    #pragma unroll
    for (int t = 0; t < 4; ++t) {
      af[t] = *(const bf16x8*)(As + ((wm + (t << 4) + lr) << 5) + (lg << 3));
      bf[t] = *(const bf16x8*)(Bs + ((wn + (t << 4) + lr) << 5) + (lg << 3));
    }
    #pragma unroll
    for (int mt = 0; mt < 4; ++mt)
      #pragma unroll
      for (int nt = 0; nt < 4; ++nt)
        acc[mt][nt] = __builtin_amdgcn_mfma_f32_16x16x32_bf16(bf[nt], af[mt], acc[mt][nt], 0, 0, 0);
    __syncthreads();
  }

  #pragma unroll
  for (int nt = 0; nt < 4; ++nt) {
    const int n = n0 + wn + (nt << 4) + (lg << 2);
    float4 b4 = make_float4(0.f, 0.f, 0.f, 0.f);
    if (d.bias) b4 = *(const float4*)(d.bias + n);
    #pragma unroll
    for (int mt = 0; mt < 4; ++mt) {
      f32x4 a = acc[mt][nt];
      a[0] += b4.x; a[1] += b4.y; a[2] += b4.z; a[3] += b4.w;
      const int m = m0 + wm + (mt << 4) + lr;
      if (SC) {   // scatter into (B,H,L,D)
        const int bb = m >> 11, ll = m & (NL - 1);
        const int hh = n >> 6, dd = n & 63;
        *(f32x4*)(d.C + (((size_t)(bb*NH + hh)*NL + ll) << 6) + dd) = a;
      } else {
        *(f32x4*)(d.C + ((size_t)m << 10) + n) = a;
      }
    }
  }
}

// ---------------------------------------------------------------- K combine: Kp0+Kp1+bias -> Kbf bf16, khat partials
// grid NBH*32 (bh, 64-row segment); 256 thr = 4 waves; wave g does rows g,g+4,...
__global__ __launch_bounds__(256) void combine_k(const float* __restrict__ Kp0,
                                                 const float* __restrict__ Kp1,
                                                 const float* __restrict__ bk,
                                                 short* __restrict__ Kbf,
                                                 double* __restrict__ kpart) {
  __shared__ double sm[4][64];
  const int bh = blockIdx.x >> 5, seg = blockIdx.x & 31;
  const int g = threadIdx.x >> 6, d = threadIdx.x & 63;
  const int h = bh & 15;
  const float bias = bk[(h << 6) + d];
  double acc = 0.0;
  #pragma unroll 4
  for (int i = 0; i < 16; ++i) {
    const int l = (seg << 6) + (i << 2) + g;
    const size_t o = (((size_t)bh * NL + l) << 6) + d;
    const float k = Kp0[o] + Kp1[o] + bias;
    float ss = k * k;
    #pragma unroll
    for (int off = 32; off > 0; off >>= 1) ss += __shfl_xor(ss, off);
    const double inv = 1.0 / sqrt((double)ss);
    Kbf[o] = f2bf(k);
    acc += (double)k * inv;
  }
  sm[g][d] = acc;
  __syncthreads();
  if (threadIdx.x < 64)
    kpart[((((size_t)bh << 5) + seg) << 6) + threadIdx.x] =
        sm[0][threadIdx.x] + sm[1][threadIdx.x] + sm[2][threadIdx.x] + sm[3][threadIdx.x];
}

// ---------------------------------------------------------------- kbar: combine 32 segments (f64)
__global__ __launch_bounds__(64) void kbar2_k(const double* __restrict__ kpart,
                                              double* __restrict__ kbar) {
  const int bh = blockIdx.x, d = threadIdx.x;
  double s = 0.0;
  #pragma unroll
  for (int seg = 0; seg < 32; ++seg)
    s += kpart[((((size_t)bh << 5) + seg) << 6) + d];
  kbar[(bh << 6) + d] = s * (1.0 / NL);
}

// ---------------------------------------------------------------- wtilde[bh][j] = sum_d Wq[h*64+d][j]*kbar[bh][d]; s0 = bq.kbar
__global__ __launch_bounds__(256) void wtilde_k(const float* __restrict__ Wq,
                                                const float* __restrict__ bq,
                                                const double* __restrict__ kbar,
                                                double* __restrict__ wt,
                                                double* __restrict__ s0) {
  __shared__ double kb[64];
  const int bh = blockIdx.x, h = bh & 15;
  const int tid = threadIdx.x;
  if (tid < 64) kb[tid] = kbar[(bh << 6) + tid];
  __syncthreads();
  const int j = (blockIdx.y << 8) + tid;
  double a = 0.0;
  #pragma unroll 8
  for (int d = 0; d < 64; ++d)
    a += (double)Wq[(((size_t)((h << 6) + d)) << 10) + j] * kb[d];
  wt[((size_t)bh << 10) + j] = a;
  if (blockIdx.y == 0 && tid < 64) {
    double p = (double)bq[(h << 6) + tid] * kb[tid];
    #pragma unroll
    for (int off = 32; off > 0; off >>= 1) p += __shfl_xor(p, off);
    if (tid == 0) s0[bh] = p;
  }
}

// ---------------------------------------------------------------- dotq[bh][l] = x_row . wt[bh]  (f64 accum)
__global__ __launch_bounds__(256) void dotq_k(const float* __restrict__ x,
                                              const double* __restrict__ wt,
                                              float* __restrict__ dotq) {
  __shared__ float xs[1024];
  __shared__ double sm[16][16];
  const int r = blockIdx.x, b = r >> 11, l = r & (NL - 1);
  const int tid = threadIdx.x;
  ((float4*)xs)[tid] = ((const float4*)(x + ((size_t)r << 10)))[tid];
  __syncthreads();
  const int h = tid >> 4, t = tid & 15;
  const double* w = wt + ((size_t)((b << 4) + h) << 10);
  double a = 0.0;
  #pragma unroll 8
  for (int i = 0; i < 64; ++i) {
    const int j = t + (i << 4);
    a += (double)xs[j] * w[j];
  }
  sm[h][t] = a;
  __syncthreads();
  if (tid < 16) {
    double s = 0.0;
    #pragma unroll
    for (int t2 = 0; t2 < 16; ++t2) s += sm[tid][t2];
    dotq[(((size_t)(b << 4) + tid) << 11) + l] = (float)s;
  }
}

// ---------------------------------------------------------------- Q row inv-norms (f64)
__global__ __launch_bounds__(256) void invnorm_k(const float* __restrict__ Qb,
                                                 float* __restrict__ invn) {
  const int r = blockIdx.x * 256 + threadIdx.x;
  const float4* p = (const float4*)(Qb + ((size_t)r << 6));
  double s = 0.0;
  #pragma unroll
  for (int i = 0; i < 16; ++i) {
    const float4 v = p[i];
    s += (double)v.x*v.x + (double)v.y*v.y + (double)v.z*v.z + (double)v.w*v.w;
  }
  invn[r] = (float)(1.0 / sqrt(s));
}

// ---------------------------------------------------------------- ms = (dotq + s0) * invq
__global__ __launch_bounds__(256) void msq_k(const float* __restrict__ dotq,
                                             const double* __restrict__ s0,
                                             const float* __restrict__ invq,
                                             float* __restrict__ ms) {
  const int r = blockIdx.x * 256 + threadIdx.x;
  const int bh = r >> 11;
  ms[r] = (float)(((double)dotq[r] + s0[bh]) * (double)invq[r]);
}

// ---------------------------------------------------------------- rank-based top-NU selection
__global__ __launch_bounds__(256) void select_rank_k(const float* __restrict__ ms,
                                                     int* __restrict__ sel) {
  __shared__ unsigned long long keys[NL];
  const int bh = blockIdx.x >> 3, seg = blockIdx.x & 7;
  const int tid = threadIdx.x;
  for (int l = tid; l < NL; l += 256) {
    unsigned u = __float_as_uint(ms[(size_t)bh * NL + l]);
    u = (u & 0x80000000u) ? ~u : (u | 0x80000000u);   // order-preserving map
    keys[l] = ((unsigned long long)u << 32) | (unsigned)(NL - 1 - l);
  }
  __syncthreads();
  const int r = (seg << 8) + tid;
  const unsigned long long mine = keys[r];
  int cnt = 0;
  #pragma unroll 8
  for (int l = 0; l < NL; ++l) cnt += (keys[l] > mine) ? 1 : 0;
  if (cnt < NU) sel[bh*NU + cnt] = r;
}

// ---------------------------------------------------------------- V = Vp0+Vp1+bv, transpose -> Vt (bh,d,l) bf16
__global__ __launch_bounds__(256) void transpose_v_k(const float* __restrict__ V0,
                                                     const float* __restrict__ V1,
                                                     const float* __restrict__ bv,
                                                     short* __restrict__ Vt) {
  __shared__ float Ts[64][65];
  const int bh = blockIdx.x >> 5, lt = blockIdx.x & 31;
  const int l0 = lt << 6, tid = threadIdx.x;
  const int lr = tid >> 2, j = tid & 3;
  const int h = bh & 15;
  const size_t rowo = ((size_t)bh*NL + l0 + lr) << 6;
  #pragma unroll
  for (int s = 0; s < 4; ++s) {
    const int dd = (j + 4*s) << 2;
    float4 v = *(const float4*)(V0 + rowo + dd);
    const float4 q = *(const float4*)(V1 + rowo + dd);
    const float4 b4 = *(const float4*)(bv + (h << 6) + dd);
    v.x += q.x + b4.x; v.y += q.y + b4.y; v.z += q.z + b4.z; v.w += q.w + b4.w;
    Ts[lr][dd+0] = v.x; Ts[lr][dd+1] = v.y; Ts[lr][dd+2] = v.z; Ts[lr][dd+3] = v.w;
  }
  __syncthreads();
  const int d = tid >> 2, lc = (tid & 3) << 4;
  short* dst = Vt + ((size_t)bh*ND + d) * NL + l0 + lc;
  bf16x8 o0, o1;
  #pragma unroll
  for (int i = 0; i < 8; ++i) {
    o0[i] = f2bf(Ts[lc + i][d]);
    o1[i] = f2bf(Ts[lc + 8 + i][d]);
  }
  *(bf16x8*)dst = o0;
  *(bf16x8*)(dst + 8) = o1;
}

// ---------------------------------------------------------------- gather selected Q rows -> bf16 [MTOT][64]
__global__ __launch_bounds__(256) void gather_q_k(const float* __restrict__ Qb,
                                                  const int* __restrict__ sel,
                                                  short* __restrict__ Qg) {
  const int row = blockIdx.x * 4 + (threadIdx.x >> 6);
  const int d = threadIdx.x & 63;
  const int bh = row / NUP, u = row - bh * NUP;
  float v = 0.f;
  if (u < NU) {
    const int lq = sel[bh*NU + u];
    v = Qb[(((size_t)bh*NL + lq) << 6) + d];
  }
  Qg[((size_t)row << 6) + d] = f2bf(v);
}

// ---------------------------------------------------------------- S = Qg * K^T  (bf16 MFMA), half-band
__global__ __launch_bounds__(256) void sgemm_qk_k(const short* __restrict__ Qg,
                                                  const short* __restrict__ Kb,
                                                  short* __restrict__ S, int mbase) {
  const int w = threadIdx.x >> 6, L = threadIdx.x & 63;
  const int mloc = (blockIdx.x << 6) + (w << 4);
  const int mg = mbase + mloc;
  const int n0 = blockIdx.y << 6;
  const int bh = mg / NUP;
  const int lr = L & 15, lg = L >> 4;

  const short* qp = Qg + (((size_t)mg + lr) << 6) + lg*8;
  const bf16x8 qf0 = *(const bf16x8*)qp;
  const bf16x8 qf1 = *(const bf16x8*)(qp + 32);

  const short* kbase = Kb + (((size_t)bh*NL + n0 + lr) << 6) + lg*8;
  f32x4 acc[4];
  #pragma unroll
  for (int nt = 0; nt < 4; ++nt) {
    const short* kp = kbase + ((size_t)nt << 10);
    const bf16x8 kf0 = *(const bf16x8*)kp;
    const bf16x8 kf1 = *(const bf16x8*)(kp + 32);
    f32x4 a = {0.f,0.f,0.f,0.f};
    a = __builtin_amdgcn_mfma_f32_16x16x32_bf16(kf0, qf0, a, 0, 0, 0);
    a = __builtin_amdgcn_mfma_f32_16x16x32_bf16(kf1, qf1, a, 0, 0, 0);
    acc[nt] = a;
  }
  short* sp = S + ((size_t)mloc + lr) * NL + n0 + lg*4;
  #pragma unroll
  for (int nt = 0; nt < 4; ++nt) {
    bf16x4 o;
    o[0]=f2bf(acc[nt][0]); o[1]=f2bf(acc[nt][1]);
    o[2]=f2bf(acc[nt][2]); o[3]=f2bf(acc[nt][3]);
    *(bf16x4*)(sp + nt*16) = o;
  }
}

// ---------------------------------------------------------------- row softmax, in place, scale 1/8
__global__ __launch_bounds__(256) void softmax_k(short* __restrict__ S) {
  __shared__ float red[4];
  const int tid = threadIdx.x;
  short* sp = S + (size_t)blockIdx.x * NL + tid*8;
  const bf16x8 v = *(const bf16x8*)sp;
  float f[8];
  #pragma unroll
  for (int i = 0; i < 8; ++i) f[i] = bf2f(v[i]) * 0.125f;
  float m = f[0];
  #pragma unroll
  for (int i = 1; i < 8; ++i) m = fmaxf(m, f[i]);
  #pragma unroll
  for (int off = 32; off > 0; off >>= 1) m = fmaxf(m, __shfl_xor(m, off));
  if ((tid & 63) == 0) red[tid >> 6] = m;
  __syncthreads();
  const float gm = fmaxf(fmaxf(red[0], red[1]), fmaxf(red[2], red[3]));
  __syncthreads();
  float s = 0.f;
  #pragma unroll
  for (int i = 0; i < 8; ++i) { f[i] = __expf(f[i] - gm); s += f[i]; }
  #pragma unroll
  for (int off = 32; off > 0; off >>= 1) s += __shfl_xor(s, off);
  if ((tid & 63) == 0) red[tid >> 6] = s;
  __syncthreads();
  const float inv = 1.f / (red[0] + red[1] + red[2] + red[3]);
  bf16x8 o;
  #pragma unroll
  for (int i = 0; i < 8; ++i) o[i] = f2bf(f[i] * inv);
  *(bf16x8*)sp = o;
}

// ---------------------------------------------------------------- Csel = P * V  (bf16 MFMA), half-band
__global__ __launch_bounds__(256) void pgemm_pv_k(const short* __restrict__ P,
                                                  const short* __restrict__ Vt,
                                                  float* __restrict__ Csel, int mbase) {
  const int w = threadIdx.x >> 6, L = threadIdx.x & 63;
  const int mloc = blockIdx.x << 5;
  const int mg = mbase + mloc;
  const int bh = mg / NUP;
  const int mt = w & 1, d0 = (w >> 1) << 5;
  const int lr = L & 15, lg = L >> 4;

  const short* prow = P + ((size_t)mloc + mt*16 + lr) * NL + lg*8;
  const short* v0 = Vt + ((size_t)bh*ND + d0 + lr) * NL + lg*8;
  const short* v1 = v0 + (size_t)16 * NL;

  f32x4 acc0 = {0.f,0.f,0.f,0.f}, acc1 = {0.f,0.f,0.f,0.f};
  for (int k = 0; k < NL; k += 32) {
    const bf16x8 pf  = *(const bf16x8*)(prow + k);
    const bf16x8 vf0 = *(const bf16x8*)(v0 + k);
    const bf16x8 vf1 = *(const bf16x8*)(v1 + k);
    acc0 = __builtin_amdgcn_mfma_f32_16x16x32_bf16(pf, vf0, acc0, 0, 0, 0);
    acc1 = __builtin_amdgcn_mfma_f32_16x16x32_bf16(pf, vf1, acc1, 0, 0, 0);
  }
  float* c = Csel + (((size_t)mg + mt*16 + lg*4) << 6);
  #pragma unroll
  for (int r = 0; r < 4; ++r) {
    c[(size_t)(r << 6) + d0 + lr]      = acc0[r];
    c[(size_t)(r << 6) + d0 + 16 + lr] = acc1[r];
  }
}

// ---------------------------------------------------------------- scatter+split Csel rows into zeroed Cta/Ctb
__global__ __launch_bounds__(256) void scatter_split2_k(const float* __restrict__ Csel,
                                                        const int* __restrict__ sel,
                                                        short* __restrict__ Ca,
                                                        short* __restrict__ Cb) {
  const int r = blockIdx.x * 4 + (threadIdx.x >> 6);
  const int d = threadIdx.x & 63;
  if (r >= NBH * NU) return;
  const int bh = r / NU, u = r - bh * NU;
  const int b = bh >> 4, h = bh & 15;
  const int lq = sel[bh*NU + u];
  const float x = Csel[(((size_t)bh*NUP + u) << 6) + d];
  const short A = f2bf(x);
  const size_t o = ((((size_t)b << 11) + lq) << 10) + (h << 6) + d;
  Ca[o] = A;
  Cb[o] = f2bf(x - bf2f(A));
}

// ---------------------------------------------------------------- out += P1 + bias
__global__ __launch_bounds__(256) void oadd_k(float* __restrict__ out,
                                              const float* __restrict__ P1,
                                              const float* __restrict__ bo) {
  const size_t i4 = (size_t)blockIdx.x * 256 + threadIdx.x;
  const size_t i = i4 << 2;
  float4 a = *(float4*)(out + i);
  const float4 b = *(const float4*)(P1 + i);
  const float4 c = *(const float4*)(bo + ((i4 & 255) << 2));
  a.x += b.x + c.x; a.y += b.y + c.y; a.z += b.z + c.z; a.w += b.w + c.w;
  *(float4*)(out + i) = a;
}

// ---------------------------------------------------------------- launch
extern "C" void kernel_launch(void* const* d_in, const int* in_sizes, int n_in,
                              void* d_out, int out_size, void* d_ws, size_t ws_size,
                              hipStream_t stream)
{
  (void)in_sizes; (void)n_in; (void)out_size; (void)ws_size;
  const float* queries = (const float*)d_in[0];
  const float* keys    = (const float*)d_in[1];
  const float* values  = (const float*)d_in[2];
  const float* Wq = (const float*)d_in[3];  const float* bq = (const float*)d_in[4];
  const float* Wk = (const float*)d_in[5];  const float* bk = (const float*)d_in[6];
  const float* Wv = (const float*)d_in[7];  const float* bv = (const float*)d_in[8];
  const float* Wo = (const float*)d_in[9];  const float* bo = (const float*)d_in[10];
  float* out = (float*)d_out;

  char* base = (char*)d_ws;
  #define MB(x) ((size_t)(x) << 20)

  // Region map (time-multiplexed; see phase comments)
  short* Qa   = (short*)(base + MB(0));    // queries split a      -> Kbf after phase1
  short* Qb2  = (short*)(base + MB(8));    // queries split b      -> Vt
  short* Ka   = (short*)(base + MB(16));   // keys split a         -> Va -> Sh/Cta
  short* Kb2  = (short*)(base + MB(24));   // keys split b         -> Vb2 -> Sh/Ctb
  short* Kc   = (short*)(base + MB(32));   // keys split c         -> Sh tail
  float* Qb   = (float*)(base + MB(44));   // Q proj f32           -> Csel after gather
  float* Kp0  = (float*)(base + MB(60));   // K partial 0 -> Vp0 -> P1o
  float* Kp1  = (float*)(base + MB(76));   // K partial 1 -> Vp1
  short* Wqa  = (short*)(base + MB(92));   // -> Woa
  short* Wqb  = (short*)(base + MB(94));   // -> Wob
  short* Wka  = (short*)(base + MB(96));   // -> Wva
  short* Wkb  = (short*)(base + MB(98));   // -> Wvb
  short* Wkc  = (short*)(base + MB(100));  // -> smalls after phase1
  short* Qg   = (short*)(base + MB(102));  // 1.7 MB

  // aliases
  short* Kbf = Qa;
  short* Vt  = Qb2;
  short* Va  = Ka;
  short* Vb2 = Kb2;
  short* Sh  = (short*)(base + MB(16));    // 26 MB (16..42), over Va/Vb2/Kc (dead)
  short* Cta = Ka;                          // after attention
  short* Ctb = Kb2;
  float* Vp0 = Kp0;
  float* Vp1 = Kp1;
  float* P1o = Kp0;
  float* Csel = Qb;                         // 3.41 MB, after gather_q
  short* Woa = Wqa; short* Wob = Wqb;
  short* Wva = Wka; short* Wvb = Wkb;

  char* sm = base + MB(100);                // over dead Wkc
  double* kpart = (double*)sm;              sm += 524288;
  double* kbar  = (double*)sm;              sm += 16384;
  double* wtil  = (double*)sm;              sm += 262144;
  double* s0    = (double*)sm;              sm += 512;
  float*  invq  = (float*)sm;               sm += 262144;
  float*  dotq  = (float*)sm;               sm += 262144;
  float*  msb   = (float*)sm;               sm += 262144;
  int*    sel   = (int*)sm;

  // ---- phase 0: splits (Q 2-way, K 3-way; Wq 2-way, Wk 3-way)
  {
    SplitArgs a;
    a.d[0] = {queries, Qa, Qb2, nullptr, 2};
    a.d[1] = {keys,    Ka, Kb2, Kc, 3};
    msplit_k<<<dim3(2048,1,2), 256, 0, stream>>>(a);
  }
  {
    SplitArgs a;
    a.d[0] = {Wq, Wqa, Wqb, nullptr, 2};
    a.d[1] = {Wk, Wka, Wkb, Wkc, 3};
    msplit_k<<<dim3(512,1,2), 256, 0, stream>>>(a);
  }
  // ---- phase 1: Q (3-product) + K (6-product, split-K 2-way) fused, 768 blocks
  {
    GemmArgs g;
    g.d[0] = {{Qa,Qb2,nullptr}, {Wqa,Wqb,nullptr}, bq, Qb, 0, 96};
    g.d[1] = {{Ka,Kb2,Kc}, {Wka,Wkb,Wkc}, nullptr, Kp0, 0, 96};
    g.d[2] = {{Ka,Kb2,Kc}, {Wka,Wkb,Wkc}, nullptr, Kp1, 96, 192};
    gemm_tile_k<true><<<dim3(8,32,3), 256, 0, stream>>>(g);
  }
  // ---- K combine (+norm +bf16 +kbar partials), then ranking chain
  combine_k<<<NBH*32, 256, 0, stream>>>(Kp0, Kp1, bk, Kbf, kpart);
  kbar2_k<<<NBH, 64, 0, stream>>>(kpart, kbar);
  invnorm_k<<<NRTOT/256, 256, 0, stream>>>(Qb, invq);
  wtilde_k<<<dim3(NBH,4), 256, 0, stream>>>(Wq, bq, kbar, wtil, s0);
  dotq_k<<<NROWS, 256, 0, stream>>>(queries, wtil, dotq);
  msq_k<<<NRTOT/256, 256, 0, stream>>>(dotq, s0, invq, msb);
  select_rank_k<<<NBH*8, 256, 0, stream>>>(msb, sel);

  // ---- phase 2: V (3-product, split-K 2-way over z)
  {
    SplitArgs a;
    a.d[0] = {values, Va, Vb2, nullptr, 2};
    a.d[1] = a.d[0];
    msplit_k<<<dim3(2048,1,1), 256, 0, stream>>>(a);
  }
  {
    SplitArgs a;
    a.d[0] = {Wv, Wva, Wvb, nullptr, 2};
    a.d[1] = {Wo, Woa, Wob, nullptr, 2};
    msplit_k<<<dim3(512,1,2), 256, 0, stream>>>(a);
  }
  {
    GemmArgs g;
    g.d[0] = {{Va,Vb2,nullptr}, {Wva,Wvb,nullptr}, nullptr, Vp0, 0, 48};
    g.d[1] = {{Va,Vb2,nullptr}, {Wva,Wvb,nullptr}, nullptr, Vp1, 48, 96};
    g.d[2] = g.d[0];
    gemm_tile_k<true><<<dim3(8,32,2), 256, 0, stream>>>(g);
  }
  transpose_v_k<<<NBH*32, 256, 0, stream>>>(Vp0, Vp1, bv, Vt);
  gather_q_k<<<MTOT/4, 256, 0, stream>>>(Qb, sel, Qg);

  // ---- phase 3: attention (two m-halves share the 26 MB S buffer)
  for (int half = 0; half < 2; ++half) {
    const int mbase = half * MHALF;
    sgemm_qk_k<<<dim3(MHALF/64, NL/64), 256, 0, stream>>>(Qg, Kbf, Sh, mbase);
    softmax_k<<<MHALF, 256, 0, stream>>>(Sh);
    pgemm_pv_k<<<MHALF/32, 256, 0, stream>>>(Sh, Vt, Csel, mbase);
  }

  // ---- phase 4: output projection (split-K 2-way) + combine
  zero_f4<<<4096, 256, 0, stream>>>((float4*)Cta);            // zeroes Cta+Ctb (16 MB)
  scatter_split2_k<<<(NBH*NU + 3)/4, 256, 0, stream>>>(Csel, sel, Cta, Ctb);
  {
    GemmArgs g;
    g.d[0] = {{Cta,Ctb,nullptr}, {Woa,Wob,nullptr}, nullptr, out, 0, 48};
    g.d[1] = {{Cta,Ctb,nullptr}, {Woa,Wob,nullptr}, nullptr, P1o, 48, 96};
    g.d[2] = g.d[0];
    gemm_tile_k<false><<<dim3(8,32,2), 256, 0, stream>>>(g);
  }
  oadd_k<<<4096, 256, 0, stream>>>(out, P1o, bo);
}

// Round 6
// 372.106 us; speedup vs baseline: 7.2278x; 1.1950x over previous
//
#include <hip/hip_runtime.h>
#include <math.h>

// Problem constants (fixed by setup_inputs)
#define NB 2
#define NL 2048
#define NH 16
#define ND 64
#define NDM 1024
#define NU 409                  // max(1, 2048 // 5)
#define NUP 416                 // NU padded to multiple of 32; 416 = 26*16 = 13*32
#define NBH (NB*NH)             // 32
#define NROWS (NB*NL)           // 4096
#define NRTOT (NB*NH*NL)        // 65536
#define MTOT (NBH*NUP)          // 13312

typedef short bf16x8 __attribute__((ext_vector_type(8)));
typedef short bf16x4 __attribute__((ext_vector_type(4)));
typedef float f32x4  __attribute__((ext_vector_type(4)));

__device__ __forceinline__ short f2bf(float x) {   // RNE f32 -> bf16
  unsigned u = __float_as_uint(x);
  return (short)((u + 0x7FFFu + ((u >> 16) & 1u)) >> 16);
}
__device__ __forceinline__ float bf2f(short s) {
  return __uint_as_float(((unsigned)(unsigned short)s) << 16);
}

__device__ __forceinline__ void gload16(const short* g, short* l) {
  __builtin_amdgcn_global_load_lds(
      (const __attribute__((address_space(1))) void*)g,
      (__attribute__((address_space(3))) void*)l, 16, 0, 0);
}

// ---------------------------------------------------------------- zero fill
__global__ __launch_bounds__(256) void zero_f4(float4* __restrict__ p) {
  const size_t i = (size_t)blockIdx.x * 256 + threadIdx.x;
  p[i] = make_float4(0.f, 0.f, 0.f, 0.f);
}

// ---------------------------------------------------------------- multi-tensor f32 -> bf16 splits
struct SplitDesc { const float* in; short* a; short* b; short* c; int nc; };
struct SplitArgs { SplitDesc d[2]; };

__global__ __launch_bounds__(256) void msplit_k(SplitArgs args) {
  const SplitDesc d = args.d[blockIdx.z];
  const size_t i = (size_t)blockIdx.x * 256 + threadIdx.x;
  const float4 x0 = ((const float4*)d.in)[2*i];
  const float4 x1 = ((const float4*)d.in)[2*i + 1];
  float x[8] = {x0.x,x0.y,x0.z,x0.w, x1.x,x1.y,x1.z,x1.w};
  bf16x8 va, vb, vc;
  #pragma unroll
  for (int j = 0; j < 8; ++j) {
    const short A = f2bf(x[j]);
    const float r1 = x[j] - bf2f(A);
    const short B = f2bf(r1);
    va[j] = A; vb[j] = B;
    vc[j] = f2bf(r1 - bf2f(B));
  }
  *(bf16x8*)(d.a + 8*i) = va;
  *(bf16x8*)(d.b + 8*i) = vb;
  if (d.nc == 3) *(bf16x8*)(d.c + 8*i) = vc;
}

// ---------------------------------------------------------------- tiled split-bf16 MFMA GEMM (m97 structure)
// chunk pairs: c0 (a,a), c1 (a,b), c2 (b,a), c3 (a,c), c4 (c,a), c5 (b,b)
// 128x128 tile, BK=32, 4 waves (2x2), each wave 64x64 = 4x4 16x16 frags.
// XCD-aware bijective block swizzle (T1): nwg % 8 == 0 for all launches here.
struct GemmDesc {
  const short* X[3];
  const short* W[3];
  const float* bias;    // may be null
  float* C;
  int sbeg, send;       // step range; one step = 32 k-elems; chunk = step>>5
};
struct GemmArgs { GemmDesc d[3]; };

template<bool SC>
__global__ __launch_bounds__(256) void gemm_tile_k(GemmArgs args) {
  __shared__ short As[128*32];   // 8 KB, row-major [m][k]
  __shared__ short Bs[128*32];   // 8 KB, row-major [n][k]
  // --- T1 swizzle: consecutive remapped ids share X panels on one XCD
  const int nwg = gridDim.x * gridDim.y * gridDim.z;
  int id = blockIdx.x + (gridDim.x * (blockIdx.y + gridDim.y * blockIdx.z));
  id = (id & 7) * (nwg >> 3) + (id >> 3);
  const int bx = id & 7;            // gridDim.x == 8
  const int by = (id >> 3) & 31;    // gridDim.y == 32
  const int bz = id >> 8;
  const GemmDesc d = args.d[bz];
  const int tid = threadIdx.x;
  const int wv = tid >> 6, L = tid & 63;
  const int lr = L & 15, lg = L >> 4;
  const int n0 = bx << 7, m0 = by << 7;
  const int wm = (wv >> 1) << 6, wn = (wv & 1) << 6;

  const int srow = (wv << 4) + (L >> 2);
  const int scol = (L & 3) << 3;
  short* const asd = As + (tid << 3);
  short* const bsd = Bs + (tid << 3);

  f32x4 acc[4][4];
  #pragma unroll
  for (int i = 0; i < 4; ++i)
    #pragma unroll
    for (int j = 0; j < 4; ++j) acc[i][j] = (f32x4){0.f,0.f,0.f,0.f};

  for (int step = d.sbeg; step < d.send; ++step) {
    const int c = step >> 5, kk = (step & 31) << 5;
    const short *Xg, *Wg;
    switch (c) {
      case 0:  Xg = d.X[0]; Wg = d.W[0]; break;
      case 1:  Xg = d.X[0]; Wg = d.W[1]; break;
      case 2:  Xg = d.X[1]; Wg = d.W[0]; break;
      case 3:  Xg = d.X[0]; Wg = d.W[2]; break;
      case 4:  Xg = d.X[2]; Wg = d.W[0]; break;
      default: Xg = d.X[1]; Wg = d.W[1]; break;
    }
    const short* xg = Xg + (size_t)(m0 + srow) * NDM + kk + scol;
    const short* wg = Wg + (size_t)(n0 + srow) * NDM + kk + scol;
    gload16(xg,              asd);
    gload16(xg + (NDM << 6), asd + 2048);   // +64 rows
    gload16(wg,              bsd);
    gload16(wg + (NDM << 6), bsd + 2048);
    __syncthreads();
    bf16x8 af[4], bf[4];
    #pragma unroll
    for (int t = 0; t < 4; ++t) {
      af[t] = *(const bf16x8*)(As + ((wm + (t << 4) + lr) << 5) + (lg << 3));
      bf[t] = *(const bf16x8*)(Bs + ((wn + (t << 4) + lr) << 5) + (lg << 3));
    }
    #pragma unroll
    for (int mt = 0; mt < 4; ++mt)
      #pragma unroll
      for (int nt = 0; nt < 4; ++nt)
        acc[mt][nt] = __builtin_amdgcn_mfma_f32_16x16x32_bf16(bf[nt], af[mt], acc[mt][nt], 0, 0, 0);
    __syncthreads();
  }

  #pragma unroll
  for (int nt = 0; nt < 4; ++nt) {
    const int n = n0 + wn + (nt << 4) + (lg << 2);
    float4 b4 = make_float4(0.f, 0.f, 0.f, 0.f);
    if (d.bias) b4 = *(const float4*)(d.bias + n);
    #pragma unroll
    for (int mt = 0; mt < 4; ++mt) {
      f32x4 a = acc[mt][nt];
      a[0] += b4.x; a[1] += b4.y; a[2] += b4.z; a[3] += b4.w;
      const int m = m0 + wm + (mt << 4) + lr;
      if (SC) {   // scatter into (B,H,L,D)
        const int bb = m >> 11, ll = m & (NL - 1);
        const int hh = n >> 6, dd = n & 63;
        *(f32x4*)(d.C + (((size_t)(bb*NH + hh)*NL + ll) << 6) + dd) = a;
      } else {
        *(f32x4*)(d.C + ((size_t)m << 10) + n) = a;
      }
    }
  }
}

// ---------------------------------------------------------------- K combine: Kp0+Kp1+bias -> Kbf bf16, khat partials
__global__ __launch_bounds__(256) void combine_k(const float* __restrict__ Kp0,
                                                 const float* __restrict__ Kp1,
                                                 const float* __restrict__ bk,
                                                 short* __restrict__ Kbf,
                                                 double* __restrict__ kpart) {
  __shared__ double sm[4][64];
  const int bh = blockIdx.x >> 5, seg = blockIdx.x & 31;
  const int g = threadIdx.x >> 6, d = threadIdx.x & 63;
  const int h = bh & 15;
  const float bias = bk[(h << 6) + d];
  double acc = 0.0;
  #pragma unroll 4
  for (int i = 0; i < 16; ++i) {
    const int l = (seg << 6) + (i << 2) + g;
    const size_t o = (((size_t)bh * NL + l) << 6) + d;
    const float k = Kp0[o] + Kp1[o] + bias;
    float ss = k * k;
    #pragma unroll
    for (int off = 32; off > 0; off >>= 1) ss += __shfl_xor(ss, off);
    const double inv = 1.0 / sqrt((double)ss);
    Kbf[o] = f2bf(k);
    acc += (double)k * inv;
  }
  sm[g][d] = acc;
  __syncthreads();
  if (threadIdx.x < 64)
    kpart[((((size_t)bh << 5) + seg) << 6) + threadIdx.x] =
        sm[0][threadIdx.x] + sm[1][threadIdx.x] + sm[2][threadIdx.x] + sm[3][threadIdx.x];
}

// ---------------------------------------------------------------- kbar: combine 32 segments (f64)
__global__ __launch_bounds__(64) void kbar2_k(const double* __restrict__ kpart,
                                              double* __restrict__ kbar) {
  const int bh = blockIdx.x, d = threadIdx.x;
  double s = 0.0;
  #pragma unroll
  for (int seg = 0; seg < 32; ++seg)
    s += kpart[((((size_t)bh << 5) + seg) << 6) + d];
  kbar[(bh << 6) + d] = s * (1.0 / NL);
}

// ---------------------------------------------------------------- wtilde[bh][j] = sum_d Wq[h*64+d][j]*kbar[bh][d]; s0 = bq.kbar
__global__ __launch_bounds__(256) void wtilde_k(const float* __restrict__ Wq,
                                                const float* __restrict__ bq,
                                                const double* __restrict__ kbar,
                                                double* __restrict__ wt,
                                                double* __restrict__ s0) {
  __shared__ double kb[64];
  const int bh = blockIdx.x, h = bh & 15;
  const int tid = threadIdx.x;
  if (tid < 64) kb[tid] = kbar[(bh << 6) + tid];
  __syncthreads();
  const int j = (blockIdx.y << 8) + tid;
  double a = 0.0;
  #pragma unroll 8
  for (int d = 0; d < 64; ++d)
    a += (double)Wq[(((size_t)((h << 6) + d)) << 10) + j] * kb[d];
  wt[((size_t)bh << 10) + j] = a;
  if (blockIdx.y == 0 && tid < 64) {
    double p = (double)bq[(h << 6) + tid] * kb[tid];
    #pragma unroll
    for (int off = 32; off > 0; off >>= 1) p += __shfl_xor(p, off);
    if (tid == 0) s0[bh] = p;
  }
}

// ---------------------------------------------------------------- dotq[bh][l] = x_row . wt[bh]  (f64 accum)
__global__ __launch_bounds__(256) void dotq_k(const float* __restrict__ x,
                                              const double* __restrict__ wt,
                                              float* __restrict__ dotq) {
  __shared__ float xs[1024];
  __shared__ double sm[16][16];
  const int r = blockIdx.x, b = r >> 11, l = r & (NL - 1);
  const int tid = threadIdx.x;
  ((float4*)xs)[tid] = ((const float4*)(x + ((size_t)r << 10)))[tid];
  __syncthreads();
  const int h = tid >> 4, t = tid & 15;
  const double* w = wt + ((size_t)((b << 4) + h) << 10);
  double a = 0.0;
  #pragma unroll 8
  for (int i = 0; i < 64; ++i) {
    const int j = t + (i << 4);
    a += (double)xs[j] * w[j];
  }
  sm[h][t] = a;
  __syncthreads();
  if (tid < 16) {
    double s = 0.0;
    #pragma unroll
    for (int t2 = 0; t2 < 16; ++t2) s += sm[tid][t2];
    dotq[(((size_t)(b << 4) + tid) << 11) + l] = (float)s;
  }
}

// ---------------------------------------------------------------- Q row inv-norms (f64)
__global__ __launch_bounds__(256) void invnorm_k(const float* __restrict__ Qb,
                                                 float* __restrict__ invn) {
  const int r = blockIdx.x * 256 + threadIdx.x;
  const float4* p = (const float4*)(Qb + ((size_t)r << 6));
  double s = 0.0;
  #pragma unroll
  for (int i = 0; i < 16; ++i) {
    const float4 v = p[i];
    s += (double)v.x*v.x + (double)v.y*v.y + (double)v.z*v.z + (double)v.w*v.w;
  }
  invn[r] = (float)(1.0 / sqrt(s));
}

// ---------------------------------------------------------------- ms = (dotq + s0) * invq
__global__ __launch_bounds__(256) void msq_k(const float* __restrict__ dotq,
                                             const double* __restrict__ s0,
                                             const float* __restrict__ invq,
                                             float* __restrict__ ms) {
  const int r = blockIdx.x * 256 + threadIdx.x;
  const int bh = r >> 11;
  ms[r] = (float)(((double)dotq[r] + s0[bh]) * (double)invq[r]);
}

// ---------------------------------------------------------------- rank-based top-NU selection
__global__ __launch_bounds__(256) void select_rank_k(const float* __restrict__ ms,
                                                     int* __restrict__ sel) {
  __shared__ unsigned long long keys[NL];
  const int bh = blockIdx.x >> 3, seg = blockIdx.x & 7;
  const int tid = threadIdx.x;
  for (int l = tid; l < NL; l += 256) {
    unsigned u = __float_as_uint(ms[(size_t)bh * NL + l]);
    u = (u & 0x80000000u) ? ~u : (u | 0x80000000u);   // order-preserving map
    keys[l] = ((unsigned long long)u << 32) | (unsigned)(NL - 1 - l);
  }
  __syncthreads();
  const int r = (seg << 8) + tid;
  const unsigned long long mine = keys[r];
  int cnt = 0;
  #pragma unroll 8
  for (int l = 0; l < NL; ++l) cnt += (keys[l] > mine) ? 1 : 0;
  if (cnt < NU) sel[bh*NU + cnt] = r;
}

// ---------------------------------------------------------------- V = Vp0+Vp1+bv, transpose -> Vt (bh,d,l) bf16
__global__ __launch_bounds__(256) void transpose_v_k(const float* __restrict__ V0,
                                                     const float* __restrict__ V1,
                                                     const float* __restrict__ bv,
                                                     short* __restrict__ Vt) {
  __shared__ float Ts[64][65];
  const int bh = blockIdx.x >> 5, lt = blockIdx.x & 31;
  const int l0 = lt << 6, tid = threadIdx.x;
  const int lr = tid >> 2, j = tid & 3;
  const int h = bh & 15;
  const size_t rowo = ((size_t)bh*NL + l0 + lr) << 6;
  #pragma unroll
  for (int s = 0; s < 4; ++s) {
    const int dd = (j + 4*s) << 2;
    float4 v = *(const float4*)(V0 + rowo + dd);
    const float4 q = *(const float4*)(V1 + rowo + dd);
    const float4 b4 = *(const float4*)(bv + (h << 6) + dd);
    v.x += q.x + b4.x; v.y += q.y + b4.y; v.z += q.z + b4.z; v.w += q.w + b4.w;
    Ts[lr][dd+0] = v.x; Ts[lr][dd+1] = v.y; Ts[lr][dd+2] = v.z; Ts[lr][dd+3] = v.w;
  }
  __syncthreads();
  const int d = tid >> 2, lc = (tid & 3) << 4;
  short* dst = Vt + ((size_t)bh*ND + d) * NL + l0 + lc;
  bf16x8 o0, o1;
  #pragma unroll
  for (int i = 0; i < 8; ++i) {
    o0[i] = f2bf(Ts[lc + i][d]);
    o1[i] = f2bf(Ts[lc + 8 + i][d]);
  }
  *(bf16x8*)dst = o0;
  *(bf16x8*)(dst + 8) = o1;
}

// ---------------------------------------------------------------- gather selected Q rows -> bf16 [MTOT][64]
__global__ __launch_bounds__(256) void gather_q_k(const float* __restrict__ Qb,
                                                  const int* __restrict__ sel,
                                                  short* __restrict__ Qg) {
  const int row = blockIdx.x * 4 + (threadIdx.x >> 6);
  const int d = threadIdx.x & 63;
  const int bh = row / NUP, u = row - bh * NUP;
  float v = 0.f;
  if (u < NU) {
    const int lq = sel[bh*NU + u];
    v = Qb[(((size_t)bh*NL + lq) << 6) + d];
  }
  Qg[((size_t)row << 6) + d] = f2bf(v);
}

// ---------------------------------------------------------------- fused attention: QK^T -> softmax -> PV per 32-row block
// 416 blocks (13 per bh), 8 waves. S[32][2048] bf16 in LDS with XOR swizzle
// byte ^= ((row&7)<<4) (write side == read side, G4/T2 involution).
__global__ __launch_bounds__(512) void fattn_k(const short* __restrict__ Qg,
                                               const short* __restrict__ Kbf,
                                               const short* __restrict__ Vt,
                                               float* __restrict__ Csel) {
  __shared__ short S[32*2048];        // 128 KB, row stride 4096 B
  __shared__ float inv_s[32];
  // XCD swizzle: 416 = 8*52; 4 whole bh per XCD -> K/V L2 locality
  int bid = blockIdx.x;
  bid = (bid & 7) * 52 + (bid >> 3);
  const int m0 = bid << 5;
  const int bh = m0 / NUP;
  const int tid = threadIdx.x;
  const int w = tid >> 6, L = tid & 63;
  const int lr = L & 15, lg = L >> 4;

  // ---- QK^T: wave w covers n in [w*256, (w+1)*256); all 32 m rows
  bf16x8 qf[2][2];
  #pragma unroll
  for (int mt = 0; mt < 2; ++mt) {
    const short* qp = Qg + (((size_t)m0 + mt*16 + lr) << 6) + lg*8;
    qf[mt][0] = *(const bf16x8*)qp;
    qf[mt][1] = *(const bf16x8*)(qp + 32);
  }
  const int nb = w << 8;
  const short* kb0 = Kbf + (((size_t)bh*NL + nb + lr) << 6) + lg*8;
  #pragma unroll 2
  for (int nt = 0; nt < 16; ++nt) {
    const short* kp = kb0 + ((size_t)nt << 10);       // +16 rows * 64
    const bf16x8 kf0 = *(const bf16x8*)kp;
    const bf16x8 kf1 = *(const bf16x8*)(kp + 32);
    #pragma unroll
    for (int mt = 0; mt < 2; ++mt) {
      f32x4 a = {0.f,0.f,0.f,0.f};
      a = __builtin_amdgcn_mfma_f32_16x16x32_bf16(kf0, qf[mt][0], a, 0, 0, 0);
      a = __builtin_amdgcn_mfma_f32_16x16x32_bf16(kf1, qf[mt][1], a, 0, 0, 0);
      // lane holds D[n = nb+nt*16+lg*4+r][m = mt*16+lr]; store scaled to S[m][n]
      const int m = mt*16 + lr;
      bf16x4 o;
      #pragma unroll
      for (int r = 0; r < 4; ++r) o[r] = f2bf(a[r] * 0.125f);
      const int byteoff = (m << 12) + ((((nb + nt*16 + lg*4) << 1)) ^ ((m & 7) << 4));
      *(bf16x4*)((char*)S + byteoff) = o;
    }
  }
  __syncthreads();

  // ---- softmax: wave w handles rows w*4 .. w*4+3 (full 2048 row in registers: 32/lane)
  #pragma unroll
  for (int j = 0; j < 4; ++j) {
    const int R = (w << 2) + j;
    char* rowp = (char*)S + (R << 12);
    const int sw = (R & 7) << 4;
    bf16x8 v[4];
    #pragma unroll
    for (int i = 0; i < 4; ++i)
      v[i] = *(const bf16x8*)(rowp + (((L << 6) + (i << 4)) ^ sw));
    float f[32];
    #pragma unroll
    for (int i = 0; i < 4; ++i)
      #pragma unroll
      for (int e = 0; e < 8; ++e) f[i*8+e] = bf2f(v[i][e]);
    float mx = f[0];
    #pragma unroll
    for (int i = 1; i < 32; ++i) mx = fmaxf(mx, f[i]);
    #pragma unroll
    for (int off = 32; off > 0; off >>= 1) mx = fmaxf(mx, __shfl_xor(mx, off));
    float sum = 0.f;
    #pragma unroll
    for (int i = 0; i < 32; ++i) { f[i] = __expf(f[i] - mx); sum += f[i]; }
    #pragma unroll
    for (int off = 32; off > 0; off >>= 1) sum += __shfl_xor(sum, off);
    bf16x8 p[4];
    #pragma unroll
    for (int i = 0; i < 4; ++i)
      #pragma unroll
      for (int e = 0; e < 8; ++e) p[i][e] = f2bf(f[i*8+e]);
    #pragma unroll
    for (int i = 0; i < 4; ++i)
      *(bf16x8*)(rowp + (((L << 6) + (i << 4)) ^ sw)) = p[i];
    if (L == 0) inv_s[R] = 1.f / sum;
  }
  __syncthreads();

  // ---- PV: wave w -> mt = w&1 (16 rows), dt = w>>1 (16 d-cols); full K=2048
  {
    const int mt = w & 1, dt = w >> 1;
    const int m = mt*16 + lr;
    const char* arow = (const char*)S + (m << 12);
    const int sw = (m & 7) << 4;
    const short* vrow = Vt + (((size_t)bh*ND + dt*16 + lr) << 11) + lg*8;
    f32x4 acc0 = {0.f,0.f,0.f,0.f}, acc1 = {0.f,0.f,0.f,0.f};
    for (int k0 = 0; k0 < NL; k0 += 64) {
      const bf16x8 p0 = *(const bf16x8*)(arow + ((((k0 + lg*8) << 1)) ^ sw));
      const bf16x8 p1 = *(const bf16x8*)(arow + ((((k0 + 32 + lg*8) << 1)) ^ sw));
      const bf16x8 v0 = *(const bf16x8*)(vrow + k0);
      const bf16x8 v1 = *(const bf16x8*)(vrow + k0 + 32);
      acc0 = __builtin_amdgcn_mfma_f32_16x16x32_bf16(p0, v0, acc0, 0, 0, 0);
      acc1 = __builtin_amdgcn_mfma_f32_16x16x32_bf16(p1, v1, acc1, 0, 0, 0);
    }
    // D: col = lr = d, row = lg*4+r = m-within-16
    float* c = Csel + (((size_t)m0 + mt*16 + (lg << 2)) << 6) + dt*16 + lr;
    #pragma unroll
    for (int r = 0; r < 4; ++r)
      c[(size_t)(r << 6)] = (acc0[r] + acc1[r]) * inv_s[mt*16 + (lg << 2) + r];
  }
}

// ---------------------------------------------------------------- scatter+split Csel rows into zeroed Cta/Ctb
__global__ __launch_bounds__(256) void scatter_split2_k(const float* __restrict__ Csel,
                                                        const int* __restrict__ sel,
                                                        short* __restrict__ Ca,
                                                        short* __restrict__ Cb) {
  const int r = blockIdx.x * 4 + (threadIdx.x >> 6);
  const int d = threadIdx.x & 63;
  if (r >= NBH * NU) return;
  const int bh = r / NU, u = r - bh * NU;
  const int b = bh >> 4, h = bh & 15;
  const int lq = sel[bh*NU + u];
  const float x = Csel[(((size_t)bh*NUP + u) << 6) + d];
  const short A = f2bf(x);
  const size_t o = ((((size_t)b << 11) + lq) << 10) + (h << 6) + d;
  Ca[o] = A;
  Cb[o] = f2bf(x - bf2f(A));
}

// ---------------------------------------------------------------- out += P1 + bias
__global__ __launch_bounds__(256) void oadd_k(float* __restrict__ out,
                                              const float* __restrict__ P1,
                                              const float* __restrict__ bo) {
  const size_t i4 = (size_t)blockIdx.x * 256 + threadIdx.x;
  const size_t i = i4 << 2;
  float4 a = *(float4*)(out + i);
  const float4 b = *(const float4*)(P1 + i);
  const float4 c = *(const float4*)(bo + ((i4 & 255) << 2));
  a.x += b.x + c.x; a.y += b.y + c.y; a.z += b.z + c.z; a.w += b.w + c.w;
  *(float4*)(out + i) = a;
}

// ---------------------------------------------------------------- launch
extern "C" void kernel_launch(void* const* d_in, const int* in_sizes, int n_in,
                              void* d_out, int out_size, void* d_ws, size_t ws_size,
                              hipStream_t stream)
{
  (void)in_sizes; (void)n_in; (void)out_size; (void)ws_size;
  const float* queries = (const float*)d_in[0];
  const float* keys    = (const float*)d_in[1];
  const float* values  = (const float*)d_in[2];
  const float* Wq = (const float*)d_in[3];  const float* bq = (const float*)d_in[4];
  const float* Wk = (const float*)d_in[5];  const float* bk = (const float*)d_in[6];
  const float* Wv = (const float*)d_in[7];  const float* bv = (const float*)d_in[8];
  const float* Wo = (const float*)d_in[9];  const float* bo = (const float*)d_in[10];
  float* out = (float*)d_out;

  char* base = (char*)d_ws;
  #define MB(x) ((size_t)(x) << 20)

  // Region map (time-multiplexed; same footprint as round-5, S-buffer freed)
  short* Qa   = (short*)(base + MB(0));    // queries split a      -> Kbf after phase1
  short* Qb2  = (short*)(base + MB(8));    // queries split b      -> Vt
  short* Ka   = (short*)(base + MB(16));   // keys split a         -> Va -> Cta
  short* Kb2  = (short*)(base + MB(24));   // keys split b         -> Vb2 -> Ctb
  short* Kc   = (short*)(base + MB(32));   // keys split c         (dead after ph1)
  float* Qb   = (float*)(base + MB(44));   // Q proj f32           -> Csel after gather
  float* Kp0  = (float*)(base + MB(60));   // K partial 0 -> Vp0 -> P1o
  float* Kp1  = (float*)(base + MB(76));   // K partial 1 -> Vp1
  short* Wqa  = (short*)(base + MB(92));   // -> Woa
  short* Wqb  = (short*)(base + MB(94));   // -> Wob
  short* Wka  = (short*)(base + MB(96));   // -> Wva
  short* Wkb  = (short*)(base + MB(98));   // -> Wvb
  short* Wkc  = (short*)(base + MB(100));  // -> smalls after phase1
  short* Qg   = (short*)(base + MB(102));  // 1.7 MB

  // aliases
  short* Kbf = Qa;
  short* Vt  = Qb2;
  short* Va  = Ka;
  short* Vb2 = Kb2;
  short* Cta = Ka;
  short* Ctb = Kb2;
  float* Vp0 = Kp0;
  float* Vp1 = Kp1;
  float* P1o = Kp0;
  float* Csel = Qb;
  short* Woa = Wqa; short* Wob = Wqb;
  short* Wva = Wka; short* Wvb = Wkb;

  char* sm = base + MB(100);                // over dead Wkc
  double* kpart = (double*)sm;              sm += 524288;
  double* kbar  = (double*)sm;              sm += 16384;
  double* wtil  = (double*)sm;              sm += 262144;
  double* s0    = (double*)sm;              sm += 512;
  float*  invq  = (float*)sm;               sm += 262144;
  float*  dotq  = (float*)sm;               sm += 262144;
  float*  msb   = (float*)sm;               sm += 262144;
  int*    sel   = (int*)sm;

  // ---- phase 0: splits (Q 2-way, K 3-way; Wq 2-way, Wk 3-way)
  {
    SplitArgs a;
    a.d[0] = {queries, Qa, Qb2, nullptr, 2};
    a.d[1] = {keys,    Ka, Kb2, Kc, 3};
    msplit_k<<<dim3(2048,1,2), 256, 0, stream>>>(a);
  }
  {
    SplitArgs a;
    a.d[0] = {Wq, Wqa, Wqb, nullptr, 2};
    a.d[1] = {Wk, Wka, Wkb, Wkc, 3};
    msplit_k<<<dim3(512,1,2), 256, 0, stream>>>(a);
  }
  // ---- phase 1: Q (3-product) + K (6-product, split-K 2-way) fused, 768 blocks
  {
    GemmArgs g;
    g.d[0] = {{Qa,Qb2,nullptr}, {Wqa,Wqb,nullptr}, bq, Qb, 0, 96};
    g.d[1] = {{Ka,Kb2,Kc}, {Wka,Wkb,Wkc}, nullptr, Kp0, 0, 96};
    g.d[2] = {{Ka,Kb2,Kc}, {Wka,Wkb,Wkc}, nullptr, Kp1, 96, 192};
    gemm_tile_k<true><<<dim3(8,32,3), 256, 0, stream>>>(g);
  }
  // ---- K combine (+norm +bf16 +kbar partials), then ranking chain
  combine_k<<<NBH*32, 256, 0, stream>>>(Kp0, Kp1, bk, Kbf, kpart);
  kbar2_k<<<NBH, 64, 0, stream>>>(kpart, kbar);
  invnorm_k<<<NRTOT/256, 256, 0, stream>>>(Qb, invq);
  wtilde_k<<<dim3(NBH,4), 256, 0, stream>>>(Wq, bq, kbar, wtil, s0);
  dotq_k<<<NROWS, 256, 0, stream>>>(queries, wtil, dotq);
  msq_k<<<NRTOT/256, 256, 0, stream>>>(dotq, s0, invq, msb);
  select_rank_k<<<NBH*8, 256, 0, stream>>>(msb, sel);

  // ---- phase 2: V (3-product, split-K 2-way over z)
  {
    SplitArgs a;
    a.d[0] = {values, Va, Vb2, nullptr, 2};
    a.d[1] = a.d[0];
    msplit_k<<<dim3(2048,1,1), 256, 0, stream>>>(a);
  }
  {
    SplitArgs a;
    a.d[0] = {Wv, Wva, Wvb, nullptr, 2};
    a.d[1] = {Wo, Woa, Wob, nullptr, 2};
    msplit_k<<<dim3(512,1,2), 256, 0, stream>>>(a);
  }
  {
    GemmArgs g;
    g.d[0] = {{Va,Vb2,nullptr}, {Wva,Wvb,nullptr}, nullptr, Vp0, 0, 48};
    g.d[1] = {{Va,Vb2,nullptr}, {Wva,Wvb,nullptr}, nullptr, Vp1, 48, 96};
    g.d[2] = g.d[0];
    gemm_tile_k<true><<<dim3(8,32,2), 256, 0, stream>>>(g);
  }
  transpose_v_k<<<NBH*32, 256, 0, stream>>>(Vp0, Vp1, bv, Vt);
  gather_q_k<<<MTOT/4, 256, 0, stream>>>(Qb, sel, Qg);

  // ---- phase 3: fused attention (one launch)
  fattn_k<<<MTOT/32, 512, 0, stream>>>(Qg, Kbf, Vt, Csel);

  // ---- phase 4: output projection (split-K 2-way) + combine
  zero_f4<<<4096, 256, 0, stream>>>((float4*)Cta);            // zeroes Cta+Ctb (16 MB)
  scatter_split2_k<<<(NBH*NU + 3)/4, 256, 0, stream>>>(Csel, sel, Cta, Ctb);
  {
    GemmArgs g;
    g.d[0] = {{Cta,Ctb,nullptr}, {Woa,Wob,nullptr}, nullptr, out, 0, 48};
    g.d[1] = {{Cta,Ctb,nullptr}, {Woa,Wob,nullptr}, nullptr, P1o, 48, 96};
    g.d[2] = g.d[0];
    gemm_tile_k<false><<<dim3(8,32,2), 256, 0, stream>>>(g);
  }
  oadd_k<<<4096, 256, 0, stream>>>(out, P1o, bo);
}

// Round 7
// 335.605 us; speedup vs baseline: 8.0139x; 1.1088x over previous
//
#include <hip/hip_runtime.h>
#include <math.h>

// Problem constants (fixed by setup_inputs)
#define NB 2
#define NL 2048
#define NH 16
#define ND 64
#define NDM 1024
#define NU 409                  // max(1, 2048 // 5)
#define NUP 416                 // NU padded to multiple of 32; 416 = 26*16 = 13*32
#define NBH (NB*NH)             // 32
#define NROWS (NB*NL)           // 4096
#define NRTOT (NB*NH*NL)        // 65536
#define MTOT (NBH*NUP)          // 13312

typedef short bf16x8 __attribute__((ext_vector_type(8)));
typedef short bf16x4 __attribute__((ext_vector_type(4)));
typedef float f32x4  __attribute__((ext_vector_type(4)));

__device__ __forceinline__ short f2bf(float x) {   // RNE f32 -> bf16
  unsigned u = __float_as_uint(x);
  return (short)((u + 0x7FFFu + ((u >> 16) & 1u)) >> 16);
}
__device__ __forceinline__ float bf2f(short s) {
  return __uint_as_float(((unsigned)(unsigned short)s) << 16);
}

__device__ __forceinline__ void gload16(const short* g, short* l) {
  __builtin_amdgcn_global_load_lds(
      (const __attribute__((address_space(1))) void*)g,
      (__attribute__((address_space(3))) void*)l, 16, 0, 0);
}

// ---------------------------------------------------------------- multi-tensor f32 -> bf16 splits
struct SplitDesc { const float* in; short* a; short* b; short* c; int nc; };
struct SplitArgs { SplitDesc d[2]; };

__global__ __launch_bounds__(256) void msplit_k(SplitArgs args) {
  const SplitDesc d = args.d[blockIdx.z];
  const size_t i = (size_t)blockIdx.x * 256 + threadIdx.x;
  const float4 x0 = ((const float4*)d.in)[2*i];
  const float4 x1 = ((const float4*)d.in)[2*i + 1];
  float x[8] = {x0.x,x0.y,x0.z,x0.w, x1.x,x1.y,x1.z,x1.w};
  bf16x8 va, vb, vc;
  #pragma unroll
  for (int j = 0; j < 8; ++j) {
    const short A = f2bf(x[j]);
    const float r1 = x[j] - bf2f(A);
    const short B = f2bf(r1);
    va[j] = A; vb[j] = B;
    vc[j] = f2bf(r1 - bf2f(B));
  }
  *(bf16x8*)(d.a + 8*i) = va;
  *(bf16x8*)(d.b + 8*i) = vb;
  if (d.nc == 3) *(bf16x8*)(d.c + 8*i) = vc;
}

// ---------------------------------------------------------------- tiled split-bf16 MFMA GEMM
// BK=64, 128x128 tile, 4 waves (2x2), each wave 64x64 = 4x4 16x16 frags.
// chunk pairs (c = step>>4): c0 (a,a), c1 (a,b), c2 (b,a), c3 (a,c), c4 (c,a), c5 (b,b)
// LDS: linear dest for global_load_lds; SOURCE k-slot pre-swizzled s^=(row&7);
// fragment reads apply the same XOR -> conflict-free ds_read_b128 (rule 21).
// XCD-aware bijective block swizzle (T1): nwg % 8 == 0 for all launches here.
struct GemmDesc {
  const short* X[3];
  const short* W[3];
  const float* bias;    // may be null
  float* C;
  int sbeg, send;       // step range; one step = 64 k-elems; chunk = step>>4
};
struct GemmArgs { GemmDesc d[3]; };

template<bool SC>
__global__ __launch_bounds__(256, 3) void gemm_tile_k(GemmArgs args) {
  __shared__ short As[128*64];   // 16 KB, row-major [m][k], swizzled slots
  __shared__ short Bs[128*64];   // 16 KB, row-major [n][k]
  // --- T1 swizzle
  const int nwg = gridDim.x * gridDim.y * gridDim.z;
  int id = blockIdx.x + (gridDim.x * (blockIdx.y + gridDim.y * blockIdx.z));
  id = (id & 7) * (nwg >> 3) + (id >> 3);
  const int bx = id & 7;            // gridDim.x == 8
  const int by = (id >> 3) & 31;    // gridDim.y == 32
  const int bz = id >> 8;
  const GemmDesc d = args.d[bz];
  const int tid = threadIdx.x;
  const int wv = tid >> 6, L = tid & 63;
  const int lr = L & 15, lg = L >> 4;
  const int n0 = bx << 7, m0 = by << 7;
  const int wm = (wv >> 1) << 6, wn = (wv & 1) << 6;

  const int sr = tid >> 3;          // staging row within 32-row group
  const int ssl = tid & 7;          // staging 16B slot within 128B row

  f32x4 acc[4][4];
  #pragma unroll
  for (int i = 0; i < 4; ++i)
    #pragma unroll
    for (int j = 0; j < 4; ++j) acc[i][j] = (f32x4){0.f,0.f,0.f,0.f};

  for (int step = d.sbeg; step < d.send; ++step) {
    const int c = step >> 4, kk = (step & 15) << 6;
    const short *Xg, *Wg;
    switch (c) {
      case 0:  Xg = d.X[0]; Wg = d.W[0]; break;
      case 1:  Xg = d.X[0]; Wg = d.W[1]; break;
      case 2:  Xg = d.X[1]; Wg = d.W[0]; break;
      case 3:  Xg = d.X[0]; Wg = d.W[2]; break;
      case 4:  Xg = d.X[2]; Wg = d.W[0]; break;
      default: Xg = d.X[1]; Wg = d.W[1]; break;
    }
    #pragma unroll
    for (int j = 0; j < 4; ++j) {
      const int row = (j << 5) + sr;
      const int kof = kk + ((ssl ^ (row & 7)) << 3);   // pre-swizzled global k
      gload16(Xg + (size_t)(m0 + row) * NDM + kof, As + (j << 11) + (tid << 3));
      gload16(Wg + (size_t)(n0 + row) * NDM + kof, Bs + (j << 11) + (tid << 3));
    }
    __syncthreads();
    #pragma unroll
    for (int c2 = 0; c2 < 2; ++c2) {
      const int sl = (((c2 << 2) + lg) ^ (lr & 7)) << 3;
      bf16x8 af[4], bfr[4];
      #pragma unroll
      for (int t = 0; t < 4; ++t) {
        af[t]  = *(const bf16x8*)(As + ((wm + (t << 4) + lr) << 6) + sl);
        bfr[t] = *(const bf16x8*)(Bs + ((wn + (t << 4) + lr) << 6) + sl);
      }
      #pragma unroll
      for (int mt = 0; mt < 4; ++mt)
        #pragma unroll
        for (int nt = 0; nt < 4; ++nt)
          acc[mt][nt] = __builtin_amdgcn_mfma_f32_16x16x32_bf16(bfr[nt], af[mt], acc[mt][nt], 0, 0, 0);
    }
    __syncthreads();
  }

  #pragma unroll
  for (int nt = 0; nt < 4; ++nt) {
    const int n = n0 + wn + (nt << 4) + (lg << 2);
    float4 b4 = make_float4(0.f, 0.f, 0.f, 0.f);
    if (d.bias) b4 = *(const float4*)(d.bias + n);
    #pragma unroll
    for (int mt = 0; mt < 4; ++mt) {
      f32x4 a = acc[mt][nt];
      a[0] += b4.x; a[1] += b4.y; a[2] += b4.z; a[3] += b4.w;
      const int m = m0 + wm + (mt << 4) + lr;
      if (SC) {   // scatter into (B,H,L,D)
        const int bb = m >> 11, ll = m & (NL - 1);
        const int hh = n >> 6, dd = n & 63;
        *(f32x4*)(d.C + (((size_t)(bb*NH + hh)*NL + ll) << 6) + dd) = a;
      } else {
        *(f32x4*)(d.C + ((size_t)m << 10) + n) = a;
      }
    }
  }
}

// ---------------------------------------------------------------- K combine: Kp0+Kp1+bias -> Kbf bf16, khat partials
__global__ __launch_bounds__(256) void combine_k(const float* __restrict__ Kp0,
                                                 const float* __restrict__ Kp1,
                                                 const float* __restrict__ bk,
                                                 short* __restrict__ Kbf,
                                                 double* __restrict__ kpart) {
  __shared__ double sm[4][64];
  const int bh = blockIdx.x >> 5, seg = blockIdx.x & 31;
  const int g = threadIdx.x >> 6, d = threadIdx.x & 63;
  const int h = bh & 15;
  const float bias = bk[(h << 6) + d];
  double acc = 0.0;
  #pragma unroll 4
  for (int i = 0; i < 16; ++i) {
    const int l = (seg << 6) + (i << 2) + g;
    const size_t o = (((size_t)bh * NL + l) << 6) + d;
    const float k = Kp0[o] + Kp1[o] + bias;
    float ss = k * k;
    #pragma unroll
    for (int off = 32; off > 0; off >>= 1) ss += __shfl_xor(ss, off);
    const double inv = 1.0 / sqrt((double)ss);
    Kbf[o] = f2bf(k);
    acc += (double)k * inv;
  }
  sm[g][d] = acc;
  __syncthreads();
  if (threadIdx.x < 64)
    kpart[((((size_t)bh << 5) + seg) << 6) + threadIdx.x] =
        sm[0][threadIdx.x] + sm[1][threadIdx.x] + sm[2][threadIdx.x] + sm[3][threadIdx.x];
}

// ---------------------------------------------------------------- wtilde (+inline kbar reduce): wt[bh][j], s0[bh]
__global__ __launch_bounds__(256) void wtilde_k(const float* __restrict__ Wq,
                                                const float* __restrict__ bq,
                                                const double* __restrict__ kpart,
                                                double* __restrict__ wt,
                                                double* __restrict__ s0) {
  __shared__ double kb[64];
  const int bh = blockIdx.x, h = bh & 15;
  const int tid = threadIdx.x;
  if (tid < 64) {
    double s = 0.0;
    #pragma unroll
    for (int seg = 0; seg < 32; ++seg)
      s += kpart[((((size_t)bh << 5) + seg) << 6) + tid];
    kb[tid] = s * (1.0 / NL);
  }
  __syncthreads();
  const int j = (blockIdx.y << 8) + tid;
  double a = 0.0;
  #pragma unroll 8
  for (int d = 0; d < 64; ++d)
    a += (double)Wq[(((size_t)((h << 6) + d)) << 10) + j] * kb[d];
  wt[((size_t)bh << 10) + j] = a;
  if (blockIdx.y == 0 && tid < 64) {
    double p = (double)bq[(h << 6) + tid] * kb[tid];
    #pragma unroll
    for (int off = 32; off > 0; off >>= 1) p += __shfl_xor(p, off);
    if (tid == 0) s0[bh] = p;
  }
}

// ---------------------------------------------------------------- dotq[bh][l] = x_row . wt[bh]  (f64 accum)
__global__ __launch_bounds__(256) void dotq_k(const float* __restrict__ x,
                                              const double* __restrict__ wt,
                                              float* __restrict__ dotq) {
  __shared__ float xs[1024];
  __shared__ double sm[16][16];
  const int r = blockIdx.x, b = r >> 11, l = r & (NL - 1);
  const int tid = threadIdx.x;
  ((float4*)xs)[tid] = ((const float4*)(x + ((size_t)r << 10)))[tid];
  __syncthreads();
  const int h = tid >> 4, t = tid & 15;
  const double* w = wt + ((size_t)((b << 4) + h) << 10);
  double a = 0.0;
  #pragma unroll 8
  for (int i = 0; i < 64; ++i) {
    const int j = t + (i << 4);
    a += (double)xs[j] * w[j];
  }
  sm[h][t] = a;
  __syncthreads();
  if (tid < 16) {
    double s = 0.0;
    #pragma unroll
    for (int t2 = 0; t2 < 16; ++t2) s += sm[tid][t2];
    dotq[(((size_t)(b << 4) + tid) << 11) + l] = (float)s;
  }
}

// ---------------------------------------------------------------- ms = (dotq + s0) / |q|  (f64, inline norm)
__global__ __launch_bounds__(256) void msq_k(const float* __restrict__ Qb,
                                             const float* __restrict__ dotq,
                                             const double* __restrict__ s0,
                                             float* __restrict__ ms) {
  const int r = blockIdx.x * 256 + threadIdx.x;
  const int bh = r >> 11;
  const float4* p = (const float4*)(Qb + ((size_t)r << 6));
  double ss = 0.0;
  #pragma unroll
  for (int i = 0; i < 16; ++i) {
    const float4 v = p[i];
    ss += (double)v.x*v.x + (double)v.y*v.y + (double)v.z*v.z + (double)v.w*v.w;
  }
  ms[r] = (float)(((double)dotq[r] + s0[bh]) / sqrt(ss));
}

// ---------------------------------------------------------------- rank-based top-NU selection (+ inverse map)
__global__ __launch_bounds__(256) void select_rank_k(const float* __restrict__ ms,
                                                     int* __restrict__ sel,
                                                     int* __restrict__ invsel) {
  __shared__ unsigned long long keys[NL];
  const int bh = blockIdx.x >> 3, seg = blockIdx.x & 7;
  const int tid = threadIdx.x;
  for (int l = tid; l < NL; l += 256) {
    unsigned u = __float_as_uint(ms[(size_t)bh * NL + l]);
    u = (u & 0x80000000u) ? ~u : (u | 0x80000000u);   // order-preserving map
    keys[l] = ((unsigned long long)u << 32) | (unsigned)(NL - 1 - l);
  }
  __syncthreads();
  const int r = (seg << 8) + tid;
  const unsigned long long mine = keys[r];
  int cnt = 0;
  #pragma unroll 8
  for (int l = 0; l < NL; ++l) cnt += (keys[l] > mine) ? 1 : 0;
  if (cnt < NU) sel[bh*NU + cnt] = r;
  invsel[(size_t)bh * NL + r] = (cnt < NU) ? cnt : -1;
}

// ---------------------------------------------------------------- V = Vp0+Vp1+bv, transpose -> Vt (bh,d,l) bf16
__global__ __launch_bounds__(256) void transpose_v_k(const float* __restrict__ V0,
                                                     const float* __restrict__ V1,
                                                     const float* __restrict__ bv,
                                                     short* __restrict__ Vt) {
  __shared__ float Ts[64][65];
  const int bh = blockIdx.x >> 5, lt = blockIdx.x & 31;
  const int l0 = lt << 6, tid = threadIdx.x;
  const int lr = tid >> 2, j = tid & 3;
  const int h = bh & 15;
  const size_t rowo = ((size_t)bh*NL + l0 + lr) << 6;
  #pragma unroll
  for (int s = 0; s < 4; ++s) {
    const int dd = (j + 4*s) << 2;
    float4 v = *(const float4*)(V0 + rowo + dd);
    const float4 q = *(const float4*)(V1 + rowo + dd);
    const float4 b4 = *(const float4*)(bv + (h << 6) + dd);
    v.x += q.x + b4.x; v.y += q.y + b4.y; v.z += q.z + b4.z; v.w += q.w + b4.w;
    Ts[lr][dd+0] = v.x; Ts[lr][dd+1] = v.y; Ts[lr][dd+2] = v.z; Ts[lr][dd+3] = v.w;
  }
  __syncthreads();
  const int d = tid >> 2, lc = (tid & 3) << 4;
  short* dst = Vt + ((size_t)bh*ND + d) * NL + l0 + lc;
  bf16x8 o0, o1;
  #pragma unroll
  for (int i = 0; i < 8; ++i) {
    o0[i] = f2bf(Ts[lc + i][d]);
    o1[i] = f2bf(Ts[lc + 8 + i][d]);
  }
  *(bf16x8*)dst = o0;
  *(bf16x8*)(dst + 8) = o1;
}

// ---------------------------------------------------------------- gather selected Q rows -> bf16 [MTOT][64]
__global__ __launch_bounds__(256) void gather_q_k(const float* __restrict__ Qb,
                                                  const int* __restrict__ sel,
                                                  short* __restrict__ Qg) {
  const int row = blockIdx.x * 4 + (threadIdx.x >> 6);
  const int d = threadIdx.x & 63;
  const int bh = row / NUP, u = row - bh * NUP;
  float v = 0.f;
  if (u < NU) {
    const int lq = sel[bh*NU + u];
    v = Qb[(((size_t)bh*NL + lq) << 6) + d];
  }
  Qg[((size_t)row << 6) + d] = f2bf(v);
}

// ---------------------------------------------------------------- fused attention: QK^T -> softmax -> PV per 32-row block
__global__ __launch_bounds__(512) void fattn_k(const short* __restrict__ Qg,
                                               const short* __restrict__ Kbf,
                                               const short* __restrict__ Vt,
                                               float* __restrict__ Csel) {
  __shared__ short S[32*2048];        // 128 KB, row stride 4096 B
  __shared__ float inv_s[32];
  int bid = blockIdx.x;
  bid = (bid & 7) * 52 + (bid >> 3);  // 416 = 8*52 XCD chunks
  const int m0 = bid << 5;
  const int bh = m0 / NUP;
  const int tid = threadIdx.x;
  const int w = tid >> 6, L = tid & 63;
  const int lr = L & 15, lg = L >> 4;

  bf16x8 qf[2][2];
  #pragma unroll
  for (int mt = 0; mt < 2; ++mt) {
    const short* qp = Qg + (((size_t)m0 + mt*16 + lr) << 6) + lg*8;
    qf[mt][0] = *(const bf16x8*)qp;
    qf[mt][1] = *(const bf16x8*)(qp + 32);
  }
  const int nb = w << 8;
  const short* kb0 = Kbf + (((size_t)bh*NL + nb + lr) << 6) + lg*8;
  #pragma unroll 2
  for (int nt = 0; nt < 16; ++nt) {
    const short* kp = kb0 + ((size_t)nt << 10);
    const bf16x8 kf0 = *(const bf16x8*)kp;
    const bf16x8 kf1 = *(const bf16x8*)(kp + 32);
    #pragma unroll
    for (int mt = 0; mt < 2; ++mt) {
      f32x4 a = {0.f,0.f,0.f,0.f};
      a = __builtin_amdgcn_mfma_f32_16x16x32_bf16(kf0, qf[mt][0], a, 0, 0, 0);
      a = __builtin_amdgcn_mfma_f32_16x16x32_bf16(kf1, qf[mt][1], a, 0, 0, 0);
      const int m = mt*16 + lr;
      bf16x4 o;
      #pragma unroll
      for (int r = 0; r < 4; ++r) o[r] = f2bf(a[r] * 0.125f);
      const int byteoff = (m << 12) + ((((nb + nt*16 + lg*4) << 1)) ^ ((m & 7) << 4));
      *(bf16x4*)((char*)S + byteoff) = o;
    }
  }
  __syncthreads();

  #pragma unroll
  for (int j = 0; j < 4; ++j) {
    const int R = (w << 2) + j;
    char* rowp = (char*)S + (R << 12);
    const int sw = (R & 7) << 4;
    bf16x8 v[4];
    #pragma unroll
    for (int i = 0; i < 4; ++i)
      v[i] = *(const bf16x8*)(rowp + (((L << 6) + (i << 4)) ^ sw));
    float f[32];
    #pragma unroll
    for (int i = 0; i < 4; ++i)
      #pragma unroll
      for (int e = 0; e < 8; ++e) f[i*8+e] = bf2f(v[i][e]);
    float mx = f[0];
    #pragma unroll
    for (int i = 1; i < 32; ++i) mx = fmaxf(mx, f[i]);
    #pragma unroll
    for (int off = 32; off > 0; off >>= 1) mx = fmaxf(mx, __shfl_xor(mx, off));
    float sum = 0.f;
    #pragma unroll
    for (int i = 0; i < 32; ++i) { f[i] = __expf(f[i] - mx); sum += f[i]; }
    #pragma unroll
    for (int off = 32; off > 0; off >>= 1) sum += __shfl_xor(sum, off);
    bf16x8 p[4];
    #pragma unroll
    for (int i = 0; i < 4; ++i)
      #pragma unroll
      for (int e = 0; e < 8; ++e) p[i][e] = f2bf(f[i*8+e]);
    #pragma unroll
    for (int i = 0; i < 4; ++i)
      *(bf16x8*)(rowp + (((L << 6) + (i << 4)) ^ sw)) = p[i];
    if (L == 0) inv_s[R] = 1.f / sum;
  }
  __syncthreads();

  {
    const int mt = w & 1, dt = w >> 1;
    const int m = mt*16 + lr;
    const char* arow = (const char*)S + (m << 12);
    const int sw = (m & 7) << 4;
    const short* vrow = Vt + (((size_t)bh*ND + dt*16 + lr) << 11) + lg*8;
    f32x4 acc0 = {0.f,0.f,0.f,0.f}, acc1 = {0.f,0.f,0.f,0.f};
    for (int k0 = 0; k0 < NL; k0 += 64) {
      const bf16x8 p0 = *(const bf16x8*)(arow + ((((k0 + lg*8) << 1)) ^ sw));
      const bf16x8 p1 = *(const bf16x8*)(arow + ((((k0 + 32 + lg*8) << 1)) ^ sw));
      const bf16x8 v0 = *(const bf16x8*)(vrow + k0);
      const bf16x8 v1 = *(const bf16x8*)(vrow + k0 + 32);
      acc0 = __builtin_amdgcn_mfma_f32_16x16x32_bf16(p0, v0, acc0, 0, 0, 0);
      acc1 = __builtin_amdgcn_mfma_f32_16x16x32_bf16(p1, v1, acc1, 0, 0, 0);
    }
    float* c = Csel + (((size_t)m0 + mt*16 + (lg << 2)) << 6) + dt*16 + lr;
    #pragma unroll
    for (int r = 0; r < 4; ++r)
      c[(size_t)(r << 6)] = (acc0[r] + acc1[r]) * inv_s[mt*16 + (lg << 2) + r];
  }
}

// ---------------------------------------------------------------- build dense split-CTX from Csel via invsel (zeros elsewhere)
__global__ __launch_bounds__(256) void ctx_build_k(const float* __restrict__ Csel,
                                                   const int* __restrict__ invsel,
                                                   short* __restrict__ Ca,
                                                   short* __restrict__ Cb) {
  const int row = blockIdx.x;                 // (b,l) in 0..4095
  const int b = row >> 11, l = row & (NL - 1);
  const int h = threadIdx.x >> 4, d0 = (threadIdx.x & 15) << 2;
  const int bh = (b << 4) + h;
  const int u = invsel[(size_t)bh * NL + l];
  bf16x4 a4 = {0,0,0,0}, b4 = {0,0,0,0};
  if (u >= 0) {
    const f32x4 x = *(const f32x4*)(Csel + (((size_t)bh*NUP + u) << 6) + d0);
    #pragma unroll
    for (int i = 0; i < 4; ++i) {
      const short A = f2bf(x[i]);
      a4[i] = A;
      b4[i] = f2bf(x[i] - bf2f(A));
    }
  }
  const size_t o = (((size_t)row) << 10) + (h << 6) + d0;
  *(bf16x4*)(Ca + o) = a4;
  *(bf16x4*)(Cb + o) = b4;
}

// ---------------------------------------------------------------- out += P1 + bias
__global__ __launch_bounds__(256) void oadd_k(float* __restrict__ out,
                                              const float* __restrict__ P1,
                                              const float* __restrict__ bo) {
  const size_t i4 = (size_t)blockIdx.x * 256 + threadIdx.x;
  const size_t i = i4 << 2;
  float4 a = *(float4*)(out + i);
  const float4 b = *(const float4*)(P1 + i);
  const float4 c = *(const float4*)(bo + ((i4 & 255) << 2));
  a.x += b.x + c.x; a.y += b.y + c.y; a.z += b.z + c.z; a.w += b.w + c.w;
  *(float4*)(out + i) = a;
}

// ---------------------------------------------------------------- launch
extern "C" void kernel_launch(void* const* d_in, const int* in_sizes, int n_in,
                              void* d_out, int out_size, void* d_ws, size_t ws_size,
                              hipStream_t stream)
{
  (void)in_sizes; (void)n_in; (void)out_size; (void)ws_size;
  const float* queries = (const float*)d_in[0];
  const float* keys    = (const float*)d_in[1];
  const float* values  = (const float*)d_in[2];
  const float* Wq = (const float*)d_in[3];  const float* bq = (const float*)d_in[4];
  const float* Wk = (const float*)d_in[5];  const float* bk = (const float*)d_in[6];
  const float* Wv = (const float*)d_in[7];  const float* bv = (const float*)d_in[8];
  const float* Wo = (const float*)d_in[9];  const float* bo = (const float*)d_in[10];
  float* out = (float*)d_out;

  char* base = (char*)d_ws;
  #define MB(x) ((size_t)(x) << 20)

  short* Qa   = (short*)(base + MB(0));    // queries split a  -> Kbf after phase1
  short* Qb2  = (short*)(base + MB(8));    // queries split b  -> Vt
  short* Ka   = (short*)(base + MB(16));   // keys split a     -> Va -> Cta
  short* Kb2  = (short*)(base + MB(24));   // keys split b     -> Vb2 -> Ctb
  short* Kc   = (short*)(base + MB(32));   // keys split c     (dead after ph1)
  float* Qb   = (float*)(base + MB(44));   // Q proj f32       -> Csel after gather
  float* Kp0  = (float*)(base + MB(60));   // K partial 0 -> Vp0 -> P1o
  float* Kp1  = (float*)(base + MB(76));   // K partial 1 -> Vp1
  short* Wqa  = (short*)(base + MB(92));   // -> Woa
  short* Wqb  = (short*)(base + MB(94));   // -> Wob
  short* Wka  = (short*)(base + MB(96));   // -> Wva
  short* Wkb  = (short*)(base + MB(98));   // -> Wvb
  short* Wkc  = (short*)(base + MB(100));  // -> smalls after phase1
  short* Qg   = (short*)(base + MB(102));  // 1.7 MB

  short* Kbf = Qa;
  short* Vt  = Qb2;
  short* Va  = Ka;
  short* Vb2 = Kb2;
  short* Cta = Ka;
  short* Ctb = Kb2;
  float* Vp0 = Kp0;
  float* Vp1 = Kp1;
  float* P1o = Kp0;
  float* Csel = Qb;
  short* Woa = Wqa; short* Wob = Wqb;
  short* Wva = Wka; short* Wvb = Wkb;

  char* sm = base + MB(100);                // over dead Wkc (written after phase1)
  double* kpart  = (double*)sm;             sm += 524288;
  double* wtil   = (double*)sm;             sm += 262144;
  double* s0     = (double*)sm;             sm += 512;
  float*  dotq   = (float*)sm;              sm += 262144;
  float*  msb    = (float*)sm;              sm += 262144;
  int*    sel    = (int*)sm;                sm += 65536;
  int*    invsel = (int*)sm;                sm += 262144;

  // ---- phase 0: splits (Q 2-way, K 3-way; Wq 2-way, Wk 3-way)
  {
    SplitArgs a;
    a.d[0] = {queries, Qa, Qb2, nullptr, 2};
    a.d[1] = {keys,    Ka, Kb2, Kc, 3};
    msplit_k<<<dim3(2048,1,2), 256, 0, stream>>>(a);
  }
  {
    SplitArgs a;
    a.d[0] = {Wq, Wqa, Wqb, nullptr, 2};
    a.d[1] = {Wk, Wka, Wkb, Wkc, 3};
    msplit_k<<<dim3(512,1,2), 256, 0, stream>>>(a);
  }
  // ---- phase 1: Q (3-product) + K (6-product, split-K 2-way), BK=64, 768 blocks
  {
    GemmArgs g;
    g.d[0] = {{Qa,Qb2,nullptr}, {Wqa,Wqb,nullptr}, bq, Qb, 0, 48};
    g.d[1] = {{Ka,Kb2,Kc}, {Wka,Wkb,Wkc}, nullptr, Kp0, 0, 48};
    g.d[2] = {{Ka,Kb2,Kc}, {Wka,Wkb,Wkc}, nullptr, Kp1, 48, 96};
    gemm_tile_k<true><<<dim3(8,32,3), 256, 0, stream>>>(g);
  }
  // ---- ranking chain
  combine_k<<<NBH*32, 256, 0, stream>>>(Kp0, Kp1, bk, Kbf, kpart);
  wtilde_k<<<dim3(NBH,4), 256, 0, stream>>>(Wq, bq, kpart, wtil, s0);
  dotq_k<<<NROWS, 256, 0, stream>>>(queries, wtil, dotq);
  msq_k<<<NRTOT/256, 256, 0, stream>>>(Qb, dotq, s0, msb);
  select_rank_k<<<NBH*8, 256, 0, stream>>>(msb, sel, invsel);

  // ---- phase 2: V (3-product, split-K 2-way over z)
  {
    SplitArgs a;
    a.d[0] = {values, Va, Vb2, nullptr, 2};
    a.d[1] = a.d[0];
    msplit_k<<<dim3(2048,1,1), 256, 0, stream>>>(a);
  }
  {
    SplitArgs a;
    a.d[0] = {Wv, Wva, Wvb, nullptr, 2};
    a.d[1] = {Wo, Woa, Wob, nullptr, 2};
    msplit_k<<<dim3(512,1,2), 256, 0, stream>>>(a);
  }
  {
    GemmArgs g;
    g.d[0] = {{Va,Vb2,nullptr}, {Wva,Wvb,nullptr}, nullptr, Vp0, 0, 24};
    g.d[1] = {{Va,Vb2,nullptr}, {Wva,Wvb,nullptr}, nullptr, Vp1, 24, 48};
    g.d[2] = g.d[0];
    gemm_tile_k<true><<<dim3(8,32,2), 256, 0, stream>>>(g);
  }
  transpose_v_k<<<NBH*32, 256, 0, stream>>>(Vp0, Vp1, bv, Vt);
  gather_q_k<<<MTOT/4, 256, 0, stream>>>(Qb, sel, Qg);

  // ---- phase 3: fused attention
  fattn_k<<<MTOT/32, 512, 0, stream>>>(Qg, Kbf, Vt, Csel);

  // ---- phase 4: dense split-CTX build + output projection (split-K 2-way) + combine
  ctx_build_k<<<NROWS, 256, 0, stream>>>(Csel, invsel, Cta, Ctb);
  {
    GemmArgs g;
    g.d[0] = {{Cta,Ctb,nullptr}, {Woa,Wob,nullptr}, nullptr, out, 0, 24};
    g.d[1] = {{Cta,Ctb,nullptr}, {Woa,Wob,nullptr}, nullptr, P1o, 24, 48};
    g.d[2] = g.d[0];
    gemm_tile_k<false><<<dim3(8,32,2), 256, 0, stream>>>(g);
  }
  oadd_k<<<4096, 256, 0, stream>>>(out, P1o, bo);
}

// Round 8
// 296.743 us; speedup vs baseline: 9.0634x; 1.1310x over previous
//
#include <hip/hip_runtime.h>
#include <math.h>

// Problem constants (fixed by setup_inputs)
#define NB 2
#define NL 2048
#define NH 16
#define ND 64
#define NDM 1024
#define NU 409                  // max(1, 2048 // 5)
#define NUP 416                 // NU padded to multiple of 32; 416 = 26*16 = 13*32
#define NBH (NB*NH)             // 32
#define NROWS (NB*NL)           // 4096
#define NRTOT (NB*NH*NL)        // 65536
#define MTOT (NBH*NUP)          // 13312

typedef short bf16x8 __attribute__((ext_vector_type(8)));
typedef short bf16x4 __attribute__((ext_vector_type(4)));
typedef float f32x4  __attribute__((ext_vector_type(4)));

__device__ __forceinline__ short f2bf(float x) {   // RNE f32 -> bf16
  unsigned u = __float_as_uint(x);
  return (short)((u + 0x7FFFu + ((u >> 16) & 1u)) >> 16);
}
__device__ __forceinline__ float bf2f(short s) {
  return __uint_as_float(((unsigned)(unsigned short)s) << 16);
}

__device__ __forceinline__ void gload16(const short* g, short* l) {
  __builtin_amdgcn_global_load_lds(
      (const __attribute__((address_space(1))) void*)g,
      (__attribute__((address_space(3))) void*)l, 16, 0, 0);
}

// ---------------------------------------------------------------- multi-tensor f32 -> bf16 splits
struct SplitDesc { const float* in; short* a; short* b; short* c; int nc; };
struct SplitArgs { SplitDesc d[4]; };

__global__ __launch_bounds__(256) void msplit_k(SplitArgs args) {
  const SplitDesc d = args.d[blockIdx.z];
  const size_t i = (size_t)blockIdx.x * 256 + threadIdx.x;
  const float4 x0 = ((const float4*)d.in)[2*i];
  const float4 x1 = ((const float4*)d.in)[2*i + 1];
  float x[8] = {x0.x,x0.y,x0.z,x0.w, x1.x,x1.y,x1.z,x1.w};
  bf16x8 va, vb, vc;
  #pragma unroll
  for (int j = 0; j < 8; ++j) {
    const short A = f2bf(x[j]);
    const float r1 = x[j] - bf2f(A);
    const short B = f2bf(r1);
    va[j] = A; vb[j] = B;
    vc[j] = f2bf(r1 - bf2f(B));
  }
  *(bf16x8*)(d.a + 8*i) = va;
  if (d.nc >= 2) *(bf16x8*)(d.b + 8*i) = vb;
  if (d.nc == 3) *(bf16x8*)(d.c + 8*i) = vc;
}

// ---------------------------------------------------------------- fused split-bf16 MFMA GEMM
// BK=64, 128x128 tile, 4 waves (2x2), wave 64x64 = 4x4 16x16 frags.
// chunk pairs (c=step>>4): c0 (a,a), c1 (a,b), c2 (b,a), c3 (a,c), c4 (c,a), c5 (b,b)
// LDS: linear dest for global_load_lds; SOURCE k-slot pre-swizzled s^=(row&7);
// fragment reads apply the same XOR (rule 21). Per-desc XCD swizzle on (bx,by).
// mode 0: normal X staging, SC-scatter f32 + bias (Q, V)
// mode 1: normal X staging, fused K epilogue (bias+norm -> Kbf bf16, f64 kbar partials)
// mode 2: X staged from Csel via invsel LDS table (one head per step), plain f32 out (O)
struct GemmDesc {
  const short* X[3];
  const short* W[3];
  const float* bias;    // may be null
  float* C;             // modes 0/2
  short* Kbf;           // mode 1
  double* kpart;        // mode 1: [bh][32][64] f64
  const int* invsel;    // mode 2
  int sbeg, send;       // step range; one step = 64 k-elems; chunk = step>>4
  int mode;
};
struct GemmArgs { GemmDesc d[3]; };

__global__ __launch_bounds__(256, 3) void gemm_fused_k(GemmArgs args) {
  __shared__ short As[128*64];   // 16 KB
  __shared__ short Bs[128*64];   // 16 KB
  __shared__ int utbl[128*16];   // 8 KB (mode 2 only)
  int id = blockIdx.x + (blockIdx.y << 3);        // 0..255 per desc
  id = (id & 7) * 32 + (id >> 3);                 // XCD-chunked, bijective
  const int bx = id & 7, by = id >> 3;
  const GemmDesc d = args.d[blockIdx.z];
  const int tid = threadIdx.x;
  const int wv = tid >> 6, L = tid & 63;
  const int lr = L & 15, lg = L >> 4;
  const int n0 = bx << 7, m0 = by << 7;
  const int wm = (wv >> 1) << 6, wn = (wv & 1) << 6;
  const int sr = tid >> 3, ssl = tid & 7;
  const int b = by >> 4;                          // batch (m rows never cross)

  if (d.mode == 2) {
    #pragma unroll
    for (int e = 0; e < 8; ++e) {
      const int idx = (tid << 3) + e;             // 0..2047
      const int row = idx >> 4, h = idx & 15;
      utbl[idx] = d.invsel[((((size_t)b << 4) + h) << 11) + ((m0 + row) & (NL - 1))];
    }
    __syncthreads();
  }

  f32x4 acc[4][4];
  #pragma unroll
  for (int i = 0; i < 4; ++i)
    #pragma unroll
    for (int j = 0; j < 4; ++j) acc[i][j] = (f32x4){0.f,0.f,0.f,0.f};

  for (int step = d.sbeg; step < d.send; ++step) {
    const int c = step >> 4, kk = (step & 15) << 6;
    const short *Xg, *Wg;
    switch (c) {
      case 0:  Xg = d.X[0]; Wg = d.W[0]; break;
      case 1:  Xg = d.X[0]; Wg = d.W[1]; break;
      case 2:  Xg = d.X[1]; Wg = d.W[0]; break;
      case 3:  Xg = d.X[0]; Wg = d.W[2]; break;
      case 4:  Xg = d.X[2]; Wg = d.W[0]; break;
      default: Xg = d.X[1]; Wg = d.W[1]; break;
    }
    #pragma unroll
    for (int j = 0; j < 4; ++j) {
      const int row = (j << 5) + sr;
      const int slot = (ssl ^ (row & 7)) << 3;    // pre-swizzled k-slot
      const short* xsrc;
      if (d.mode == 2) {
        const int h = step & 15;                  // one head per 64-wide step
        const int u = utbl[(row << 4) + h];
        xsrc = Xg + (((size_t)((b << 4) + h) * NUP + u) << 6) + slot;
      } else {
        xsrc = Xg + (size_t)(m0 + row) * NDM + kk + slot;
      }
      gload16(xsrc, As + (j << 11) + (tid << 3));
      gload16(Wg + (size_t)(n0 + row) * NDM + kk + slot, Bs + (j << 11) + (tid << 3));
    }
    __syncthreads();
    #pragma unroll
    for (int c2 = 0; c2 < 2; ++c2) {
      const int sl = (((c2 << 2) + lg) ^ (lr & 7)) << 3;
      bf16x8 af[4], bfr[4];
      #pragma unroll
      for (int t = 0; t < 4; ++t) {
        af[t]  = *(const bf16x8*)(As + ((wm + (t << 4) + lr) << 6) + sl);
        bfr[t] = *(const bf16x8*)(Bs + ((wn + (t << 4) + lr) << 6) + sl);
      }
      #pragma unroll
      for (int mt = 0; mt < 4; ++mt)
        #pragma unroll
        for (int nt = 0; nt < 4; ++nt)
          acc[mt][nt] = __builtin_amdgcn_mfma_f32_16x16x32_bf16(bfr[nt], af[mt], acc[mt][nt], 0, 0, 0);
    }
    __syncthreads();
  }

  if (d.mode == 1) {
    // ---- fused K epilogue: k = acc + bias; |k| via shfl over lg groups;
    //      Kbf bf16 store; f64 kbar partials reduced over lr lanes.
    const int hw = (bx << 1) + (wv & 1);          // head of this wave
    const int bh = (b << 4) + hw;
    const int seg = ((by & 15) << 1) + (wv >> 1); // 64-row segment within bh
    float kv[4][4][4];
    double inv[4];
    #pragma unroll
    for (int mt = 0; mt < 4; ++mt) {
      float ss = 0.f;
      #pragma unroll
      for (int nt = 0; nt < 4; ++nt) {
        const int n = n0 + wn + (nt << 4) + (lg << 2);
        const float4 b4 = *(const float4*)(d.bias + n);
        kv[mt][nt][0] = acc[mt][nt][0] + b4.x;
        kv[mt][nt][1] = acc[mt][nt][1] + b4.y;
        kv[mt][nt][2] = acc[mt][nt][2] + b4.z;
        kv[mt][nt][3] = acc[mt][nt][3] + b4.w;
        #pragma unroll
        for (int j = 0; j < 4; ++j) ss += kv[mt][nt][j] * kv[mt][nt][j];
      }
      ss += __shfl_xor(ss, 16);
      ss += __shfl_xor(ss, 32);
      inv[mt] = 1.0 / sqrt((double)ss);
    }
    #pragma unroll
    for (int mt = 0; mt < 4; ++mt) {
      const int l = (m0 + wm + (mt << 4) + lr) & (NL - 1);
      short* kp = d.Kbf + (((size_t)bh * NL + l) << 6);
      #pragma unroll
      for (int nt = 0; nt < 4; ++nt) {
        const int dd = (nt << 4) + (lg << 2);
        bf16x4 o;
        #pragma unroll
        for (int j = 0; j < 4; ++j) o[j] = f2bf(kv[mt][nt][j]);
        *(bf16x4*)(kp + dd) = o;
      }
    }
    #pragma unroll
    for (int nt = 0; nt < 4; ++nt) {
      double p[4];
      #pragma unroll
      for (int j = 0; j < 4; ++j) {
        p[j] = 0.0;
        #pragma unroll
        for (int mt = 0; mt < 4; ++mt) p[j] += (double)kv[mt][nt][j] * inv[mt];
        p[j] += __shfl_xor(p[j], 1);
        p[j] += __shfl_xor(p[j], 2);
        p[j] += __shfl_xor(p[j], 4);
        p[j] += __shfl_xor(p[j], 8);
      }
      if (lr == 0) {
        const int dd = (nt << 4) + (lg << 2);
        double* kp = d.kpart + ((((size_t)bh << 5) + seg) << 6) + dd;
        kp[0] = p[0]; kp[1] = p[1]; kp[2] = p[2]; kp[3] = p[3];
      }
    }
  } else {
    #pragma unroll
    for (int nt = 0; nt < 4; ++nt) {
      const int n = n0 + wn + (nt << 4) + (lg << 2);
      float4 b4 = make_float4(0.f, 0.f, 0.f, 0.f);
      if (d.bias) b4 = *(const float4*)(d.bias + n);
      #pragma unroll
      for (int mt = 0; mt < 4; ++mt) {
        f32x4 a = acc[mt][nt];
        a[0] += b4.x; a[1] += b4.y; a[2] += b4.z; a[3] += b4.w;
        const int m = m0 + wm + (mt << 4) + lr;
        if (d.mode == 0) {   // scatter into (B,H,L,D)
          const int bb = m >> 11, ll = m & (NL - 1);
          const int hh = n >> 6, dd = n & 63;
          *(f32x4*)(d.C + (((size_t)(bb*NH + hh)*NL + ll) << 6) + dd) = a;
        } else {
          *(f32x4*)(d.C + ((size_t)m << 10) + n) = a;
        }
      }
    }
  }
}

// ---------------------------------------------------------------- wtilde (+inline kbar reduce): wt[bh][j] f32, s0[bh] f64
__global__ __launch_bounds__(256) void wtilde_k(const float* __restrict__ Wq,
                                                const float* __restrict__ bq,
                                                const double* __restrict__ kpart,
                                                float* __restrict__ wt,
                                                double* __restrict__ s0) {
  __shared__ double kb[64];
  const int bh = blockIdx.x, h = bh & 15;
  const int tid = threadIdx.x;
  if (tid < 64) {
    double s = 0.0;
    #pragma unroll
    for (int seg = 0; seg < 32; ++seg)
      s += kpart[((((size_t)bh << 5) + seg) << 6) + tid];
    kb[tid] = s * (1.0 / NL);
  }
  __syncthreads();
  const int j = (blockIdx.y << 8) + tid;
  double a = 0.0;
  #pragma unroll 8
  for (int d = 0; d < 64; ++d)
    a += (double)Wq[(((size_t)((h << 6) + d)) << 10) + j] * kb[d];
  wt[((size_t)bh << 10) + j] = (float)a;
  if (blockIdx.y == 0 && tid < 64) {
    double p = (double)bq[(h << 6) + tid] * kb[tid];
    #pragma unroll
    for (int off = 32; off > 0; off >>= 1) p += __shfl_xor(p, off);
    if (tid == 0) s0[bh] = p;
  }
}

// ---------------------------------------------------------------- fused dotq+msq: ms[bh][l] = (x.wt + s0)/|q|
__global__ __launch_bounds__(256) void dotqms_k(const float* __restrict__ x,
                                                const float* __restrict__ Qb,
                                                const float* __restrict__ wt,
                                                const double* __restrict__ s0,
                                                float* __restrict__ ms) {
  __shared__ float xs[1024];
  __shared__ double sm[16][16];
  __shared__ double sq[16][16];
  const int r = blockIdx.x, b = r >> 11, l = r & (NL - 1);
  const int tid = threadIdx.x;
  ((float4*)xs)[tid] = ((const float4*)(x + ((size_t)r << 10)))[tid];
  __syncthreads();
  const int h = tid >> 4, t = tid & 15;
  const float* w = wt + ((size_t)((b << 4) + h) << 10);
  double a = 0.0;
  #pragma unroll 8
  for (int i = 0; i < 64; ++i) {
    const int j = t + (i << 4);
    a += (double)xs[j] * (double)w[j];
  }
  sm[h][t] = a;
  const float4 qv = *(const float4*)(Qb + (((size_t)((b << 4) + h) * NL + l) << 6) + (t << 2));
  sq[h][t] = (double)qv.x*qv.x + (double)qv.y*qv.y + (double)qv.z*qv.z + (double)qv.w*qv.w;
  __syncthreads();
  if (tid < 16) {
    double s = 0.0, ssq = 0.0;
    #pragma unroll
    for (int t2 = 0; t2 < 16; ++t2) { s += sm[tid][t2]; ssq += sq[tid][t2]; }
    ms[(((size_t)(b << 4) + tid) << 11) + l] = (float)((s + s0[(b << 4) + tid]) / sqrt(ssq));
  }
}

// ---------------------------------------------------------------- rank-based top-NU selection (+ inverse map; pad -> NU)
__global__ __launch_bounds__(256) void select_rank_k(const float* __restrict__ ms,
                                                     int* __restrict__ sel,
                                                     int* __restrict__ invsel) {
  __shared__ unsigned long long keys[NL];
  const int bh = blockIdx.x >> 3, seg = blockIdx.x & 7;
  const int tid = threadIdx.x;
  for (int l = tid; l < NL; l += 256) {
    unsigned u = __float_as_uint(ms[(size_t)bh * NL + l]);
    u = (u & 0x80000000u) ? ~u : (u | 0x80000000u);   // order-preserving map
    keys[l] = ((unsigned long long)u << 32) | (unsigned)(NL - 1 - l);
  }
  __syncthreads();
  const int r = (seg << 8) + tid;
  const unsigned long long mine = keys[r];
  int cnt = 0;
  #pragma unroll 8
  for (int l = 0; l < NL; ++l) cnt += (keys[l] > mine) ? 1 : 0;
  if (cnt < NU) sel[bh*NU + cnt] = r;
  invsel[(size_t)bh * NL + r] = (cnt < NU) ? cnt : NU;  // NU = zeroed pad row
}

// ---------------------------------------------------------------- V (bh,l,d) f32 -> Vt (bh,d,l) bf16
__global__ __launch_bounds__(256) void transpose_v_k(const float* __restrict__ V0,
                                                     short* __restrict__ Vt) {
  __shared__ float Ts[64][65];
  const int bh = blockIdx.x >> 5, lt = blockIdx.x & 31;
  const int l0 = lt << 6, tid = threadIdx.x;
  const int lr = tid >> 2, j = tid & 3;
  const size_t rowo = ((size_t)bh*NL + l0 + lr) << 6;
  #pragma unroll
  for (int s = 0; s < 4; ++s) {
    const int dd = (j + 4*s) << 2;
    const float4 v = *(const float4*)(V0 + rowo + dd);
    Ts[lr][dd+0] = v.x; Ts[lr][dd+1] = v.y; Ts[lr][dd+2] = v.z; Ts[lr][dd+3] = v.w;
  }
  __syncthreads();
  const int d = tid >> 2, lc = (tid & 3) << 4;
  short* dst = Vt + ((size_t)bh*ND + d) * NL + l0 + lc;
  bf16x8 o0, o1;
  #pragma unroll
  for (int i = 0; i < 8; ++i) {
    o0[i] = f2bf(Ts[lc + i][d]);
    o1[i] = f2bf(Ts[lc + 8 + i][d]);
  }
  *(bf16x8*)dst = o0;
  *(bf16x8*)(dst + 8) = o1;
}

// ---------------------------------------------------------------- fused attention with inline Q gather; split bf16 Csel out
__global__ __launch_bounds__(512) void fattn_k(const float* __restrict__ Qb,
                                               const int* __restrict__ sel,
                                               const short* __restrict__ Kbf,
                                               const short* __restrict__ Vt,
                                               short* __restrict__ Ca,
                                               short* __restrict__ Cb) {
  __shared__ short S[32*2048];        // 128 KB, row stride 4096 B
  __shared__ float inv_s[32];
  int bid = blockIdx.x;
  bid = (bid & 7) * 52 + (bid >> 3);  // 416 = 8*52 XCD chunks
  const int m0 = bid << 5;
  const int bh = m0 / NUP;
  const int u0 = m0 - bh * NUP;
  const int tid = threadIdx.x;
  const int w = tid >> 6, L = tid & 63;
  const int lr = L & 15, lg = L >> 4;

  // ---- Q fragments gathered from f32 Qb via sel (pad rows read row 0, discarded)
  bf16x8 qf[2][2];
  #pragma unroll
  for (int mt = 0; mt < 2; ++mt) {
    const int u = u0 + mt*16 + lr;
    const int lq = (u < NU) ? sel[bh*NU + u] : 0;
    const float* qp = Qb + (((size_t)bh*NL + lq) << 6) + lg*8;
    const float4 q0 = *(const float4*)qp;
    const float4 q1 = *(const float4*)(qp + 4);
    const float4 q2 = *(const float4*)(qp + 32);
    const float4 q3 = *(const float4*)(qp + 36);
    qf[mt][0][0]=f2bf(q0.x); qf[mt][0][1]=f2bf(q0.y); qf[mt][0][2]=f2bf(q0.z); qf[mt][0][3]=f2bf(q0.w);
    qf[mt][0][4]=f2bf(q1.x); qf[mt][0][5]=f2bf(q1.y); qf[mt][0][6]=f2bf(q1.z); qf[mt][0][7]=f2bf(q1.w);
    qf[mt][1][0]=f2bf(q2.x); qf[mt][1][1]=f2bf(q2.y); qf[mt][1][2]=f2bf(q2.z); qf[mt][1][3]=f2bf(q2.w);
    qf[mt][1][4]=f2bf(q3.x); qf[mt][1][5]=f2bf(q3.y); qf[mt][1][6]=f2bf(q3.z); qf[mt][1][7]=f2bf(q3.w);
  }
  const int nb = w << 8;
  const short* kb0 = Kbf + (((size_t)bh*NL + nb + lr) << 6) + lg*8;
  #pragma unroll 2
  for (int nt = 0; nt < 16; ++nt) {
    const short* kp = kb0 + ((size_t)nt << 10);
    const bf16x8 kf0 = *(const bf16x8*)kp;
    const bf16x8 kf1 = *(const bf16x8*)(kp + 32);
    #pragma unroll
    for (int mt = 0; mt < 2; ++mt) {
      f32x4 a = {0.f,0.f,0.f,0.f};
      a = __builtin_amdgcn_mfma_f32_16x16x32_bf16(kf0, qf[mt][0], a, 0, 0, 0);
      a = __builtin_amdgcn_mfma_f32_16x16x32_bf16(kf1, qf[mt][1], a, 0, 0, 0);
      const int m = mt*16 + lr;
      bf16x4 o;
      #pragma unroll
      for (int r = 0; r < 4; ++r) o[r] = f2bf(a[r] * 0.125f);
      const int byteoff = (m << 12) + ((((nb + nt*16 + lg*4) << 1)) ^ ((m & 7) << 4));
      *(bf16x4*)((char*)S + byteoff) = o;
    }
  }
  __syncthreads();

  #pragma unroll
  for (int j = 0; j < 4; ++j) {
    const int R = (w << 2) + j;
    char* rowp = (char*)S + (R << 12);
    const int sw = (R & 7) << 4;
    bf16x8 v[4];
    #pragma unroll
    for (int i = 0; i < 4; ++i)
      v[i] = *(const bf16x8*)(rowp + (((L << 6) + (i << 4)) ^ sw));
    float f[32];
    #pragma unroll
    for (int i = 0; i < 4; ++i)
      #pragma unroll
      for (int e = 0; e < 8; ++e) f[i*8+e] = bf2f(v[i][e]);
    float mx = f[0];
    #pragma unroll
    for (int i = 1; i < 32; ++i) mx = fmaxf(mx, f[i]);
    #pragma unroll
    for (int off = 32; off > 0; off >>= 1) mx = fmaxf(mx, __shfl_xor(mx, off));
    float sum = 0.f;
    #pragma unroll
    for (int i = 0; i < 32; ++i) { f[i] = __expf(f[i] - mx); sum += f[i]; }
    #pragma unroll
    for (int off = 32; off > 0; off >>= 1) sum += __shfl_xor(sum, off);
    bf16x8 p[4];
    #pragma unroll
    for (int i = 0; i < 4; ++i)
      #pragma unroll
      for (int e = 0; e < 8; ++e) p[i][e] = f2bf(f[i*8+e]);
    #pragma unroll
    for (int i = 0; i < 4; ++i)
      *(bf16x8*)(rowp + (((L << 6) + (i << 4)) ^ sw)) = p[i];
    if (L == 0) inv_s[R] = 1.f / sum;
  }
  __syncthreads();

  {
    const int mt = w & 1, dt = w >> 1;
    const int m = mt*16 + lr;
    const char* arow = (const char*)S + (m << 12);
    const int sw = (m & 7) << 4;
    const short* vrow = Vt + (((size_t)bh*ND + dt*16 + lr) << 11) + lg*8;
    f32x4 acc0 = {0.f,0.f,0.f,0.f}, acc1 = {0.f,0.f,0.f,0.f};
    for (int k0 = 0; k0 < NL; k0 += 64) {
      const bf16x8 p0 = *(const bf16x8*)(arow + ((((k0 + lg*8) << 1)) ^ sw));
      const bf16x8 p1 = *(const bf16x8*)(arow + ((((k0 + 32 + lg*8) << 1)) ^ sw));
      const bf16x8 v0 = *(const bf16x8*)(vrow + k0);
      const bf16x8 v1 = *(const bf16x8*)(vrow + k0 + 32);
      acc0 = __builtin_amdgcn_mfma_f32_16x16x32_bf16(p0, v0, acc0, 0, 0, 0);
      acc1 = __builtin_amdgcn_mfma_f32_16x16x32_bf16(p1, v1, acc1, 0, 0, 0);
    }
    const int ub = u0 + mt*16 + (lg << 2);
    #pragma unroll
    for (int r = 0; r < 4; ++r) {
      float val = (acc0[r] + acc1[r]) * inv_s[mt*16 + (lg << 2) + r];
      if (ub + r >= NU) val = 0.f;                 // zero pad rows (incl. row NU)
      const size_t off = (((size_t)m0 + mt*16 + (lg << 2) + r) << 6) + dt*16 + lr;
      const short A = f2bf(val);
      Ca[off] = A;
      Cb[off] = f2bf(val - bf2f(A));
    }
  }
}

// ---------------------------------------------------------------- out += P1 + bias
__global__ __launch_bounds__(256) void oadd_k(float* __restrict__ out,
                                              const float* __restrict__ P1,
                                              const float* __restrict__ bo) {
  const size_t i4 = (size_t)blockIdx.x * 256 + threadIdx.x;
  const size_t i = i4 << 2;
  float4 a = *(float4*)(out + i);
  const float4 b = *(const float4*)(P1 + i);
  const float4 c = *(const float4*)(bo + ((i4 & 255) << 2));
  a.x += b.x + c.x; a.y += b.y + c.y; a.z += b.z + c.z; a.w += b.w + c.w;
  *(float4*)(out + i) = a;
}

// ---------------------------------------------------------------- launch
extern "C" void kernel_launch(void* const* d_in, const int* in_sizes, int n_in,
                              void* d_out, int out_size, void* d_ws, size_t ws_size,
                              hipStream_t stream)
{
  (void)in_sizes; (void)n_in; (void)out_size; (void)ws_size;
  const float* queries = (const float*)d_in[0];
  const float* keys    = (const float*)d_in[1];
  const float* values  = (const float*)d_in[2];
  const float* Wq = (const float*)d_in[3];  const float* bq = (const float*)d_in[4];
  const float* Wk = (const float*)d_in[5];  const float* bk = (const float*)d_in[6];
  const float* Wv = (const float*)d_in[7];  const float* bv = (const float*)d_in[8];
  const float* Wo = (const float*)d_in[9];  const float* bo = (const float*)d_in[10];
  float* out = (float*)d_out;

  char* base = (char*)d_ws;
  #define MB(x) ((size_t)(x) << 20)

  short* Qa   = (short*)(base + MB(0));    // 8 MiB  -> Vt after gemm3
  short* Qb2  = (short*)(base + MB(8));    // 8 MiB  -> CselA/CselB after gemm3
  short* Ka   = (short*)(base + MB(16));
  short* Kb2  = (short*)(base + MB(24));
  short* Kc   = (short*)(base + MB(32));
  short* Vbf  = (short*)(base + MB(40));
  float* Qb   = (float*)(base + MB(48));   // 16 MiB -> P1o after fattn
  short* Kbf  = (short*)(base + MB(64));   // 8 MiB
  short* Wqa  = (short*)(base + MB(72));
  short* Wqb  = (short*)(base + MB(74));
  short* Wka  = (short*)(base + MB(76));
  short* Wkb  = (short*)(base + MB(78));
  short* Wkc  = (short*)(base + MB(80));
  short* Wvbf = (short*)(base + MB(82));
  short* Woa  = (short*)(base + MB(84));
  short* Wob  = (short*)(base + MB(86));
  char* sm = base + MB(88);
  double* kpart  = (double*)sm;  sm += 524288;   // [32][32][64] f64
  float*  wt     = (float*)sm;   sm += 131072;   // [32][1024] f32
  double* s0     = (double*)sm;  sm += 512;
  float*  msb    = (float*)sm;   sm += 262144;
  int*    sel    = (int*)sm;     sm += 65536;
  int*    invsel = (int*)sm;     sm += 262144;

  // time-multiplexed aliases
  float* Vp    = out;                       // V projection scratch (fully overwritten later)
  short* Vt    = Qa;                        // after gemm3
  short* CselA = Qb2;                       // 1.625 MiB
  short* CselB = (short*)(base + MB(10));   // 1.625 MiB
  float* P1o   = Qb;                        // after fattn

  // ---- 1: input splits (Q 2-way, K 3-way, V 1-way)
  {
    SplitArgs a;
    a.d[0] = {queries, Qa, Qb2, nullptr, 2};
    a.d[1] = {keys,    Ka, Kb2, Kc, 3};
    a.d[2] = {values,  Vbf, nullptr, nullptr, 1};
    a.d[3] = a.d[0];
    msplit_k<<<dim3(2048,1,3), 256, 0, stream>>>(a);
  }
  // ---- 2: weight splits (Wq 2, Wk 3, Wv 1, Wo 2)
  {
    SplitArgs a;
    a.d[0] = {Wq, Wqa, Wqb, nullptr, 2};
    a.d[1] = {Wk, Wka, Wkb, Wkc, 3};
    a.d[2] = {Wv, Wvbf, nullptr, nullptr, 1};
    a.d[3] = {Wo, Woa, Wob, nullptr, 2};
    msplit_k<<<dim3(512,1,4), 256, 0, stream>>>(a);
  }
  // ---- 3: mega projection GEMM: Q(3-prod) + K(6-prod, fused epilogue) + V(1-prod)
  {
    GemmArgs g;
    g.d[0] = {{Qa,Qb2,Qa}, {Wqa,Wqb,Wqa}, bq, Qb, nullptr, nullptr, nullptr, 0, 48, 0};
    g.d[1] = {{Ka,Kb2,Kc}, {Wka,Wkb,Wkc}, bk, nullptr, Kbf, kpart, nullptr, 0, 96, 1};
    g.d[2] = {{Vbf,Vbf,Vbf}, {Wvbf,Wvbf,Wvbf}, bv, Vp, nullptr, nullptr, nullptr, 0, 16, 0};
    gemm_fused_k<<<dim3(8,32,3), 256, 0, stream>>>(g);
  }
  // ---- 4-7: V transpose + ranking chain
  transpose_v_k<<<NBH*32, 256, 0, stream>>>(Vp, Vt);
  wtilde_k<<<dim3(NBH,4), 256, 0, stream>>>(Wq, bq, kpart, wt, s0);
  dotqms_k<<<NROWS, 256, 0, stream>>>(queries, Qb, wt, s0, msb);
  select_rank_k<<<NBH*8, 256, 0, stream>>>(msb, sel, invsel);

  // ---- 8: fused attention (inline Q gather; split bf16 Csel; pad rows zeroed)
  fattn_k<<<MTOT/32, 512, 0, stream>>>(Qb, sel, Kbf, Vt, CselA, CselB);

  // ---- 9: output projection (X gathered from Csel via invsel), split-K 2-way
  {
    GemmArgs g;
    g.d[0] = {{CselA,CselB,CselA}, {Woa,Wob,Woa}, nullptr, out, nullptr, nullptr, invsel, 0, 24, 2};
    g.d[1] = {{CselA,CselB,CselA}, {Woa,Wob,Woa}, nullptr, P1o, nullptr, nullptr, invsel, 24, 48, 2};
    g.d[2] = g.d[0];
    gemm_fused_k<<<dim3(8,32,2), 256, 0, stream>>>(g);
  }
  // ---- 10: combine + bias
  oadd_k<<<4096, 256, 0, stream>>>(out, P1o, bo);
}